// Round 1
// baseline (3748.153 us; speedup 1.0000x reference)
//
#include <hip/hip_runtime.h>
#include <math.h>

// Problem dims
#define BB   4
#define TT   12
#define NN   307
#define SS   11
#define HH   64
#define NHH  4
#define DHH  16
#define EMB  152

// GEMM epilogue flags
#define GF_BIAS  1
#define GF_RELU  2
#define GF_ACCUM 4

__device__ __forceinline__ float wave_sum(float v) {
#pragma unroll
  for (int off = 32; off; off >>= 1) v += __shfl_xor(v, off);
  return v;
}
__device__ __forceinline__ float wave_max(float v) {
#pragma unroll
  for (int off = 32; off; off >>= 1) v = fmaxf(v, __shfl_xor(v, off));
  return v;
}

// ---------------------------------------------------------------------------
// Generic fp32 tiled GEMM: C[M,N] = op(A[M,K] @ B[K,N] [+C] [+bias] [relu])
// A,B,C row-major. Batched via z-dim with per-operand strides (0 = shared).
// Tile 64x64, BK=16, 256 threads, 4x4 per thread.
// ---------------------------------------------------------------------------
__global__ __launch_bounds__(256) void gemm_kernel(
    const float* __restrict__ A, int lda, long strideA,
    const float* __restrict__ B, int ldb, long strideB,
    float* __restrict__ C, int ldc, long strideC,
    const float* __restrict__ bias,
    int M, int N, int K, int flags)
{
  int bt = blockIdx.z;
  A += (long)bt * strideA;
  B += (long)bt * strideB;
  C += (long)bt * strideC;
  int m0 = blockIdx.x * 64, n0 = blockIdx.y * 64;

  __shared__ __align__(16) float As[16][68];  // padded: store pattern -> 2-way max
  __shared__ __align__(16) float Bs[16][64];

  int tid = threadIdx.x;
  int tx = tid & 15, ty = tid >> 4;

  float acc[4][4] = {};

  for (int k0 = 0; k0 < K; k0 += 16) {
    // A tile: 64 rows x 16 k (global reads coalesced over k)
#pragma unroll
    for (int l = 0; l < 4; ++l) {
      int idx = tid + l * 256;
      int m = idx >> 4, k = idx & 15;
      float v = 0.f;
      if (m0 + m < M && k0 + k < K) v = A[(long)(m0 + m) * lda + k0 + k];
      As[k][m] = v;
    }
    // B tile: 16 k x 64 n (fully coalesced)
#pragma unroll
    for (int l = 0; l < 4; ++l) {
      int idx = tid + l * 256;
      int k = idx >> 6, n = idx & 63;
      float v = 0.f;
      if (k0 + k < K && n0 + n < N) v = B[(long)(k0 + k) * ldb + n0 + n];
      Bs[k][n] = v;
    }
    __syncthreads();
#pragma unroll
    for (int k = 0; k < 16; ++k) {
      float4 a4 = *reinterpret_cast<const float4*>(&As[k][ty * 4]);
      float4 b4 = *reinterpret_cast<const float4*>(&Bs[k][tx * 4]);
      float a[4] = {a4.x, a4.y, a4.z, a4.w};
      float b[4] = {b4.x, b4.y, b4.z, b4.w};
#pragma unroll
      for (int i = 0; i < 4; ++i)
#pragma unroll
        for (int j = 0; j < 4; ++j)
          acc[i][j] += a[i] * b[j];
    }
    __syncthreads();
  }

#pragma unroll
  for (int i = 0; i < 4; ++i) {
    int m = m0 + ty * 4 + i;
    if (m >= M) continue;
#pragma unroll
    for (int j = 0; j < 4; ++j) {
      int n = n0 + tx * 4 + j;
      if (n >= N) continue;
      float v = acc[i][j];
      if (flags & GF_ACCUM) v += C[(long)m * ldc + n];
      if (flags & GF_BIAS)  v += bias[n];
      if (flags & GF_RELU)  v = fmaxf(v, 0.f);
      C[(long)m * ldc + n] = v;
    }
  }
}

// ---------------------------------------------------------------------------
// DataEmbedding: x_emb[b,t,n, 0:24]=ori@W_val+b, 24:48=tod_emb, 48:72=dow_emb,
//                72:152=node_emb
// ---------------------------------------------------------------------------
__global__ void embed_kernel(const float* __restrict__ ori,
                             const float* __restrict__ W_val,
                             const float* __restrict__ b_val,
                             const float* __restrict__ tod_emb,
                             const float* __restrict__ dow_emb,
                             const float* __restrict__ node_emb,
                             float* __restrict__ x_emb, int total)
{
  int idx = blockIdx.x * 256 + threadIdx.x;
  if (idx >= total) return;
  int c = idx % EMB;
  int r = idx / EMB;            // r = (b*T + t)*N + n
  int n = r % NN;
  float v;
  if (c < 24) {
    const float* x = ori + (long)r * 3;
    v = x[0] * W_val[c] + x[1] * W_val[24 + c] + x[2] * W_val[48 + c] + b_val[c];
  } else if (c < 48) {
    float f = ori[(long)r * 3 + 1];
    f = f - floorf(f);
    int tod = (int)(f * 288.f);
    tod = min(max(tod, 0), 287);
    v = tod_emb[tod * 24 + (c - 24)];
  } else if (c < 72) {
    float f = ori[(long)r * 3 + 2];
    f = f - floorf(f);
    int dow = (int)(f * 7.f);
    dow = min(max(dow, 0), 6);
    v = dow_emb[dow * 24 + (c - 48)];
  } else {
    v = node_emb[n * 80 + (c - 72)];
  }
  x_emb[idx] = v;
}

// x_embT[b,n,t,c] = x_emb[b,t,n,c]  (enumerate outputs -> coalesced writes)
__global__ void transpose_emb(const float* __restrict__ x_emb,
                              float* __restrict__ x_embT, int total)
{
  int idx = blockIdx.x * 256 + threadIdx.x;
  if (idx >= total) return;
  int c = idx % EMB;
  int r = idx / EMB;            // r = (b*N + n)*T + t
  int t = r % TT;
  int r2 = r / TT;
  int n = r2 % NN;
  int b = r2 / NN;
  x_embT[idx] = x_emb[(((long)(b * TT + t)) * NN + n) * EMB + c];
}

// c2[b,n,s,h] = coeff2[b,n,s,0]*W_ce[0,h] + coeff2[b,n,s,1]*W_ce[1,h] + b_ce[h]
__global__ void c2_kernel(const float* __restrict__ coeff2,
                          const float* __restrict__ W_ce,
                          const float* __restrict__ b_ce,
                          float* __restrict__ c2)
{
  int row = blockIdx.x;         // (b*N+n)*S + s
  int h = threadIdx.x;
  float a0 = coeff2[(long)row * 2];
  float a1 = coeff2[(long)row * 2 + 1];
  c2[(long)row * 64 + h] = a0 * W_ce[h] + a1 * W_ce[64 + h] + b_ce[h];
}

// Pack Wq|Wk|Wv -> [64,192] and biases -> [192]
__global__ void pack_qkv(const float* __restrict__ Wq, const float* __restrict__ Wk,
                         const float* __restrict__ Wv, const float* __restrict__ bq,
                         const float* __restrict__ bk, const float* __restrict__ bv,
                         float* __restrict__ Wqkv, float* __restrict__ bqkv)
{
  int idx = blockIdx.x * 256 + threadIdx.x;
  if (idx < 64 * 192) {
    int k = idx / 192, j = idx % 192;
    float v = (j < 64) ? Wq[k * 64 + j]
            : (j < 128) ? Wk[k * 64 + j - 64]
                        : Wv[k * 64 + j - 128];
    Wqkv[idx] = v;
  } else if (idx < 64 * 192 + 192) {
    int j = idx - 64 * 192;
    bqkv[j] = (j < 64) ? bq[j] : (j < 128) ? bk[j - 64] : bv[j - 128];
  }
}

// zt[(b*S+s)*N+n, h] = z[(b*N+n)*S+s, h]   (wave per output row)
__global__ __launch_bounds__(256) void transpose_z(const float* __restrict__ z,
                                                   float* __restrict__ zt)
{
  int row = blockIdx.x * 4 + (threadIdx.x >> 6);
  if (row >= BB * SS * NN) return;
  int lane = threadIdx.x & 63;
  int n = row % NN;
  int bs = row / NN;
  int s = bs % SS;
  int b = bs / SS;
  zt[(long)row * 64 + lane] = z[(((long)(b * NN + n)) * SS + s) * 64 + lane];
}

// ---------------------------------------------------------------------------
// Spatial MHSA: block per (b,s,head,chunk). K/V for the head staged transposed
// in LDS ([d][m] layout -> conflict-free inner reads). Wave per query row.
// ---------------------------------------------------------------------------
__global__ __launch_bounds__(256) void attn_kernel(const float* __restrict__ qkv,
                                                   float* __restrict__ o)
{
  int bsh = blockIdx.x;           // (b*S+s)*NH + head
  int chunk = blockIdx.y;         // 0..1
  int head = bsh & 3;
  long rowbase = (long)(bsh >> 2) * NN;

  __shared__ float Kt[16 * 308];
  __shared__ float Vt[16 * 308];
  __shared__ float Pl[4][308];

  int tid = threadIdx.x;
  const float* kbase = qkv + rowbase * 192 + 64 + head * 16;
  const float* vbase = qkv + rowbase * 192 + 128 + head * 16;
  for (int idx = tid; idx < NN * 16; idx += 256) {
    int m = idx >> 4, d = idx & 15;
    Kt[d * 308 + m] = kbase[(long)m * 192 + d];
    Vt[d * 308 + m] = vbase[(long)m * 192 + d];
  }
  __syncthreads();

  int wave = tid >> 6, lane = tid & 63;
  int rstart = chunk * 154;
  int rend = min(NN, rstart + 154);
  int iters = (rend - rstart + 3) >> 2;
  const float* qbase = qkv + rowbase * 192 + head * 16;

  for (int it = 0; it < iters; ++it) {
    int n = rstart + it * 4 + wave;
    bool active = (n < rend);
    if (active) {
      float q[16];
#pragma unroll
      for (int d = 0; d < 16; ++d) q[d] = qbase[(long)n * 192 + d];
      float mx = -1e30f, sc[5];
#pragma unroll
      for (int c = 0; c < 5; ++c) {
        int m = c * 64 + lane;
        float s = -1e30f;
        if (m < NN) {
          s = 0.f;
#pragma unroll
          for (int d = 0; d < 16; ++d) s += q[d] * Kt[d * 308 + m];
          s *= 0.25f;
        }
        sc[c] = s;
        mx = fmaxf(mx, s);
      }
      mx = wave_max(mx);
      float e[5];
      float sum = 0.f;
#pragma unroll
      for (int c = 0; c < 5; ++c) {
        int m = c * 64 + lane;
        e[c] = (m < NN) ? __expf(sc[c] - mx) : 0.f;
        sum += e[c];
      }
      sum = wave_sum(sum);
      float inv = 1.f / sum;
#pragma unroll
      for (int c = 0; c < 5; ++c) {
        int m = c * 64 + lane;
        if (m < NN) Pl[wave][m] = e[c] * inv;
      }
    }
    __syncthreads();
    if (active) {
      int mg = lane >> 4, d = lane & 15;
      float acc = 0.f;
      for (int mi = mg; mi < NN; mi += 4)
        acc += Pl[wave][mi] * Vt[d * 308 + mi];
      acc += __shfl_xor(acc, 16);
      acc += __shfl_xor(acc, 32);
      if (mg == 0) o[(rowbase + n) * 64 + head * 16 + d] = acc;
    }
    __syncthreads();
  }
}

// h1 = LN(zt + o2; ln1)  — wave per row
__global__ __launch_bounds__(256) void ln1_kernel(const float* __restrict__ zt,
                                                  const float* __restrict__ o2,
                                                  const float* __restrict__ g,
                                                  const float* __restrict__ b,
                                                  float* __restrict__ h1)
{
  int row = blockIdx.x * 4 + (threadIdx.x >> 6);
  if (row >= BB * SS * NN) return;
  int lane = threadIdx.x & 63;
  long p = (long)row * 64 + lane;
  float x = zt[p] + o2[p];
  float m = wave_sum(x) * (1.f / 64.f);
  float d = x - m;
  float v = wave_sum(d * d) * (1.f / 64.f);
  h1[p] = d * rsqrtf(v + 1e-5f) * g[lane] + b[lane];
}

// t = tanh(LN(h1+ff; ln2)); z[b,n,s,h] += t * x2s[iter][b,n,s,h]
// x2s recomputed on the fly: sum_s' c2[b,n,s',h]*W_tp2[s', s*11+iter] + b_tp2
__global__ __launch_bounds__(256) void ln2_update(const float* __restrict__ h1,
                                                  const float* __restrict__ ff,
                                                  const float* __restrict__ g2,
                                                  const float* __restrict__ b2,
                                                  const float* __restrict__ c2,
                                                  const float* __restrict__ W_tp2,
                                                  const float* __restrict__ b_tp2,
                                                  float* __restrict__ z, int iter)
{
  int row = blockIdx.x * 4 + (threadIdx.x >> 6);   // (b*S+s)*N + n
  if (row >= BB * SS * NN) return;
  int lane = threadIdx.x & 63;
  long p = (long)row * 64 + lane;
  float x = h1[p] + ff[p];
  float m = wave_sum(x) * (1.f / 64.f);
  float d = x - m;
  float v = wave_sum(d * d) * (1.f / 64.f);
  float t = tanhf(d * rsqrtf(v + 1e-5f) * g2[lane] + b2[lane]);

  int n = row % NN;
  int bs = row / NN;
  int s1 = bs % SS;
  int b = bs / SS;
  long bn = (long)b * NN + n;
  float acc = b_tp2[s1 * SS + iter];
#pragma unroll
  for (int s = 0; s < SS; ++s)
    acc += c2[(bn * SS + s) * 64 + lane] * W_tp2[s * (SS * SS) + s1 * SS + iter];

  long zi = (bn * SS + s1) * 64 + lane;
  z[zi] += t * acc;
}

// gp: out[b,o,n] = w_het * (sum_{t,h} g[b,t,n,h]*Wgo[t*H+h,o] + bgo[o])
__global__ __launch_bounds__(64) void gp_kernel(const float* __restrict__ g,
                                                const float* __restrict__ Wgo,
                                                const float* __restrict__ bgo,
                                                const float* __restrict__ w_het,
                                                float* __restrict__ out)
{
  int bn = blockIdx.x;
  int b = bn / NN, n = bn % NN;
  __shared__ float buf[TT * 64];
  for (int idx = threadIdx.x; idx < TT * 64; idx += 64) {
    int t = idx >> 6, h = idx & 63;
    buf[idx] = g[(((long)(b * TT + t)) * NN + n) * 64 + h];
  }
  __syncthreads();
  int o = threadIdx.x;
  if (o < 12) {
    float acc = bgo[o];
    for (int j = 0; j < TT * 64; ++j) acc += buf[j] * Wgo[j * 12 + o];
    out[((long)b * 12 + o) * NN + n] = w_het[0] * acc;
  }
}

// zT = LN(z[:,:,S-1,:]; lnf);  out[b,o,n] += w_acl*(zT@W_end + b_end)
__global__ __launch_bounds__(64) void final_acl(const float* __restrict__ z,
                                                const float* __restrict__ lnf_g,
                                                const float* __restrict__ lnf_b,
                                                const float* __restrict__ W_end,
                                                const float* __restrict__ b_end,
                                                const float* __restrict__ w_acl,
                                                float* __restrict__ out)
{
  int bn = blockIdx.x;          // b*N + n
  int lane = threadIdx.x;
  int b = bn / NN, n = bn % NN;
  float x = z[((long)bn * SS + (SS - 1)) * 64 + lane];
  float m = wave_sum(x) * (1.f / 64.f);
  float d = x - m;
  float v = wave_sum(d * d) * (1.f / 64.f);
  float zT = d * rsqrtf(v + 1e-5f) * lnf_g[lane] + lnf_b[lane];
  float wa = w_acl[0];
  for (int o = 0; o < 12; ++o) {
    float p = zT * W_end[lane * 12 + o];
    p = wave_sum(p);
    if (lane == 0) {
      long oi = ((long)b * 12 + o) * NN + n;
      out[oi] = out[oi] + wa * (p + b_end[o]);
    }
  }
}

// ---------------------------------------------------------------------------
extern "C" void kernel_launch(void* const* d_in, const int* in_sizes, int n_in,
                              void* d_out, int out_size, void* d_ws, size_t ws_size,
                              hipStream_t stream)
{
  (void)in_sizes; (void)n_in; (void)out_size; (void)ws_size;

  const float* ori_x    = (const float*)d_in[0];
  const float* coeff2   = (const float*)d_in[2];
  const float* W_val    = (const float*)d_in[5];
  const float* b_val    = (const float*)d_in[6];
  const float* tod_emb  = (const float*)d_in[7];
  const float* dow_emb  = (const float*)d_in[8];
  const float* node_emb = (const float*)d_in[9];
  const float* W_in     = (const float*)d_in[10];
  const float* b_in     = (const float*)d_in[11];
  const float* W_ce     = (const float*)d_in[12];
  const float* b_ce     = (const float*)d_in[13];
  const float* W_tp2    = (const float*)d_in[14];
  const float* b_tp2    = (const float*)d_in[15];
  const float* Wq = (const float*)d_in[20];
  const float* Wk = (const float*)d_in[21];
  const float* Wv = (const float*)d_in[22];
  const float* Wo = (const float*)d_in[23];
  const float* bq = (const float*)d_in[24];
  const float* bk = (const float*)d_in[25];
  const float* bv = (const float*)d_in[26];
  const float* bo = (const float*)d_in[27];
  const float* ln1_g = (const float*)d_in[28];
  const float* ln1_b = (const float*)d_in[29];
  const float* Wf1   = (const float*)d_in[30];
  const float* bf1   = (const float*)d_in[31];
  const float* Wf2   = (const float*)d_in[32];
  const float* bf2   = (const float*)d_in[33];
  const float* ln2_g = (const float*)d_in[34];
  const float* ln2_b = (const float*)d_in[35];
  const float* lnf_g = (const float*)d_in[36];
  const float* lnf_b = (const float*)d_in[37];
  const float* W_end = (const float*)d_in[38];
  const float* b_end = (const float*)d_in[39];
  const float* w_acl = (const float*)d_in[40];
  const float* w_het = (const float*)d_in[41];
  const float* adj     = (const float*)d_in[42];
  const float* adj_sem = (const float*)d_in[43];
  const float* Wg1 = (const float*)d_in[44];
  const float* Wg2 = (const float*)d_in[45];
  const float* bg  = (const float*)d_in[46];
  const float* Wgo = (const float*)d_in[47];
  const float* bgo = (const float*)d_in[48];
  float* out = (float*)d_out;
  float* ws  = (float*)d_ws;

  const int ROWS_TN = BB * TT * NN;   // 14736
  const int ROWS_SN = BB * SS * NN;   // 13508
  const int ROWS_BN = BB * NN;        // 1228

  // ---- workspace layout (floats); total ~11.25M floats = ~45 MB ----
  float* Z    = ws;                      // 864512  z state [B,N,S,H]
  float* C2   = ws + 864512;             // 864512  coeff2@W_ce [B,N,S,H]
  float* WQKV = ws + 1729024;            // 12288
  float* BQKV = ws + 1741312;            // 192
  float* POOL = ws + 1741504;
  // phase 1
  float* XEMB  = POOL;                   // 2239872 [B,T,N,152]
  float* XEMBT = POOL + 2239872;         // 2239872 [B,N,T,152]
  float* XG1   = POOL + 4479744;         // 943104  [B,T,N,64]
  float* XG2   = POOL + 5422848;         // 943104
  float* G     = POOL + 6365952;         // 943104
  // phase 2 (overlays phase 1)
  float* ZT  = POOL;                     // 864512  [B,S,N,H]
  float* QKV = POOL + 864512;            // 2593536 [B,S,N,192]
  float* O   = POOL + 3458048;           // 864512
  float* O2  = POOL + 4322560;           // 864512  (o@Wo, later reused as ff)
  float* H1  = POOL + 5187072;           // 864512
  float* FFH = POOL + 6051584;           // 3458048 [B,S,N,256]

  // ---- phase 1: embedding, x_in, c2, GCN branch ----
  embed_kernel<<<dim3(8750), dim3(256), 0, stream>>>(
      ori_x, W_val, b_val, tod_emb, dow_emb, node_emb, XEMB, ROWS_TN * EMB);
  transpose_emb<<<dim3(8750), dim3(256), 0, stream>>>(XEMB, XEMBT, ROWS_TN * EMB);
  // x_in -> Z : [1228,1824]@[1824,704]
  gemm_kernel<<<dim3(20, 11, 1), dim3(256), 0, stream>>>(
      XEMBT, TT * EMB, 0L, W_in, SS * HH, 0L, Z, SS * HH, 0L, b_in,
      ROWS_BN, SS * HH, TT * EMB, GF_BIAS);
  c2_kernel<<<dim3(ROWS_BN * SS), dim3(64), 0, stream>>>(coeff2, W_ce, b_ce, C2);
  // GCN: xg = x_emb @ Wg (reassociated), then batched adj aggregation
  gemm_kernel<<<dim3(231, 1, 1), dim3(256), 0, stream>>>(
      XEMB, EMB, 0L, Wg1, HH, 0L, XG1, HH, 0L, nullptr, ROWS_TN, HH, EMB, 0);
  gemm_kernel<<<dim3(231, 1, 1), dim3(256), 0, stream>>>(
      XEMB, EMB, 0L, Wg2, HH, 0L, XG2, HH, 0L, nullptr, ROWS_TN, HH, EMB, 0);
  gemm_kernel<<<dim3(5, 1, 48), dim3(256), 0, stream>>>(
      adj, NN, 0L, XG1, HH, (long)NN * HH, G, HH, (long)NN * HH, nullptr,
      NN, HH, NN, 0);
  gemm_kernel<<<dim3(5, 1, 48), dim3(256), 0, stream>>>(
      adj_sem, NN, 0L, XG2, HH, (long)NN * HH, G, HH, (long)NN * HH, bg,
      NN, HH, NN, GF_ACCUM | GF_BIAS | GF_RELU);
  gp_kernel<<<dim3(ROWS_BN), dim3(64), 0, stream>>>(G, Wgo, bgo, w_het, out);
  pack_qkv<<<dim3(49), dim3(256), 0, stream>>>(Wq, Wk, Wv, bq, bk, bv, WQKV, BQKV);

  // ---- phase 2: Euler scan, 11 steps ----
  for (int i = 0; i < SS; ++i) {
    transpose_z<<<dim3(3377), dim3(256), 0, stream>>>(Z, ZT);
    gemm_kernel<<<dim3(212, 3, 1), dim3(256), 0, stream>>>(
        ZT, HH, 0L, WQKV, 192, 0L, QKV, 192, 0L, BQKV,
        ROWS_SN, 192, HH, GF_BIAS);
    attn_kernel<<<dim3(BB * SS * NHH, 2), dim3(256), 0, stream>>>(QKV, O);
    gemm_kernel<<<dim3(212, 1, 1), dim3(256), 0, stream>>>(
        O, HH, 0L, Wo, HH, 0L, O2, HH, 0L, bo, ROWS_SN, HH, HH, GF_BIAS);
    ln1_kernel<<<dim3(3377), dim3(256), 0, stream>>>(ZT, O2, ln1_g, ln1_b, H1);
    gemm_kernel<<<dim3(212, 4, 1), dim3(256), 0, stream>>>(
        H1, HH, 0L, Wf1, 256, 0L, FFH, 256, 0L, bf1,
        ROWS_SN, 256, HH, GF_BIAS | GF_RELU);
    gemm_kernel<<<dim3(212, 1, 1), dim3(256), 0, stream>>>(
        FFH, 256, 0L, Wf2, HH, 0L, O2, HH, 0L, bf2, ROWS_SN, HH, 256, GF_BIAS);
    ln2_update<<<dim3(3377), dim3(256), 0, stream>>>(
        H1, O2, ln2_g, ln2_b, C2, W_tp2, b_tp2, Z, i);
  }

  // ---- epilogue: zT layernorm + end_conv, added onto het part ----
  final_acl<<<dim3(ROWS_BN), dim3(64), 0, stream>>>(
      Z, lnf_g, lnf_b, W_end, b_end, w_acl, out);
}

// Round 2
// 3458.398 us; speedup vs baseline: 1.0838x; 1.0838x over previous
//
#include <hip/hip_runtime.h>
#include <math.h>

// Problem dims
#define BB   4
#define TT   12
#define NN   307
#define SS   11
#define HH   64
#define NHH  4
#define DHH  16
#define EMB  152
#define ROWS 13508          // B*S*N

// GEMM epilogue flags
#define GF_BIAS  1
#define GF_RELU  2
#define GF_ACCUM 4

__device__ __forceinline__ float wave_sum(float v) {
#pragma unroll
  for (int off = 32; off; off >>= 1) v += __shfl_xor(v, off);
  return v;
}
__device__ __forceinline__ float wave_max(float v) {
#pragma unroll
  for (int off = 32; off; off >>= 1) v = fmaxf(v, __shfl_xor(v, off));
  return v;
}
// broadcast lane k of v to all lanes (k wave-uniform)
__device__ __forceinline__ float rl(float v, int k) {
  return __int_as_float(__builtin_amdgcn_readlane(__float_as_int(v), k));
}
// row r in (b,s,n) order -> flat offset of the 64-float row in Z ([b,n,s,h])
__device__ __forceinline__ long zoff_of_row(int r, int* s_out, long* bn_out) {
  int b = r / (SS * NN);
  int rem = r - b * (SS * NN);
  int s = rem / NN;
  int n = rem - s * NN;
  long bn = (long)b * NN + n;
  if (s_out) *s_out = s;
  if (bn_out) *bn_out = bn;
  return (bn * SS + s) * 64;
}

// ---------------------------------------------------------------------------
// Generic fp32 tiled GEMM (kept for phase-1 mid-size matmuls)
// ---------------------------------------------------------------------------
__global__ __launch_bounds__(256) void gemm_kernel(
    const float* __restrict__ A, int lda, long strideA,
    const float* __restrict__ B, int ldb, long strideB,
    float* __restrict__ C, int ldc, long strideC,
    const float* __restrict__ bias,
    int M, int N, int K, int flags)
{
  int bt = blockIdx.z;
  A += (long)bt * strideA;
  B += (long)bt * strideB;
  C += (long)bt * strideC;
  int m0 = blockIdx.x * 64, n0 = blockIdx.y * 64;

  __shared__ __align__(16) float As[16][68];
  __shared__ __align__(16) float Bs[16][64];

  int tid = threadIdx.x;
  int tx = tid & 15, ty = tid >> 4;
  float acc[4][4] = {};

  for (int k0 = 0; k0 < K; k0 += 16) {
#pragma unroll
    for (int l = 0; l < 4; ++l) {
      int idx = tid + l * 256;
      int m = idx >> 4, k = idx & 15;
      float v = 0.f;
      if (m0 + m < M && k0 + k < K) v = A[(long)(m0 + m) * lda + k0 + k];
      As[k][m] = v;
    }
#pragma unroll
    for (int l = 0; l < 4; ++l) {
      int idx = tid + l * 256;
      int k = idx >> 6, n = idx & 63;
      float v = 0.f;
      if (k0 + k < K && n0 + n < N) v = B[(long)(k0 + k) * ldb + n0 + n];
      Bs[k][n] = v;
    }
    __syncthreads();
#pragma unroll
    for (int k = 0; k < 16; ++k) {
      float4 a4 = *reinterpret_cast<const float4*>(&As[k][ty * 4]);
      float4 b4 = *reinterpret_cast<const float4*>(&Bs[k][tx * 4]);
      float a[4] = {a4.x, a4.y, a4.z, a4.w};
      float b[4] = {b4.x, b4.y, b4.z, b4.w};
#pragma unroll
      for (int i = 0; i < 4; ++i)
#pragma unroll
        for (int j = 0; j < 4; ++j)
          acc[i][j] += a[i] * b[j];
    }
    __syncthreads();
  }

#pragma unroll
  for (int i = 0; i < 4; ++i) {
    int m = m0 + ty * 4 + i;
    if (m >= M) continue;
#pragma unroll
    for (int j = 0; j < 4; ++j) {
      int n = n0 + tx * 4 + j;
      if (n >= N) continue;
      float v = acc[i][j];
      if (flags & GF_ACCUM) v += C[(long)m * ldc + n];
      if (flags & GF_BIAS)  v += bias[n];
      if (flags & GF_RELU)  v = fmaxf(v, 0.f);
      C[(long)m * ldc + n] = v;
    }
  }
}

// Split-K GEMM: each z-block handles KS of K, atomicAdd into pre-initialized C.
__global__ __launch_bounds__(256) void gemm_splitk(
    const float* __restrict__ A, int lda,
    const float* __restrict__ B, int ldb,
    float* __restrict__ C, int ldc,
    int M, int N, int K, int KS)
{
  int kstart = blockIdx.z * KS;
  int kend = min(K, kstart + KS);
  int m0 = blockIdx.x * 64, n0 = blockIdx.y * 64;

  __shared__ __align__(16) float As[16][68];
  __shared__ __align__(16) float Bs[16][64];

  int tid = threadIdx.x;
  int tx = tid & 15, ty = tid >> 4;
  float acc[4][4] = {};

  for (int k0 = kstart; k0 < kend; k0 += 16) {
#pragma unroll
    for (int l = 0; l < 4; ++l) {
      int idx = tid + l * 256;
      int m = idx >> 4, k = idx & 15;
      float v = 0.f;
      if (m0 + m < M && k0 + k < kend) v = A[(long)(m0 + m) * lda + k0 + k];
      As[k][m] = v;
    }
#pragma unroll
    for (int l = 0; l < 4; ++l) {
      int idx = tid + l * 256;
      int k = idx >> 6, n = idx & 63;
      float v = 0.f;
      if (k0 + k < kend && n0 + n < N) v = B[(long)(k0 + k) * ldb + n0 + n];
      Bs[k][n] = v;
    }
    __syncthreads();
#pragma unroll
    for (int k = 0; k < 16; ++k) {
      float4 a4 = *reinterpret_cast<const float4*>(&As[k][ty * 4]);
      float4 b4 = *reinterpret_cast<const float4*>(&Bs[k][tx * 4]);
      float a[4] = {a4.x, a4.y, a4.z, a4.w};
      float b[4] = {b4.x, b4.y, b4.z, b4.w};
#pragma unroll
      for (int i = 0; i < 4; ++i)
#pragma unroll
        for (int j = 0; j < 4; ++j)
          acc[i][j] += a[i] * b[j];
    }
    __syncthreads();
  }

#pragma unroll
  for (int i = 0; i < 4; ++i) {
    int m = m0 + ty * 4 + i;
    if (m >= M) continue;
#pragma unroll
    for (int j = 0; j < 4; ++j) {
      int n = n0 + tx * 4 + j;
      if (n >= N) continue;
      atomicAdd(&C[(long)m * ldc + n], acc[i][j]);
    }
  }
}

// Z[r, c] = b_in[c]   (bias-init for split-K accumulation)
__global__ void zinit_kernel(float* __restrict__ Z, const float* __restrict__ b_in,
                             int total)
{
  int idx = blockIdx.x * 256 + threadIdx.x;
  if (idx < total) Z[idx] = b_in[idx % (SS * HH)];
}

// ---------------------------------------------------------------------------
// DataEmbedding
// ---------------------------------------------------------------------------
__global__ void embed_kernel(const float* __restrict__ ori,
                             const float* __restrict__ W_val,
                             const float* __restrict__ b_val,
                             const float* __restrict__ tod_emb,
                             const float* __restrict__ dow_emb,
                             const float* __restrict__ node_emb,
                             float* __restrict__ x_emb, int total)
{
  int idx = blockIdx.x * 256 + threadIdx.x;
  if (idx >= total) return;
  int c = idx % EMB;
  int r = idx / EMB;            // (b*T + t)*N + n
  int n = r % NN;
  float v;
  if (c < 24) {
    const float* x = ori + (long)r * 3;
    v = x[0] * W_val[c] + x[1] * W_val[24 + c] + x[2] * W_val[48 + c] + b_val[c];
  } else if (c < 48) {
    float f = ori[(long)r * 3 + 1];
    f = f - floorf(f);
    int tod = (int)(f * 288.f);
    tod = min(max(tod, 0), 287);
    v = tod_emb[tod * 24 + (c - 24)];
  } else if (c < 72) {
    float f = ori[(long)r * 3 + 2];
    f = f - floorf(f);
    int dow = (int)(f * 7.f);
    dow = min(max(dow, 0), 6);
    v = dow_emb[dow * 24 + (c - 48)];
  } else {
    v = node_emb[n * 80 + (c - 72)];
  }
  x_emb[idx] = v;
}

__global__ void transpose_emb(const float* __restrict__ x_emb,
                              float* __restrict__ x_embT, int total)
{
  int idx = blockIdx.x * 256 + threadIdx.x;
  if (idx >= total) return;
  int c = idx % EMB;
  int r = idx / EMB;            // (b*N + n)*T + t
  int t = r % TT;
  int r2 = r / TT;
  int n = r2 % NN;
  int b = r2 / NN;
  x_embT[idx] = x_emb[(((long)(b * TT + t)) * NN + n) * EMB + c];
}

__global__ void c2_kernel(const float* __restrict__ coeff2,
                          const float* __restrict__ W_ce,
                          const float* __restrict__ b_ce,
                          float* __restrict__ c2)
{
  int row = blockIdx.x;         // (b*N+n)*S + s
  int h = threadIdx.x;
  float a0 = coeff2[(long)row * 2];
  float a1 = coeff2[(long)row * 2 + 1];
  c2[(long)row * 64 + h] = a0 * W_ce[h] + a1 * W_ce[64 + h] + b_ce[h];
}

// Pack Wg1|Wg2 -> [152,128]
__global__ void pack_wg(const float* __restrict__ Wg1, const float* __restrict__ Wg2,
                        float* __restrict__ WGP)
{
  int idx = blockIdx.x * 256 + threadIdx.x;
  if (idx >= EMB * 128) return;
  int k = idx >> 7, c = idx & 127;
  WGP[idx] = (c < 64) ? Wg1[k * 64 + c] : Wg2[k * 64 + c - 64];
}

// ---------------------------------------------------------------------------
// Scan-step fused kernels ("row-wave" GEMMs: lane=output col, row operand in
// one VGPR/lane, broadcast via v_readlane; weights staged in LDS [k][c])
// ---------------------------------------------------------------------------

// K_A: QKV projection from Z (with (b,s,n)->(b,n,s) gather). 32 rows/block.
__global__ __launch_bounds__(256) void qkv_rowwave(
    const float* __restrict__ Z,
    const float* __restrict__ Wq, const float* __restrict__ Wk,
    const float* __restrict__ Wv, const float* __restrict__ bq,
    const float* __restrict__ bk, const float* __restrict__ bv,
    float* __restrict__ qkv)
{
  __shared__ __align__(16) float Wls[64 * 192];
  int tid = threadIdx.x;
  for (int i = tid; i < 1024; i += 256) {
    int k = i >> 4, c4 = (i & 15) * 4;
    *(float4*)&Wls[k * 192 + c4]       = ((const float4*)Wq)[i];
    *(float4*)&Wls[k * 192 + 64 + c4]  = ((const float4*)Wk)[i];
    *(float4*)&Wls[k * 192 + 128 + c4] = ((const float4*)Wv)[i];
  }
  __syncthreads();

  int wave = tid >> 6, lane = tid & 63;
  float bqv = bq[lane], bkv = bk[lane], bvv = bv[lane];
  int rbase = blockIdx.x * 32 + wave * 8;

  for (int p = 0; p < 2; ++p) {
    int r0 = rbase + p * 4;
    float zr[4], aq[4], ak[4], av[4];
    bool act[4];
#pragma unroll
    for (int j = 0; j < 4; ++j) {
      int r = r0 + j;
      act[j] = (r < ROWS);
      zr[j] = act[j] ? Z[zoff_of_row(r, nullptr, nullptr) + lane] : 0.f;
      aq[j] = bqv; ak[j] = bkv; av[j] = bvv;
    }
#pragma unroll 8
    for (int k = 0; k < 64; ++k) {
      float w0 = Wls[k * 192 + lane];
      float w1 = Wls[k * 192 + 64 + lane];
      float w2 = Wls[k * 192 + 128 + lane];
#pragma unroll
      for (int j = 0; j < 4; ++j) {
        float a = rl(zr[j], k);
        aq[j] += a * w0; ak[j] += a * w1; av[j] += a * w2;
      }
    }
#pragma unroll
    for (int j = 0; j < 4; ++j) {
      if (!act[j]) continue;
      long base = (long)(r0 + j) * 192;
      qkv[base + lane] = aq[j];
      qkv[base + 64 + lane] = ak[j];
      qkv[base + 128 + lane] = av[j];
    }
  }
}

// K_B: spatial MHSA (unchanged structure)
__global__ __launch_bounds__(256) void attn_kernel(const float* __restrict__ qkv,
                                                   float* __restrict__ o)
{
  int bsh = blockIdx.x;           // (b*S+s)*NH + head
  int chunk = blockIdx.y;         // 0..1
  int head = bsh & 3;
  long rowbase = (long)(bsh >> 2) * NN;

  __shared__ float Kt[16 * 308];
  __shared__ float Vt[16 * 308];
  __shared__ float Pl[4][308];

  int tid = threadIdx.x;
  const float* kbase = qkv + rowbase * 192 + 64 + head * 16;
  const float* vbase = qkv + rowbase * 192 + 128 + head * 16;
  for (int idx = tid; idx < NN * 16; idx += 256) {
    int m = idx >> 4, d = idx & 15;
    Kt[d * 308 + m] = kbase[(long)m * 192 + d];
    Vt[d * 308 + m] = vbase[(long)m * 192 + d];
  }
  __syncthreads();

  int wave = tid >> 6, lane = tid & 63;
  int rstart = chunk * 154;
  int rend = min(NN, rstart + 154);
  int iters = (rend - rstart + 3) >> 2;
  const float* qbase = qkv + rowbase * 192 + head * 16;

  for (int it = 0; it < iters; ++it) {
    int n = rstart + it * 4 + wave;
    bool active = (n < rend);
    if (active) {
      float q[16];
#pragma unroll
      for (int d = 0; d < 16; ++d) q[d] = qbase[(long)n * 192 + d];
      float mx = -1e30f, sc[5];
#pragma unroll
      for (int c = 0; c < 5; ++c) {
        int m = c * 64 + lane;
        float s = -1e30f;
        if (m < NN) {
          s = 0.f;
#pragma unroll
          for (int d = 0; d < 16; ++d) s += q[d] * Kt[d * 308 + m];
          s *= 0.25f;
        }
        sc[c] = s;
        mx = fmaxf(mx, s);
      }
      mx = wave_max(mx);
      float e[5];
      float sum = 0.f;
#pragma unroll
      for (int c = 0; c < 5; ++c) {
        int m = c * 64 + lane;
        e[c] = (m < NN) ? __expf(sc[c] - mx) : 0.f;
        sum += e[c];
      }
      sum = wave_sum(sum);
      float inv = 1.f / sum;
#pragma unroll
      for (int c = 0; c < 5; ++c) {
        int m = c * 64 + lane;
        if (m < NN) Pl[wave][m] = e[c] * inv;
      }
    }
    __syncthreads();
    if (active) {
      int mg = lane >> 4, d = lane & 15;
      float acc = 0.f;
      for (int mi = mg; mi < NN; mi += 4)
        acc += Pl[wave][mi] * Vt[d * 308 + mi];
      acc += __shfl_xor(acc, 16);
      acc += __shfl_xor(acc, 32);
      if (mg == 0) o[(rowbase + n) * 64 + head * 16 + d] = acc;
    }
    __syncthreads();
  }
}

// K_C: o2 = O@Wo + bo; h1 = LN(z + o2; ln1). 32 rows/block.
__global__ __launch_bounds__(256) void wo_ln1(
    const float* __restrict__ O, const float* __restrict__ Z,
    const float* __restrict__ Wo, const float* __restrict__ bo,
    const float* __restrict__ g, const float* __restrict__ b,
    float* __restrict__ h1)
{
  __shared__ __align__(16) float Ws[64 * 64];
  int tid = threadIdx.x;
  for (int i = tid; i < 1024; i += 256)
    *(float4*)&Ws[i * 4] = ((const float4*)Wo)[i];
  __syncthreads();

  int wave = tid >> 6, lane = tid & 63;
  float bov = bo[lane], gv = g[lane], bv = b[lane];
  int rbase = blockIdx.x * 32 + wave * 8;

  for (int p = 0; p < 2; ++p) {
    int r0 = rbase + p * 4;
    float orr[4], zr[4], acc[4];
    bool act[4];
#pragma unroll
    for (int j = 0; j < 4; ++j) {
      int r = r0 + j;
      act[j] = (r < ROWS);
      orr[j] = act[j] ? O[(long)r * 64 + lane] : 0.f;
      zr[j]  = act[j] ? Z[zoff_of_row(r, nullptr, nullptr) + lane] : 0.f;
      acc[j] = 0.f;
    }
#pragma unroll 8
    for (int k = 0; k < 64; ++k) {
      float w = Ws[k * 64 + lane];
#pragma unroll
      for (int j = 0; j < 4; ++j) acc[j] += rl(orr[j], k) * w;
    }
#pragma unroll
    for (int j = 0; j < 4; ++j) {
      if (!act[j]) continue;
      float x = zr[j] + acc[j] + bov;
      float m = wave_sum(x) * (1.f / 64.f);
      float d = x - m;
      float v = wave_sum(d * d) * (1.f / 64.f);
      h1[(long)(r0 + j) * 64 + lane] = d * rsqrtf(v + 1e-5f) * gv + bv;
    }
  }
}

// K_D: ff = relu(h1@Wf1+bf1)@Wf2+bf2 (4 chunks of 64 hidden through LDS);
//      t = tanh(LN(h1+ff; ln2)); Z += t * x2s[iter] (x2s recomputed from C2).
__global__ __launch_bounds__(256) void ffn_ln2(
    const float* __restrict__ H1, const float* __restrict__ C2,
    const float* __restrict__ Wf1, const float* __restrict__ bf1,
    const float* __restrict__ Wf2, const float* __restrict__ bf2,
    const float* __restrict__ g2, const float* __restrict__ b2,
    const float* __restrict__ W_tp2, const float* __restrict__ b_tp2,
    float* __restrict__ Z, int iter)
{
  __shared__ __align__(16) float W1s[64 * 64];
  __shared__ __align__(16) float W2s[64 * 64];
  int tid = threadIdx.x;
  int wave = tid >> 6, lane = tid & 63;
  int rbase = blockIdx.x * 32 + wave * 8;

  float h1r[8], ff[8];
  bool act[8];
#pragma unroll
  for (int j = 0; j < 8; ++j) {
    int r = rbase + j;
    act[j] = (r < ROWS);
    h1r[j] = act[j] ? H1[(long)r * 64 + lane] : 0.f;
    ff[j] = 0.f;
  }
  float g2v = g2[lane], b2v = b2[lane], bf2v = bf2[lane];

  for (int ch = 0; ch < 4; ++ch) {
    __syncthreads();
    for (int i = tid; i < 1024; i += 256) {
      int k = i >> 4, c4 = (i & 15) * 4;
      *(float4*)&W1s[k * 64 + c4] =
          *(const float4*)(Wf1 + (long)k * 256 + ch * 64 + c4);
      *(float4*)&W2s[k * 64 + c4] =
          *(const float4*)(Wf2 + (long)(ch * 64 + k) * 64 + c4);
    }
    __syncthreads();
    float bf1v = bf1[ch * 64 + lane];
#pragma unroll
    for (int jp = 0; jp < 4; ++jp) {
      int j0 = jp * 2, j1 = jp * 2 + 1;
      float h0 = bf1v, h1v = bf1v;
#pragma unroll 8
      for (int k = 0; k < 64; ++k) {
        float w = W1s[k * 64 + lane];
        h0  += rl(h1r[j0], k) * w;
        h1v += rl(h1r[j1], k) * w;
      }
      h0 = fmaxf(h0, 0.f);
      h1v = fmaxf(h1v, 0.f);
#pragma unroll 8
      for (int k = 0; k < 64; ++k) {
        float w = W2s[k * 64 + lane];
        ff[j0] += rl(h0, k) * w;
        ff[j1] += rl(h1v, k) * w;
      }
    }
  }

#pragma unroll
  for (int j = 0; j < 8; ++j) {
    if (!act[j]) continue;
    int r = rbase + j;
    float x = h1r[j] + ff[j] + bf2v;
    float m = wave_sum(x) * (1.f / 64.f);
    float d = x - m;
    float v = wave_sum(d * d) * (1.f / 64.f);
    float t = tanhf(d * rsqrtf(v + 1e-5f) * g2v + b2v);

    int s1; long bn;
    long zo = zoff_of_row(r, &s1, &bn);
    float acc = b_tp2[s1 * SS + iter];
#pragma unroll
    for (int s = 0; s < SS; ++s)
      acc += C2[(bn * SS + s) * 64 + lane] * W_tp2[s * (SS * SS) + s1 * SS + iter];
    Z[zo + lane] += t * acc;
  }
}

// gp: out[b,o,n] = w_het * (sum_{t,h} g[b,t,n,h]*Wgo[t*H+h,o] + bgo[o])
__global__ __launch_bounds__(64) void gp_kernel(const float* __restrict__ g,
                                                const float* __restrict__ Wgo,
                                                const float* __restrict__ bgo,
                                                const float* __restrict__ w_het,
                                                float* __restrict__ out)
{
  int bn = blockIdx.x;
  int b = bn / NN, n = bn % NN;
  __shared__ float buf[TT * 64];
  for (int idx = threadIdx.x; idx < TT * 64; idx += 64) {
    int t = idx >> 6, h = idx & 63;
    buf[idx] = g[(((long)(b * TT + t)) * NN + n) * 64 + h];
  }
  __syncthreads();
  int o = threadIdx.x;
  if (o < 12) {
    float acc = bgo[o];
    for (int j = 0; j < TT * 64; ++j) acc += buf[j] * Wgo[j * 12 + o];
    out[((long)b * 12 + o) * NN + n] = w_het[0] * acc;
  }
}

// zT = LN(z[:,:,S-1,:]; lnf);  out[b,o,n] += w_acl*(zT@W_end + b_end)
__global__ __launch_bounds__(64) void final_acl(const float* __restrict__ z,
                                                const float* __restrict__ lnf_g,
                                                const float* __restrict__ lnf_b,
                                                const float* __restrict__ W_end,
                                                const float* __restrict__ b_end,
                                                const float* __restrict__ w_acl,
                                                float* __restrict__ out)
{
  int bn = blockIdx.x;          // b*N + n
  int lane = threadIdx.x;
  int b = bn / NN, n = bn % NN;
  float x = z[((long)bn * SS + (SS - 1)) * 64 + lane];
  float m = wave_sum(x) * (1.f / 64.f);
  float d = x - m;
  float v = wave_sum(d * d) * (1.f / 64.f);
  float zT = d * rsqrtf(v + 1e-5f) * lnf_g[lane] + lnf_b[lane];
  float wa = w_acl[0];
  for (int o = 0; o < 12; ++o) {
    float p = zT * W_end[lane * 12 + o];
    p = wave_sum(p);
    if (lane == 0) {
      long oi = ((long)b * 12 + o) * NN + n;
      out[oi] = out[oi] + wa * (p + b_end[o]);
    }
  }
}

// ---------------------------------------------------------------------------
extern "C" void kernel_launch(void* const* d_in, const int* in_sizes, int n_in,
                              void* d_out, int out_size, void* d_ws, size_t ws_size,
                              hipStream_t stream)
{
  (void)in_sizes; (void)n_in; (void)out_size; (void)ws_size;

  const float* ori_x    = (const float*)d_in[0];
  const float* coeff2   = (const float*)d_in[2];
  const float* W_val    = (const float*)d_in[5];
  const float* b_val    = (const float*)d_in[6];
  const float* tod_emb  = (const float*)d_in[7];
  const float* dow_emb  = (const float*)d_in[8];
  const float* node_emb = (const float*)d_in[9];
  const float* W_in     = (const float*)d_in[10];
  const float* b_in     = (const float*)d_in[11];
  const float* W_ce     = (const float*)d_in[12];
  const float* b_ce     = (const float*)d_in[13];
  const float* W_tp2    = (const float*)d_in[14];
  const float* b_tp2    = (const float*)d_in[15];
  const float* Wq = (const float*)d_in[20];
  const float* Wk = (const float*)d_in[21];
  const float* Wv = (const float*)d_in[22];
  const float* Wo = (const float*)d_in[23];
  const float* bq = (const float*)d_in[24];
  const float* bk = (const float*)d_in[25];
  const float* bv = (const float*)d_in[26];
  const float* bo = (const float*)d_in[27];
  const float* ln1_g = (const float*)d_in[28];
  const float* ln1_b = (const float*)d_in[29];
  const float* Wf1   = (const float*)d_in[30];
  const float* bf1   = (const float*)d_in[31];
  const float* Wf2   = (const float*)d_in[32];
  const float* bf2   = (const float*)d_in[33];
  const float* ln2_g = (const float*)d_in[34];
  const float* ln2_b = (const float*)d_in[35];
  const float* lnf_g = (const float*)d_in[36];
  const float* lnf_b = (const float*)d_in[37];
  const float* W_end = (const float*)d_in[38];
  const float* b_end = (const float*)d_in[39];
  const float* w_acl = (const float*)d_in[40];
  const float* w_het = (const float*)d_in[41];
  const float* adj     = (const float*)d_in[42];
  const float* adj_sem = (const float*)d_in[43];
  const float* Wg1 = (const float*)d_in[44];
  const float* Wg2 = (const float*)d_in[45];
  const float* bg  = (const float*)d_in[46];
  const float* Wgo = (const float*)d_in[47];
  const float* bgo = (const float*)d_in[48];
  float* out = (float*)d_out;
  float* ws  = (float*)d_ws;

  const int ROWS_TN = BB * TT * NN;   // 14736
  const int ROWS_BN = BB * NN;        // 1228

  // ---- workspace layout (floats) ----
  float* Z    = ws;                      // 864512  z state [B,N,S,H]
  float* C2   = ws + 864512;             // 864512
  float* POOL = ws + 1729024;
  // phase 1
  float* XEMB  = POOL;                   // 2239872 [B,T,N,152]
  float* XEMBT = POOL + 2239872;         // 2239872 [B,N,T,152]
  float* XGP   = POOL + 4479744;         // 1886208 [B,T,N,128]
  float* G     = POOL + 6365952;         // 943104  [B,T,N,64]
  float* WGP   = POOL + 7309056;         // 19456
  // phase 2 (overlays phase 1)
  float* QKV = POOL;                     // 2593536 [rows,192]
  float* O   = POOL + 2593536;           // 864512
  float* H1  = POOL + 3458048;           // 864512

  // ---- phase 1 ----
  embed_kernel<<<dim3(8750), dim3(256), 0, stream>>>(
      ori_x, W_val, b_val, tod_emb, dow_emb, node_emb, XEMB, ROWS_TN * EMB);
  transpose_emb<<<dim3(8750), dim3(256), 0, stream>>>(XEMB, XEMBT, ROWS_TN * EMB);
  zinit_kernel<<<dim3(3377), dim3(256), 0, stream>>>(Z, b_in, ROWS_BN * SS * HH);
  // x_in: [1228,1824]@[1824,704], split-K 6x304
  gemm_splitk<<<dim3(20, 11, 6), dim3(256), 0, stream>>>(
      XEMBT, TT * EMB, W_in, SS * HH, Z, SS * HH,
      ROWS_BN, SS * HH, TT * EMB, 304);
  c2_kernel<<<dim3(ROWS_BN * SS), dim3(64), 0, stream>>>(coeff2, W_ce, b_ce, C2);
  pack_wg<<<dim3(76), dim3(256), 0, stream>>>(Wg1, Wg2, WGP);
  gemm_kernel<<<dim3(231, 2, 1), dim3(256), 0, stream>>>(
      XEMB, EMB, 0L, WGP, 128, 0L, XGP, 128, 0L, nullptr, ROWS_TN, 128, EMB, 0);
  gemm_kernel<<<dim3(5, 1, 48), dim3(256), 0, stream>>>(
      adj, NN, 0L, XGP, 128, (long)NN * 128, G, HH, (long)NN * HH, nullptr,
      NN, HH, NN, 0);
  gemm_kernel<<<dim3(5, 1, 48), dim3(256), 0, stream>>>(
      adj_sem, NN, 0L, XGP + 64, 128, (long)NN * 128, G, HH, (long)NN * HH, bg,
      NN, HH, NN, GF_ACCUM | GF_BIAS | GF_RELU);
  gp_kernel<<<dim3(ROWS_BN), dim3(64), 0, stream>>>(G, Wgo, bgo, w_het, out);

  // ---- phase 2: Euler scan, 11 steps, 4 dispatches each ----
  for (int i = 0; i < SS; ++i) {
    qkv_rowwave<<<dim3(423), dim3(256), 0, stream>>>(
        Z, Wq, Wk, Wv, bq, bk, bv, QKV);
    attn_kernel<<<dim3(BB * SS * NHH, 2), dim3(256), 0, stream>>>(QKV, O);
    wo_ln1<<<dim3(423), dim3(256), 0, stream>>>(O, Z, Wo, bo, ln1_g, ln1_b, H1);
    ffn_ln2<<<dim3(423), dim3(256), 0, stream>>>(
        H1, C2, Wf1, bf1, Wf2, bf2, ln2_g, ln2_b, W_tp2, b_tp2, Z, i);
  }

  // ---- epilogue ----
  final_acl<<<dim3(ROWS_BN), dim3(64), 0, stream>>>(
      Z, lnf_g, lnf_b, W_end, b_end, w_acl, out);
}

// Round 3
// 2219.802 us; speedup vs baseline: 1.6885x; 1.5580x over previous
//
#include <hip/hip_runtime.h>
#include <math.h>

// Problem dims
#define BB   4
#define TT   12
#define NN   307
#define SS   11
#define HH   64
#define NHH  4
#define DHH  16
#define EMB  152
#define ROWS 13508          // B*S*N
#define KTP  312            // global K^T/V^T row pitch (floats)
#define LKP  310            // LDS K/V row pitch (310 mod 32 = 22 -> 16 distinct bank bases)

// GEMM epilogue flags
#define GF_BIAS  1
#define GF_RELU  2
#define GF_ACCUM 4

__device__ __forceinline__ float wave_sum(float v) {
#pragma unroll
  for (int off = 32; off; off >>= 1) v += __shfl_xor(v, off);
  return v;
}
__device__ __forceinline__ float wave_max(float v) {
#pragma unroll
  for (int off = 32; off; off >>= 1) v = fmaxf(v, __shfl_xor(v, off));
  return v;
}
__device__ __forceinline__ float rl(float v, int k) {
  return __int_as_float(__builtin_amdgcn_readlane(__float_as_int(v), k));
}
// row r in (b,s,n) order -> flat offset of the 64-float row in Z ([b,n,s,h])
__device__ __forceinline__ long zoff_of_row(int r, int* s_out, long* bn_out) {
  int b = r / (SS * NN);
  int rem = r - b * (SS * NN);
  int s = rem / NN;
  int n = rem - s * NN;
  long bn = (long)b * NN + n;
  if (s_out) *s_out = s;
  if (bn_out) *bn_out = bn;
  return (bn * SS + s) * 64;
}

// ---------------------------------------------------------------------------
// Generic fp32 tiled GEMM (phase-1 mid-size matmuls)
// ---------------------------------------------------------------------------
__global__ __launch_bounds__(256) void gemm_kernel(
    const float* __restrict__ A, int lda, long strideA,
    const float* __restrict__ B, int ldb, long strideB,
    float* __restrict__ C, int ldc, long strideC,
    const float* __restrict__ bias,
    int M, int N, int K, int flags)
{
  int bt = blockIdx.z;
  A += (long)bt * strideA;
  B += (long)bt * strideB;
  C += (long)bt * strideC;
  int m0 = blockIdx.x * 64, n0 = blockIdx.y * 64;

  __shared__ __align__(16) float As[16][68];
  __shared__ __align__(16) float Bs[16][64];

  int tid = threadIdx.x;
  int tx = tid & 15, ty = tid >> 4;
  float acc[4][4] = {};

  for (int k0 = 0; k0 < K; k0 += 16) {
#pragma unroll
    for (int l = 0; l < 4; ++l) {
      int idx = tid + l * 256;
      int m = idx >> 4, k = idx & 15;
      float v = 0.f;
      if (m0 + m < M && k0 + k < K) v = A[(long)(m0 + m) * lda + k0 + k];
      As[k][m] = v;
    }
#pragma unroll
    for (int l = 0; l < 4; ++l) {
      int idx = tid + l * 256;
      int k = idx >> 6, n = idx & 63;
      float v = 0.f;
      if (k0 + k < K && n0 + n < N) v = B[(long)(k0 + k) * ldb + n0 + n];
      Bs[k][n] = v;
    }
    __syncthreads();
#pragma unroll
    for (int k = 0; k < 16; ++k) {
      float4 a4 = *reinterpret_cast<const float4*>(&As[k][ty * 4]);
      float4 b4 = *reinterpret_cast<const float4*>(&Bs[k][tx * 4]);
      float a[4] = {a4.x, a4.y, a4.z, a4.w};
      float b[4] = {b4.x, b4.y, b4.z, b4.w};
#pragma unroll
      for (int i = 0; i < 4; ++i)
#pragma unroll
        for (int j = 0; j < 4; ++j)
          acc[i][j] += a[i] * b[j];
    }
    __syncthreads();
  }

#pragma unroll
  for (int i = 0; i < 4; ++i) {
    int m = m0 + ty * 4 + i;
    if (m >= M) continue;
#pragma unroll
    for (int j = 0; j < 4; ++j) {
      int n = n0 + tx * 4 + j;
      if (n >= N) continue;
      float v = acc[i][j];
      if (flags & GF_ACCUM) v += C[(long)m * ldc + n];
      if (flags & GF_BIAS)  v += bias[n];
      if (flags & GF_RELU)  v = fmaxf(v, 0.f);
      C[(long)m * ldc + n] = v;
    }
  }
}

// Split-K GEMM: each z-block handles KS of K, atomicAdd into pre-initialized C.
__global__ __launch_bounds__(256) void gemm_splitk(
    const float* __restrict__ A, int lda,
    const float* __restrict__ B, int ldb,
    float* __restrict__ C, int ldc,
    int M, int N, int K, int KS)
{
  int kstart = blockIdx.z * KS;
  int kend = min(K, kstart + KS);
  int m0 = blockIdx.x * 64, n0 = blockIdx.y * 64;

  __shared__ __align__(16) float As[16][68];
  __shared__ __align__(16) float Bs[16][64];

  int tid = threadIdx.x;
  int tx = tid & 15, ty = tid >> 4;
  float acc[4][4] = {};

  for (int k0 = kstart; k0 < kend; k0 += 16) {
#pragma unroll
    for (int l = 0; l < 4; ++l) {
      int idx = tid + l * 256;
      int m = idx >> 4, k = idx & 15;
      float v = 0.f;
      if (m0 + m < M && k0 + k < kend) v = A[(long)(m0 + m) * lda + k0 + k];
      As[k][m] = v;
    }
#pragma unroll
    for (int l = 0; l < 4; ++l) {
      int idx = tid + l * 256;
      int k = idx >> 6, n = idx & 63;
      float v = 0.f;
      if (k0 + k < kend && n0 + n < N) v = B[(long)(k0 + k) * ldb + n0 + n];
      Bs[k][n] = v;
    }
    __syncthreads();
#pragma unroll
    for (int k = 0; k < 16; ++k) {
      float4 a4 = *reinterpret_cast<const float4*>(&As[k][ty * 4]);
      float4 b4 = *reinterpret_cast<const float4*>(&Bs[k][tx * 4]);
      float a[4] = {a4.x, a4.y, a4.z, a4.w};
      float b[4] = {b4.x, b4.y, b4.z, b4.w};
#pragma unroll
      for (int i = 0; i < 4; ++i)
#pragma unroll
        for (int j = 0; j < 4; ++j)
          acc[i][j] += a[i] * b[j];
    }
    __syncthreads();
  }

#pragma unroll
  for (int i = 0; i < 4; ++i) {
    int m = m0 + ty * 4 + i;
    if (m >= M) continue;
#pragma unroll
    for (int j = 0; j < 4; ++j) {
      int n = n0 + tx * 4 + j;
      if (n >= N) continue;
      atomicAdd(&C[(long)m * ldc + n], acc[i][j]);
    }
  }
}

__global__ void zinit_kernel(float* __restrict__ Z, const float* __restrict__ b_in,
                             int total)
{
  int idx = blockIdx.x * 256 + threadIdx.x;
  if (idx < total) Z[idx] = b_in[idx % (SS * HH)];
}

// ---------------------------------------------------------------------------
// DataEmbedding
// ---------------------------------------------------------------------------
__global__ void embed_kernel(const float* __restrict__ ori,
                             const float* __restrict__ W_val,
                             const float* __restrict__ b_val,
                             const float* __restrict__ tod_emb,
                             const float* __restrict__ dow_emb,
                             const float* __restrict__ node_emb,
                             float* __restrict__ x_emb, int total)
{
  int idx = blockIdx.x * 256 + threadIdx.x;
  if (idx >= total) return;
  int c = idx % EMB;
  int r = idx / EMB;            // (b*T + t)*N + n
  int n = r % NN;
  float v;
  if (c < 24) {
    const float* x = ori + (long)r * 3;
    v = x[0] * W_val[c] + x[1] * W_val[24 + c] + x[2] * W_val[48 + c] + b_val[c];
  } else if (c < 48) {
    float f = ori[(long)r * 3 + 1];
    f = f - floorf(f);
    int tod = (int)(f * 288.f);
    tod = min(max(tod, 0), 287);
    v = tod_emb[tod * 24 + (c - 24)];
  } else if (c < 72) {
    float f = ori[(long)r * 3 + 2];
    f = f - floorf(f);
    int dow = (int)(f * 7.f);
    dow = min(max(dow, 0), 6);
    v = dow_emb[dow * 24 + (c - 48)];
  } else {
    v = node_emb[n * 80 + (c - 72)];
  }
  x_emb[idx] = v;
}

__global__ void transpose_emb(const float* __restrict__ x_emb,
                              float* __restrict__ x_embT, int total)
{
  int idx = blockIdx.x * 256 + threadIdx.x;
  if (idx >= total) return;
  int c = idx % EMB;
  int r = idx / EMB;            // (b*N + n)*T + t
  int t = r % TT;
  int r2 = r / TT;
  int n = r2 % NN;
  int b = r2 / NN;
  x_embT[idx] = x_emb[(((long)(b * TT + t)) * NN + n) * EMB + c];
}

__global__ void c2_kernel(const float* __restrict__ coeff2,
                          const float* __restrict__ W_ce,
                          const float* __restrict__ b_ce,
                          float* __restrict__ c2)
{
  int row = blockIdx.x;         // (b*N+n)*S + s
  int h = threadIdx.x;
  float a0 = coeff2[(long)row * 2];
  float a1 = coeff2[(long)row * 2 + 1];
  c2[(long)row * 64 + h] = a0 * W_ce[h] + a1 * W_ce[64 + h] + b_ce[h];
}

__global__ void pack_wg(const float* __restrict__ Wg1, const float* __restrict__ Wg2,
                        float* __restrict__ WGP)
{
  int idx = blockIdx.x * 256 + threadIdx.x;
  if (idx >= EMB * 128) return;
  int k = idx >> 7, c = idx & 127;
  WGP[idx] = (c < 64) ? Wg1[k * 64 + c] : Wg2[k * 64 + c - 64];
}

// ---------------------------------------------------------------------------
// K_A: QKV projection. Emits Q [bs,n,64], and K^T/V^T [bs,64,KTP] (transposed
// via LDS so global writes are coalesced). Block = (bs, 16-row n-tile).
// ---------------------------------------------------------------------------
__global__ __launch_bounds__(256) void qkv_rowwave(
    const float* __restrict__ Z,
    const float* __restrict__ Wq, const float* __restrict__ Wk,
    const float* __restrict__ Wv, const float* __restrict__ bq,
    const float* __restrict__ bk, const float* __restrict__ bv,
    float* __restrict__ Qa, float* __restrict__ KT, float* __restrict__ VT)
{
  __shared__ __align__(16) float Wls[64 * 192];  // 48 KB
  __shared__ float kb[64 * 17];                  // 4.25 KB
  __shared__ float vb2[64 * 17];                 // 4.25 KB
  int tid = threadIdx.x;
  for (int i = tid; i < 1024; i += 256) {
    int k = i >> 4, c4 = (i & 15) * 4;
    *(float4*)&Wls[k * 192 + c4]       = ((const float4*)Wq)[i];
    *(float4*)&Wls[k * 192 + 64 + c4]  = ((const float4*)Wk)[i];
    *(float4*)&Wls[k * 192 + 128 + c4] = ((const float4*)Wv)[i];
  }

  int bs = blockIdx.x;              // b*S + s
  int nt = blockIdx.y;              // 0..19
  int b = bs / SS, s = bs - b * SS;
  int wave = tid >> 6, lane = tid & 63;
  int n0 = nt * 16;
  __syncthreads();

  float bqv = bq[lane], bkv = bk[lane], bvv = bv[lane];
  int i0 = wave * 4;
  float zr[4], aq[4], ak[4], av[4];
  bool act[4];
#pragma unroll
  for (int j = 0; j < 4; ++j) {
    int n = n0 + i0 + j;
    act[j] = (n < NN);
    zr[j] = act[j] ? Z[(((long)(b * NN + n)) * SS + s) * 64 + lane] : 0.f;
    aq[j] = bqv; ak[j] = bkv; av[j] = bvv;
  }
#pragma unroll 8
  for (int k = 0; k < 64; ++k) {
    float w0 = Wls[k * 192 + lane];
    float w1 = Wls[k * 192 + 64 + lane];
    float w2 = Wls[k * 192 + 128 + lane];
#pragma unroll
    for (int j = 0; j < 4; ++j) {
      float a = rl(zr[j], k);
      aq[j] += a * w0; ak[j] += a * w1; av[j] += a * w2;
    }
  }
#pragma unroll
  for (int j = 0; j < 4; ++j) {
    int n = n0 + i0 + j;
    if (act[j]) Qa[((long)bs * NN + n) * 64 + lane] = aq[j];
    kb[lane * 17 + i0 + j] = ak[j];
    vb2[lane * 17 + i0 + j] = av[j];
  }
  __syncthreads();
  for (int e = tid; e < 1024; e += 256) {
    int c = e >> 4, i = e & 15;
    int n = n0 + i;
    if (n < NN) {
      long o = ((long)bs * 64 + c) * KTP + n;
      KT[o] = kb[c * 17 + i];
      VT[o] = vb2[c * 17 + i];
    }
  }
}

// ---------------------------------------------------------------------------
// K_B: spatial MHSA v2. Block = (bs*head, 24-query chunk). K^T/V^T staged
// coalesced into LDS; no barriers in the query loop; 2 queries per wave-iter
// sharing all K/V reads (pair offsets -> ds_read2).
// ---------------------------------------------------------------------------
__global__ __launch_bounds__(256) void attn_kernel(
    const float* __restrict__ Qa, const float* __restrict__ KTg,
    const float* __restrict__ VTg, float* __restrict__ O)
{
  int bsh = blockIdx.x;           // bs*NH + head
  int chunk = blockIdx.y;         // 0..12 (24 queries each)
  int head = bsh & 3;
  int bs = bsh >> 2;

  __shared__ float Kt[16 * LKP + 8];
  __shared__ float Vt[16 * LKP + 8];
  __shared__ float Pl[4][2][312];

  int tid = threadIdx.x;
  const float* KTh = KTg + ((long)bs * 64 + head * 16) * KTP;
  const float* VTh = VTg + ((long)bs * 64 + head * 16) * KTP;
  if (tid < 8) { Kt[16 * LKP + tid] = 0.f; Vt[16 * LKP + tid] = 0.f; }
#pragma unroll
  for (int d = 0; d < 16; ++d) {
    for (int m = tid; m < LKP; m += 256) {
      float kv = 0.f, vv = 0.f;
      if (m < NN) { kv = KTh[(long)d * KTP + m]; vv = VTh[(long)d * KTP + m]; }
      Kt[d * LKP + m] = kv;
      Vt[d * LKP + m] = vv;
    }
  }
  __syncthreads();

  int wave = tid >> 6, lane = tid & 63;
  int q0 = chunk * 24;
  int qn = min(24, NN - q0);      // 24, last chunk 19
  const float* qb = Qa + ((long)bs * NN + q0) * 64 + head * 16;
  long obase = ((long)bs * NN + q0) * 64 + head * 16;
  float* PA = &Pl[wave][0][0];
  float* PB = &Pl[wave][1][0];

  for (int it = 0; it < 3; ++it) {
    int ql = wave * 6 + it * 2;
    if (ql >= qn) continue;                 // wave-uniform, no barriers below
    bool vbq = (ql + 1) < qn;
    const float* qra = qb + (long)ql * 64;
    const float* qrb = qb + (long)(ql + 1) * 64;

    float sa[5] = {}, sb[5] = {};
#pragma unroll
    for (int d = 0; d < 16; ++d) {
      float qav = qra[d];
      float qbv = vbq ? qrb[d] : 0.f;
      float k0 = Kt[d * LKP + lane];
      float k1 = Kt[d * LKP + 64 + lane];
      float k2 = Kt[d * LKP + 128 + lane];
      float k3 = Kt[d * LKP + 192 + lane];
      float k4 = Kt[d * LKP + 256 + lane];  // lanes>=51 read pad/garbage, masked later
      sa[0] += qav * k0; sa[1] += qav * k1; sa[2] += qav * k2;
      sa[3] += qav * k3; sa[4] += qav * k4;
      sb[0] += qbv * k0; sb[1] += qbv * k1; sb[2] += qbv * k2;
      sb[3] += qbv * k3; sb[4] += qbv * k4;
    }
    bool tl = (lane < 51);
#pragma unroll
    for (int c = 0; c < 4; ++c) { sa[c] *= 0.25f; sb[c] *= 0.25f; }
    sa[4] = tl ? sa[4] * 0.25f : -1e30f;
    sb[4] = tl ? sb[4] * 0.25f : -1e30f;

    float mxa = fmaxf(fmaxf(fmaxf(sa[0], sa[1]), fmaxf(sa[2], sa[3])), sa[4]);
    float mxb = fmaxf(fmaxf(fmaxf(sb[0], sb[1]), fmaxf(sb[2], sb[3])), sb[4]);
    mxa = wave_max(mxa); mxb = wave_max(mxb);
    float ea[5], eb[5], suma = 0.f, sumb = 0.f;
#pragma unroll
    for (int c = 0; c < 5; ++c) {
      ea[c] = __expf(sa[c] - mxa); suma += ea[c];
      eb[c] = __expf(sb[c] - mxb); sumb += eb[c];
    }
    suma = wave_sum(suma); sumb = wave_sum(sumb);
    float ia = 1.f / suma, ib = 1.f / sumb;
#pragma unroll
    for (int c = 0; c < 4; ++c) {
      PA[c * 64 + lane] = ea[c] * ia;
      PB[c * 64 + lane] = eb[c] * ib;
    }
    if (lane < 56) {            // covers m=256..311; zeros for m>=307
      PA[256 + lane] = tl ? ea[4] * ia : 0.f;
      PB[256 + lane] = tl ? eb[4] * ib : 0.f;
    }

    // PV: lane = (part, d); each lane sums ranges [39p,39p+39) and +156.
    int p = lane >> 4, d = lane & 15;
    float aa = 0.f, ab = 0.f;
    int r0 = 39 * p;
#pragma unroll 13
    for (int i = 0; i < 39; ++i) {
      int m0 = r0 + i, m1 = m0 + 156;
      float v0 = Vt[d * LKP + m0];
      float v1 = Vt[d * LKP + m1];
      float pa0 = PA[m0], pa1 = PA[m1];
      float pb0 = PB[m0], pb1 = PB[m1];
      aa += pa0 * v0 + pa1 * v1;
      ab += pb0 * v0 + pb1 * v1;
    }
    aa += __shfl_xor(aa, 16); aa += __shfl_xor(aa, 32);
    ab += __shfl_xor(ab, 16); ab += __shfl_xor(ab, 32);
    if (p == 0) {
      O[obase + (long)ql * 64 + d] = aa;
      if (vbq) O[obase + (long)(ql + 1) * 64 + d] = ab;
    }
  }
}

// K_C: o2 = O@Wo + bo; h1 = LN(z + o2; ln1). 32 rows/block.
__global__ __launch_bounds__(256) void wo_ln1(
    const float* __restrict__ O, const float* __restrict__ Z,
    const float* __restrict__ Wo, const float* __restrict__ bo,
    const float* __restrict__ g, const float* __restrict__ b,
    float* __restrict__ h1)
{
  __shared__ __align__(16) float Ws[64 * 64];
  int tid = threadIdx.x;
  for (int i = tid; i < 1024; i += 256)
    *(float4*)&Ws[i * 4] = ((const float4*)Wo)[i];
  __syncthreads();

  int wave = tid >> 6, lane = tid & 63;
  float bov = bo[lane], gv = g[lane], bv = b[lane];
  int rbase = blockIdx.x * 32 + wave * 8;

  for (int p = 0; p < 2; ++p) {
    int r0 = rbase + p * 4;
    float orr[4], zr[4], acc[4];
    bool act[4];
#pragma unroll
    for (int j = 0; j < 4; ++j) {
      int r = r0 + j;
      act[j] = (r < ROWS);
      orr[j] = act[j] ? O[(long)r * 64 + lane] : 0.f;
      zr[j]  = act[j] ? Z[zoff_of_row(r, nullptr, nullptr) + lane] : 0.f;
      acc[j] = 0.f;
    }
#pragma unroll 8
    for (int k = 0; k < 64; ++k) {
      float w = Ws[k * 64 + lane];
#pragma unroll
      for (int j = 0; j < 4; ++j) acc[j] += rl(orr[j], k) * w;
    }
#pragma unroll
    for (int j = 0; j < 4; ++j) {
      if (!act[j]) continue;
      float x = zr[j] + acc[j] + bov;
      float m = wave_sum(x) * (1.f / 64.f);
      float d = x - m;
      float v = wave_sum(d * d) * (1.f / 64.f);
      h1[(long)(r0 + j) * 64 + lane] = d * rsqrtf(v + 1e-5f) * gv + bv;
    }
  }
}

// K_D: FFN + LN2 + tanh + Euler update (x2s recomputed from C2).
__global__ __launch_bounds__(256) void ffn_ln2(
    const float* __restrict__ H1, const float* __restrict__ C2,
    const float* __restrict__ Wf1, const float* __restrict__ bf1,
    const float* __restrict__ Wf2, const float* __restrict__ bf2,
    const float* __restrict__ g2, const float* __restrict__ b2,
    const float* __restrict__ W_tp2, const float* __restrict__ b_tp2,
    float* __restrict__ Z, int iter)
{
  __shared__ __align__(16) float W1s[64 * 64];
  __shared__ __align__(16) float W2s[64 * 64];
  int tid = threadIdx.x;
  int wave = tid >> 6, lane = tid & 63;
  int rbase = blockIdx.x * 32 + wave * 8;

  float h1r[8], ff[8];
  bool act[8];
#pragma unroll
  for (int j = 0; j < 8; ++j) {
    int r = rbase + j;
    act[j] = (r < ROWS);
    h1r[j] = act[j] ? H1[(long)r * 64 + lane] : 0.f;
    ff[j] = 0.f;
  }
  float g2v = g2[lane], b2v = b2[lane], bf2v = bf2[lane];

  for (int ch = 0; ch < 4; ++ch) {
    __syncthreads();
    for (int i = tid; i < 1024; i += 256) {
      int k = i >> 4, c4 = (i & 15) * 4;
      *(float4*)&W1s[k * 64 + c4] =
          *(const float4*)(Wf1 + (long)k * 256 + ch * 64 + c4);
      *(float4*)&W2s[k * 64 + c4] =
          *(const float4*)(Wf2 + (long)(ch * 64 + k) * 64 + c4);
    }
    __syncthreads();
    float bf1v = bf1[ch * 64 + lane];
#pragma unroll
    for (int jp = 0; jp < 4; ++jp) {
      int j0 = jp * 2, j1 = jp * 2 + 1;
      float h0 = bf1v, h1v = bf1v;
#pragma unroll 8
      for (int k = 0; k < 64; ++k) {
        float w = W1s[k * 64 + lane];
        h0  += rl(h1r[j0], k) * w;
        h1v += rl(h1r[j1], k) * w;
      }
      h0 = fmaxf(h0, 0.f);
      h1v = fmaxf(h1v, 0.f);
#pragma unroll 8
      for (int k = 0; k < 64; ++k) {
        float w = W2s[k * 64 + lane];
        ff[j0] += rl(h0, k) * w;
        ff[j1] += rl(h1v, k) * w;
      }
    }
  }

#pragma unroll
  for (int j = 0; j < 8; ++j) {
    if (!act[j]) continue;
    int r = rbase + j;
    float x = h1r[j] + ff[j] + bf2v;
    float m = wave_sum(x) * (1.f / 64.f);
    float d = x - m;
    float v = wave_sum(d * d) * (1.f / 64.f);
    float t = tanhf(d * rsqrtf(v + 1e-5f) * g2v + b2v);

    int s1; long bn;
    long zo = zoff_of_row(r, &s1, &bn);
    float acc = b_tp2[s1 * SS + iter];
#pragma unroll
    for (int s = 0; s < SS; ++s)
      acc += C2[(bn * SS + s) * 64 + lane] * W_tp2[s * (SS * SS) + s1 * SS + iter];
    Z[zo + lane] += t * acc;
  }
}

// gp: out[b,o,n] = w_het * (sum_{t,h} g[b,t,n,h]*Wgo[t*H+h,o] + bgo[o])
__global__ __launch_bounds__(64) void gp_kernel(const float* __restrict__ g,
                                                const float* __restrict__ Wgo,
                                                const float* __restrict__ bgo,
                                                const float* __restrict__ w_het,
                                                float* __restrict__ out)
{
  int bn = blockIdx.x;
  int b = bn / NN, n = bn % NN;
  __shared__ float buf[TT * 64];
  for (int idx = threadIdx.x; idx < TT * 64; idx += 64) {
    int t = idx >> 6, h = idx & 63;
    buf[idx] = g[(((long)(b * TT + t)) * NN + n) * 64 + h];
  }
  __syncthreads();
  int o = threadIdx.x;
  if (o < 12) {
    float acc = bgo[o];
    for (int j = 0; j < TT * 64; ++j) acc += buf[j] * Wgo[j * 12 + o];
    out[((long)b * 12 + o) * NN + n] = w_het[0] * acc;
  }
}

// zT = LN(z[:,:,S-1,:]; lnf);  out[b,o,n] += w_acl*(zT@W_end + b_end)
__global__ __launch_bounds__(64) void final_acl(const float* __restrict__ z,
                                                const float* __restrict__ lnf_g,
                                                const float* __restrict__ lnf_b,
                                                const float* __restrict__ W_end,
                                                const float* __restrict__ b_end,
                                                const float* __restrict__ w_acl,
                                                float* __restrict__ out)
{
  int bn = blockIdx.x;          // b*N + n
  int lane = threadIdx.x;
  int b = bn / NN, n = bn % NN;
  float x = z[((long)bn * SS + (SS - 1)) * 64 + lane];
  float m = wave_sum(x) * (1.f / 64.f);
  float d = x - m;
  float v = wave_sum(d * d) * (1.f / 64.f);
  float zT = d * rsqrtf(v + 1e-5f) * lnf_g[lane] + lnf_b[lane];
  float wa = w_acl[0];
  for (int o = 0; o < 12; ++o) {
    float p = zT * W_end[lane * 12 + o];
    p = wave_sum(p);
    if (lane == 0) {
      long oi = ((long)b * 12 + o) * NN + n;
      out[oi] = out[oi] + wa * (p + b_end[o]);
    }
  }
}

// ---------------------------------------------------------------------------
extern "C" void kernel_launch(void* const* d_in, const int* in_sizes, int n_in,
                              void* d_out, int out_size, void* d_ws, size_t ws_size,
                              hipStream_t stream)
{
  (void)in_sizes; (void)n_in; (void)out_size; (void)ws_size;

  const float* ori_x    = (const float*)d_in[0];
  const float* coeff2   = (const float*)d_in[2];
  const float* W_val    = (const float*)d_in[5];
  const float* b_val    = (const float*)d_in[6];
  const float* tod_emb  = (const float*)d_in[7];
  const float* dow_emb  = (const float*)d_in[8];
  const float* node_emb = (const float*)d_in[9];
  const float* W_in     = (const float*)d_in[10];
  const float* b_in     = (const float*)d_in[11];
  const float* W_ce     = (const float*)d_in[12];
  const float* b_ce     = (const float*)d_in[13];
  const float* W_tp2    = (const float*)d_in[14];
  const float* b_tp2    = (const float*)d_in[15];
  const float* Wq = (const float*)d_in[20];
  const float* Wk = (const float*)d_in[21];
  const float* Wv = (const float*)d_in[22];
  const float* Wo = (const float*)d_in[23];
  const float* bq = (const float*)d_in[24];
  const float* bk = (const float*)d_in[25];
  const float* bv = (const float*)d_in[26];
  const float* bo = (const float*)d_in[27];
  const float* ln1_g = (const float*)d_in[28];
  const float* ln1_b = (const float*)d_in[29];
  const float* Wf1   = (const float*)d_in[30];
  const float* bf1   = (const float*)d_in[31];
  const float* Wf2   = (const float*)d_in[32];
  const float* bf2   = (const float*)d_in[33];
  const float* ln2_g = (const float*)d_in[34];
  const float* ln2_b = (const float*)d_in[35];
  const float* lnf_g = (const float*)d_in[36];
  const float* lnf_b = (const float*)d_in[37];
  const float* W_end = (const float*)d_in[38];
  const float* b_end = (const float*)d_in[39];
  const float* w_acl = (const float*)d_in[40];
  const float* w_het = (const float*)d_in[41];
  const float* adj     = (const float*)d_in[42];
  const float* adj_sem = (const float*)d_in[43];
  const float* Wg1 = (const float*)d_in[44];
  const float* Wg2 = (const float*)d_in[45];
  const float* bg  = (const float*)d_in[46];
  const float* Wgo = (const float*)d_in[47];
  const float* bgo = (const float*)d_in[48];
  float* out = (float*)d_out;
  float* ws  = (float*)d_ws;

  const int ROWS_TN = BB * TT * NN;   // 14736
  const int ROWS_BN = BB * NN;        // 1228

  // ---- workspace layout (floats) ----
  float* Z    = ws;                      // 864512  z state [B,N,S,H]
  float* C2   = ws + 864512;             // 864512
  float* POOL = ws + 1729024;
  // phase 1
  float* XEMB  = POOL;                   // 2239872 [B,T,N,152]
  float* XEMBT = POOL + 2239872;         // 2239872 [B,N,T,152]
  float* XGP   = POOL + 4479744;         // 1886208 [B,T,N,128]
  float* G     = POOL + 6365952;         // 943104  [B,T,N,64]
  float* WGP   = POOL + 7309056;         // 19456
  // phase 2 (overlays phase 1)
  float* Qa = POOL;                      // 864512  [bs,307,64]
  float* KT = POOL + 864512;             // 878592  [bs,64,KTP]
  float* VT = POOL + 1743104;            // 878592
  float* O  = POOL + 2621696;            // 864512
  float* H1 = POOL + 3486208;            // 864512

  // ---- phase 1 ----
  embed_kernel<<<dim3(8750), dim3(256), 0, stream>>>(
      ori_x, W_val, b_val, tod_emb, dow_emb, node_emb, XEMB, ROWS_TN * EMB);
  transpose_emb<<<dim3(8750), dim3(256), 0, stream>>>(XEMB, XEMBT, ROWS_TN * EMB);
  zinit_kernel<<<dim3(3377), dim3(256), 0, stream>>>(Z, b_in, ROWS_BN * SS * HH);
  gemm_splitk<<<dim3(20, 11, 6), dim3(256), 0, stream>>>(
      XEMBT, TT * EMB, W_in, SS * HH, Z, SS * HH,
      ROWS_BN, SS * HH, TT * EMB, 304);
  c2_kernel<<<dim3(ROWS_BN * SS), dim3(64), 0, stream>>>(coeff2, W_ce, b_ce, C2);
  pack_wg<<<dim3(76), dim3(256), 0, stream>>>(Wg1, Wg2, WGP);
  gemm_kernel<<<dim3(231, 2, 1), dim3(256), 0, stream>>>(
      XEMB, EMB, 0L, WGP, 128, 0L, XGP, 128, 0L, nullptr, ROWS_TN, 128, EMB, 0);
  gemm_kernel<<<dim3(5, 1, 48), dim3(256), 0, stream>>>(
      adj, NN, 0L, XGP, 128, (long)NN * 128, G, HH, (long)NN * HH, nullptr,
      NN, HH, NN, 0);
  gemm_kernel<<<dim3(5, 1, 48), dim3(256), 0, stream>>>(
      adj_sem, NN, 0L, XGP + 64, 128, (long)NN * 128, G, HH, (long)NN * HH, bg,
      NN, HH, NN, GF_ACCUM | GF_BIAS | GF_RELU);
  gp_kernel<<<dim3(ROWS_BN), dim3(64), 0, stream>>>(G, Wgo, bgo, w_het, out);

  // ---- phase 2: Euler scan, 11 steps ----
  for (int i = 0; i < SS; ++i) {
    qkv_rowwave<<<dim3(BB * SS, 20), dim3(256), 0, stream>>>(
        Z, Wq, Wk, Wv, bq, bk, bv, Qa, KT, VT);
    attn_kernel<<<dim3(BB * SS * NHH, 13), dim3(256), 0, stream>>>(Qa, KT, VT, O);
    wo_ln1<<<dim3(423), dim3(256), 0, stream>>>(O, Z, Wo, bo, ln1_g, ln1_b, H1);
    ffn_ln2<<<dim3(423), dim3(256), 0, stream>>>(
        H1, C2, Wf1, bf1, Wf2, bf2, ln2_g, ln2_b, W_tp2, b_tp2, Z, i);
  }

  // ---- epilogue ----
  final_acl<<<dim3(ROWS_BN), dim3(64), 0, stream>>>(
      Z, lnf_g, lnf_b, W_end, b_end, w_acl, out);
}

// Round 4
// 1781.568 us; speedup vs baseline: 2.1039x; 1.2460x over previous
//
#include <hip/hip_runtime.h>
#include <hip/hip_bf16.h>
#include <math.h>

// Problem dims
#define BB   4
#define TT   12
#define NN   307
#define SS   11
#define HH   64
#define NHH  4
#define DHH  16
#define EMB  152
#define ROWS 13508          // B*S*N
#define NBS  44             // B*S
#define NP   320            // padded node count (per-bs row pad)
#define RPAD 13568          // 212*64 padded flat rows
#define KTP  312            // global K^T/V^T row pitch (floats)
#define LKP  310            // LDS K/V pitch in attn

#define GF_BIAS  1
#define GF_RELU  2
#define GF_ACCUM 4

typedef short short8 __attribute__((ext_vector_type(8)));   // 8 bf16
typedef float floatx4 __attribute__((ext_vector_type(4)));
#define MFMA_B16(a, b, c) __builtin_amdgcn_mfma_f32_16x16x32_bf16(a, b, c, 0, 0, 0)

__device__ __forceinline__ float wave_sum(float v) {
#pragma unroll
  for (int off = 32; off; off >>= 1) v += __shfl_xor(v, off);
  return v;
}
__device__ __forceinline__ float wave_max(float v) {
#pragma unroll
  for (int off = 32; off; off >>= 1) v = fmaxf(v, __shfl_xor(v, off));
  return v;
}
// row r in (b,s,n) order -> flat offset of the 64-float row in Z ([b,n,s,h])
__device__ __forceinline__ long zoff_of_row(int r, int* s_out, long* bn_out) {
  int b = r / (SS * NN);
  int rem = r - b * (SS * NN);
  int s = rem / NN;
  int n = rem - s * NN;
  long bn = (long)b * NN + n;
  if (s_out) *s_out = s;
  if (bn_out) *bn_out = bn;
  return (bn * SS + s) * 64;
}

// ---------------------------------------------------------------------------
// fp32 tiled GEMM (phase-1 GCN matmuls only)
// ---------------------------------------------------------------------------
__global__ __launch_bounds__(256) void gemm_kernel(
    const float* __restrict__ A, int lda, long strideA,
    const float* __restrict__ B, int ldb, long strideB,
    float* __restrict__ C, int ldc, long strideC,
    const float* __restrict__ bias,
    int M, int N, int K, int flags)
{
  int bt = blockIdx.z;
  A += (long)bt * strideA;
  B += (long)bt * strideB;
  C += (long)bt * strideC;
  int m0 = blockIdx.x * 64, n0 = blockIdx.y * 64;

  __shared__ __align__(16) float As[16][68];
  __shared__ __align__(16) float Bs[16][64];

  int tid = threadIdx.x;
  int tx = tid & 15, ty = tid >> 4;
  float acc[4][4] = {};

  for (int k0 = 0; k0 < K; k0 += 16) {
#pragma unroll
    for (int l = 0; l < 4; ++l) {
      int idx = tid + l * 256;
      int m = idx >> 4, k = idx & 15;
      float v = 0.f;
      if (m0 + m < M && k0 + k < K) v = A[(long)(m0 + m) * lda + k0 + k];
      As[k][m] = v;
    }
#pragma unroll
    for (int l = 0; l < 4; ++l) {
      int idx = tid + l * 256;
      int k = idx >> 6, n = idx & 63;
      float v = 0.f;
      if (k0 + k < K && n0 + n < N) v = B[(long)(k0 + k) * ldb + n0 + n];
      Bs[k][n] = v;
    }
    __syncthreads();
#pragma unroll
    for (int k = 0; k < 16; ++k) {
      float4 a4 = *reinterpret_cast<const float4*>(&As[k][ty * 4]);
      float4 b4 = *reinterpret_cast<const float4*>(&Bs[k][tx * 4]);
      float a[4] = {a4.x, a4.y, a4.z, a4.w};
      float b[4] = {b4.x, b4.y, b4.z, b4.w};
#pragma unroll
      for (int i = 0; i < 4; ++i)
#pragma unroll
        for (int j = 0; j < 4; ++j)
          acc[i][j] += a[i] * b[j];
    }
    __syncthreads();
  }

#pragma unroll
  for (int i = 0; i < 4; ++i) {
    int m = m0 + ty * 4 + i;
    if (m >= M) continue;
#pragma unroll
    for (int j = 0; j < 4; ++j) {
      int n = n0 + tx * 4 + j;
      if (n >= N) continue;
      float v = acc[i][j];
      if (flags & GF_ACCUM) v += C[(long)m * ldc + n];
      if (flags & GF_BIAS)  v += bias[n];
      if (flags & GF_RELU)  v = fmaxf(v, 0.f);
      C[(long)m * ldc + n] = v;
    }
  }
}

// ---------------------------------------------------------------------------
// transpose + fp32->bf16 convert: out[N,K] = in[K,N]^T
// ---------------------------------------------------------------------------
__global__ __launch_bounds__(256) void transpose_cvt(
    const float* __restrict__ in, __hip_bfloat16* __restrict__ out, int K, int N)
{
  __shared__ float t[32][33];
  int k0 = blockIdx.x * 32, n0 = blockIdx.y * 32;
  int tx = threadIdx.x & 31, ty = threadIdx.x >> 5;   // 8 rows per pass
#pragma unroll
  for (int i = 0; i < 32; i += 8) {
    int k = k0 + ty + i, n = n0 + tx;
    if (k < K && n < N) t[ty + i][tx] = in[(long)k * N + n];
  }
  __syncthreads();
#pragma unroll
  for (int i = 0; i < 32; i += 8) {
    int n = n0 + ty + i, k = k0 + tx;
    if (k < K && n < N) out[(long)n * K + k] = __float2bfloat16(t[tx][ty + i]);
  }
}

__global__ void pack_bias(const float* __restrict__ bq, const float* __restrict__ bk,
                          const float* __restrict__ bv, float* __restrict__ bqkv)
{
  int t = threadIdx.x;
  if (t < 64) { bqkv[t] = bq[t]; bqkv[64 + t] = bk[t]; bqkv[128 + t] = bv[t]; }
}

__global__ void zinit_kernel(float* __restrict__ Z, const float* __restrict__ b_in,
                             int total)
{
  int idx = blockIdx.x * 256 + threadIdx.x;
  if (idx < total) Z[idx] = b_in[idx % (SS * HH)];
}

// ---------------------------------------------------------------------------
// DataEmbedding
// ---------------------------------------------------------------------------
__global__ void embed_kernel(const float* __restrict__ ori,
                             const float* __restrict__ W_val,
                             const float* __restrict__ b_val,
                             const float* __restrict__ tod_emb,
                             const float* __restrict__ dow_emb,
                             const float* __restrict__ node_emb,
                             float* __restrict__ x_emb, int total)
{
  int idx = blockIdx.x * 256 + threadIdx.x;
  if (idx >= total) return;
  int c = idx % EMB;
  int r = idx / EMB;            // (b*T + t)*N + n
  int n = r % NN;
  float v;
  if (c < 24) {
    const float* x = ori + (long)r * 3;
    v = x[0] * W_val[c] + x[1] * W_val[24 + c] + x[2] * W_val[48 + c] + b_val[c];
  } else if (c < 48) {
    float f = ori[(long)r * 3 + 1];
    f = f - floorf(f);
    int tod = (int)(f * 288.f);
    tod = min(max(tod, 0), 287);
    v = tod_emb[tod * 24 + (c - 24)];
  } else if (c < 72) {
    float f = ori[(long)r * 3 + 2];
    f = f - floorf(f);
    int dow = (int)(f * 7.f);
    dow = min(max(dow, 0), 6);
    v = dow_emb[dow * 24 + (c - 48)];
  } else {
    v = node_emb[n * 80 + (c - 72)];
  }
  x_emb[idx] = v;
}

// x_embT(bf16)[b,n,t,c] = x_emb[b,t,n,c]
__global__ void transpose_emb(const float* __restrict__ x_emb,
                              __hip_bfloat16* __restrict__ x_embT, int total)
{
  int idx = blockIdx.x * 256 + threadIdx.x;
  if (idx >= total) return;
  int c = idx % EMB;
  int r = idx / EMB;            // (b*N + n)*T + t
  int t = r % TT;
  int r2 = r / TT;
  int n = r2 % NN;
  int b = r2 / NN;
  x_embT[idx] = __float2bfloat16(x_emb[(((long)(b * TT + t)) * NN + n) * EMB + c]);
}

__global__ void c2_kernel(const float* __restrict__ coeff2,
                          const float* __restrict__ W_ce,
                          const float* __restrict__ b_ce,
                          float* __restrict__ c2)
{
  int row = blockIdx.x;         // (b*N+n)*S + s
  int h = threadIdx.x;
  float a0 = coeff2[(long)row * 2];
  float a1 = coeff2[(long)row * 2 + 1];
  c2[(long)row * 64 + h] = a0 * W_ce[h] + a1 * W_ce[64 + h] + b_ce[h];
}

__global__ void pack_wg(const float* __restrict__ Wg1, const float* __restrict__ Wg2,
                        float* __restrict__ WGP)
{
  int idx = blockIdx.x * 256 + threadIdx.x;
  if (idx >= EMB * 128) return;
  int k = idx >> 7, c = idx & 127;
  WGP[idx] = (c < 64) ? Wg1[k * 64 + c] : Wg2[k * 64 + c - 64];
}

// ---------------------------------------------------------------------------
// x_in GEMM, bf16 MFMA, split-K=4, atomicAdd into bias-initialized Z.
// A [1228,1824] bf16, BT [704,1824] bf16 (=W_in^T), C=Z fp32 [1228,704].
// ---------------------------------------------------------------------------
__global__ __launch_bounds__(256) void gemm_xin(
    const __hip_bfloat16* __restrict__ A, const __hip_bfloat16* __restrict__ BT,
    float* __restrict__ C)
{
  int tid = threadIdx.x, w = tid >> 6, l = tid & 63;
  int m0 = blockIdx.x * 64 + w * 16;
  int n0 = blockIdx.y * 64;
  int k0s = blockIdx.z * 480;
  int k0e = min(1824, k0s + 480);

  int cq = l & 15, rq = l >> 4;
  int arow = min(m0 + cq, 1227);
  const short* Ap = (const short*)A + (long)arow * 1824 + rq * 8;
  const short* Bp = (const short*)BT + rq * 8;

  floatx4 acc[4] = {};
  for (int k0 = k0s; k0 < k0e; k0 += 32) {
    short8 a = *(const short8*)(Ap + k0);
#pragma unroll
    for (int nt = 0; nt < 4; ++nt) {
      short8 b = *(const short8*)(Bp + (long)(n0 + nt * 16 + cq) * 1824 + k0);
      acc[nt] = MFMA_B16(a, b, acc[nt]);
    }
  }
#pragma unroll
  for (int nt = 0; nt < 4; ++nt) {
    int c = n0 + nt * 16 + cq;
#pragma unroll
    for (int r = 0; r < 4; ++r) {
      int row = m0 + rq * 4 + r;
      if (row < 1228) atomicAdd(&C[(long)row * 704 + c], acc[nt][r]);
    }
  }
}

// Z (fp32, [b,n,s,h]) -> Zb (bf16, [bs, node(pad 320), 64]); pads zero-filled.
__global__ __launch_bounds__(256) void ztbf_kernel(const float* __restrict__ Z,
                                                   __hip_bfloat16* __restrict__ Zb)
{
  int row = blockIdx.x * 4 + (threadIdx.x >> 6);
  if (row >= NBS * NP) return;
  int lane = threadIdx.x & 63;
  int bs = row / NP, node = row - bs * NP;
  int b = bs / SS, s = bs - b * SS;
  float v = 0.f;
  if (node < NN) v = Z[(((long)(b * NN + node)) * SS + s) * 64 + lane];
  Zb[(long)row * 64 + lane] = __float2bfloat16(v);
}

// ---------------------------------------------------------------------------
// QKV projection, per-bs MFMA. A = Zb [bs,NP,64] bf16; WT [192,64] bf16.
// Writes Qa fp32 [bs,NP,64], KT/VT fp32 [bs,64,KTP] (transposed scatter).
// ---------------------------------------------------------------------------
__global__ __launch_bounds__(256) void qkv_mfma(
    const __hip_bfloat16* __restrict__ Zb, const __hip_bfloat16* __restrict__ WT,
    const float* __restrict__ bqkv,
    float* __restrict__ Qa, float* __restrict__ KT, float* __restrict__ VT)
{
  int bs = blockIdx.x, mt = blockIdx.y;
  int tid = threadIdx.x, w = tid >> 6, l = tid & 63;
  int m0 = mt * 64 + w * 16;
  int cq = l & 15, rq = l >> 4;

  const short* Ap = (const short*)Zb + ((long)bs * NP + m0 + cq) * 64 + rq * 8;
  short8 a0 = *(const short8*)Ap;
  short8 a1 = *(const short8*)(Ap + 32);

#pragma unroll
  for (int nt = 0; nt < 12; ++nt) {
    const short* Bp = (const short*)WT + (long)(nt * 16 + cq) * 64 + rq * 8;
    floatx4 acc = {0.f, 0.f, 0.f, 0.f};
    acc = MFMA_B16(a0, *(const short8*)Bp, acc);
    acc = MFMA_B16(a1, *(const short8*)(Bp + 32), acc);
    int c = nt * 16 + cq;
    float bias = bqkv[c];
#pragma unroll
    for (int r = 0; r < 4; ++r) {
      int node = m0 + rq * 4 + r;
      if (node < NN) {
        float v = acc[r] + bias;
        if (c < 64)       Qa[((long)bs * NP + node) * 64 + c] = v;
        else if (c < 128) KT[((long)bs * 64 + (c - 64)) * KTP + node] = v;
        else              VT[((long)bs * 64 + (c - 128)) * KTP + node] = v;
      }
    }
  }
}

// ---------------------------------------------------------------------------
// Spatial MHSA (fp32, R3 structure). Output stored as bf16.
// ---------------------------------------------------------------------------
__global__ __launch_bounds__(256) void attn_kernel(
    const float* __restrict__ Qa, const float* __restrict__ KTg,
    const float* __restrict__ VTg, __hip_bfloat16* __restrict__ O)
{
  int bsh = blockIdx.x;           // bs*NH + head
  int chunk = blockIdx.y;         // 0..12 (24 queries each)
  int head = bsh & 3;
  int bs = bsh >> 2;

  __shared__ float Kt[16 * LKP + 8];
  __shared__ float Vt[16 * LKP + 8];
  __shared__ float Pl[4][2][312];

  int tid = threadIdx.x;
  const float* KTh = KTg + ((long)bs * 64 + head * 16) * KTP;
  const float* VTh = VTg + ((long)bs * 64 + head * 16) * KTP;
  if (tid < 8) { Kt[16 * LKP + tid] = 0.f; Vt[16 * LKP + tid] = 0.f; }
#pragma unroll
  for (int d = 0; d < 16; ++d) {
    for (int m = tid; m < LKP; m += 256) {
      float kv = 0.f, vv = 0.f;
      if (m < NN) { kv = KTh[(long)d * KTP + m]; vv = VTh[(long)d * KTP + m]; }
      Kt[d * LKP + m] = kv;
      Vt[d * LKP + m] = vv;
    }
  }
  __syncthreads();

  int wave = tid >> 6, lane = tid & 63;
  int q0 = chunk * 24;
  int qn = min(24, NN - q0);
  const float* qb = Qa + ((long)bs * NP + q0) * 64 + head * 16;
  long obase = ((long)bs * NN + q0) * 64 + head * 16;
  float* PA = &Pl[wave][0][0];
  float* PB = &Pl[wave][1][0];

  for (int it = 0; it < 3; ++it) {
    int ql = wave * 6 + it * 2;
    if (ql >= qn) continue;                 // wave-uniform
    bool vbq = (ql + 1) < qn;
    const float* qra = qb + (long)ql * 64;
    const float* qrb = qb + (long)(ql + 1) * 64;

    float sa[5] = {}, sb[5] = {};
#pragma unroll
    for (int d = 0; d < 16; ++d) {
      float qav = qra[d];
      float qbv = vbq ? qrb[d] : 0.f;
      float k0 = Kt[d * LKP + lane];
      float k1 = Kt[d * LKP + 64 + lane];
      float k2 = Kt[d * LKP + 128 + lane];
      float k3 = Kt[d * LKP + 192 + lane];
      float k4 = Kt[d * LKP + 256 + lane];
      sa[0] += qav * k0; sa[1] += qav * k1; sa[2] += qav * k2;
      sa[3] += qav * k3; sa[4] += qav * k4;
      sb[0] += qbv * k0; sb[1] += qbv * k1; sb[2] += qbv * k2;
      sb[3] += qbv * k3; sb[4] += qbv * k4;
    }
    bool tl = (lane < 51);
#pragma unroll
    for (int c = 0; c < 4; ++c) { sa[c] *= 0.25f; sb[c] *= 0.25f; }
    sa[4] = tl ? sa[4] * 0.25f : -1e30f;
    sb[4] = tl ? sb[4] * 0.25f : -1e30f;

    float mxa = fmaxf(fmaxf(fmaxf(sa[0], sa[1]), fmaxf(sa[2], sa[3])), sa[4]);
    float mxb = fmaxf(fmaxf(fmaxf(sb[0], sb[1]), fmaxf(sb[2], sb[3])), sb[4]);
    mxa = wave_max(mxa); mxb = wave_max(mxb);
    float ea[5], eb[5], suma = 0.f, sumb = 0.f;
#pragma unroll
    for (int c = 0; c < 5; ++c) {
      ea[c] = __expf(sa[c] - mxa); suma += ea[c];
      eb[c] = __expf(sb[c] - mxb); sumb += eb[c];
    }
    suma = wave_sum(suma); sumb = wave_sum(sumb);
    float ia = 1.f / suma, ib = 1.f / sumb;
#pragma unroll
    for (int c = 0; c < 4; ++c) {
      PA[c * 64 + lane] = ea[c] * ia;
      PB[c * 64 + lane] = eb[c] * ib;
    }
    if (lane < 56) {
      PA[256 + lane] = tl ? ea[4] * ia : 0.f;
      PB[256 + lane] = tl ? eb[4] * ib : 0.f;
    }

    int p = lane >> 4, d = lane & 15;
    float aa = 0.f, ab = 0.f;
    int r0 = 39 * p;
#pragma unroll 13
    for (int i = 0; i < 39; ++i) {
      int m0 = r0 + i, m1 = m0 + 156;
      float v0 = Vt[d * LKP + m0];
      float v1 = Vt[d * LKP + m1];
      aa += PA[m0] * v0 + PA[m1] * v1;
      ab += PB[m0] * v0 + PB[m1] * v1;
    }
    aa += __shfl_xor(aa, 16); aa += __shfl_xor(aa, 32);
    ab += __shfl_xor(ab, 16); ab += __shfl_xor(ab, 32);
    if (p == 0) {
      O[obase + (long)ql * 64 + d] = __float2bfloat16(aa);
      if (vbq) O[obase + (long)(ql + 1) * 64 + d] = __float2bfloat16(ab);
    }
  }
}

// ---------------------------------------------------------------------------
// Generic flat-row MFMA GEMM for the scan: C[M=ROWS,N] = A[RPAD,K]@BT^T +bias
// ---------------------------------------------------------------------------
template <int K, int N, int RELU>
__global__ __launch_bounds__(256) void gemm_scan(
    const __hip_bfloat16* __restrict__ A, const __hip_bfloat16* __restrict__ BT,
    const float* __restrict__ bias, float* __restrict__ Cf,
    __hip_bfloat16* __restrict__ Cb)
{
  int tid = threadIdx.x, w = tid >> 6, l = tid & 63;
  int m0 = blockIdx.x * 64 + w * 16;
  int cq = l & 15, rq = l >> 4;
  constexpr int NK = K / 32;

  short8 af[NK];
  const short* Ap = (const short*)A + (long)(m0 + cq) * K + rq * 8;
#pragma unroll
  for (int kk = 0; kk < NK; ++kk) af[kk] = *(const short8*)(Ap + kk * 32);

#pragma unroll
  for (int nt = 0; nt < N / 16; ++nt) {
    const short* Bp = (const short*)BT + (long)(nt * 16 + cq) * K + rq * 8;
    floatx4 acc = {0.f, 0.f, 0.f, 0.f};
#pragma unroll
    for (int kk = 0; kk < NK; ++kk)
      acc = MFMA_B16(af[kk], *(const short8*)(Bp + kk * 32), acc);
    int c = nt * 16 + cq;
    float bv = bias ? bias[c] : 0.f;
#pragma unroll
    for (int r = 0; r < 4; ++r) {
      int row = m0 + rq * 4 + r;
      if (row < ROWS) {
        float v = acc[r] + bv;
        if (RELU) v = fmaxf(v, 0.f);
        if (Cf) Cf[(long)row * N + c] = v;
        if (Cb) Cb[(long)row * N + c] = __float2bfloat16(v);
      }
    }
  }
}

// h1 = LN(z + o2; ln1); writes fp32 + bf16
__global__ __launch_bounds__(256) void ln1_kernel(
    const float* __restrict__ Z, const float* __restrict__ O2,
    const float* __restrict__ g, const float* __restrict__ b,
    float* __restrict__ H1, __hip_bfloat16* __restrict__ H1b)
{
  int row = blockIdx.x * 4 + (threadIdx.x >> 6);
  if (row >= ROWS) return;
  int lane = threadIdx.x & 63;
  long p = (long)row * 64 + lane;
  float x = Z[zoff_of_row(row, nullptr, nullptr) + lane] + O2[p];
  float m = wave_sum(x) * (1.f / 64.f);
  float d = x - m;
  float v = wave_sum(d * d) * (1.f / 64.f);
  float h = d * rsqrtf(v + 1e-5f) * g[lane] + b[lane];
  H1[p] = h;
  H1b[p] = __float2bfloat16(h);
}

// t = tanh(LN(h1+ff; ln2)); Z += t*x2s[iter]; also writes Zb (bf16) for next iter
__global__ __launch_bounds__(256) void ln2_update(
    const float* __restrict__ H1, const float* __restrict__ FF,
    const float* __restrict__ g2, const float* __restrict__ b2,
    const float* __restrict__ C2, const float* __restrict__ W_tp2,
    const float* __restrict__ b_tp2,
    float* __restrict__ Z, __hip_bfloat16* __restrict__ Zb, int iter)
{
  int row = blockIdx.x * 4 + (threadIdx.x >> 6);   // (b*S+s)*N + n
  if (row >= ROWS) return;
  int lane = threadIdx.x & 63;
  long p = (long)row * 64 + lane;
  float x = H1[p] + FF[p];
  float m = wave_sum(x) * (1.f / 64.f);
  float d = x - m;
  float v = wave_sum(d * d) * (1.f / 64.f);
  float t = tanhf(d * rsqrtf(v + 1e-5f) * g2[lane] + b2[lane]);

  int s1; long bn;
  long zo = zoff_of_row(row, &s1, &bn);
  float acc = b_tp2[s1 * SS + iter];
#pragma unroll
  for (int s = 0; s < SS; ++s)
    acc += C2[(bn * SS + s) * 64 + lane] * W_tp2[s * (SS * SS) + s1 * SS + iter];

  float zn = Z[zo + lane] + t * acc;
  Z[zo + lane] = zn;
  int b = (int)(bn / NN), n = (int)(bn - (long)b * NN);
  Zb[(((long)(b * SS + s1)) * NP + n) * 64 + lane] = __float2bfloat16(zn);
}

// gp: out[b,o,n] = w_het * (sum_{t,h} g[b,t,n,h]*Wgo[t*H+h,o] + bgo[o])
__global__ __launch_bounds__(64) void gp_kernel(const float* __restrict__ g,
                                                const float* __restrict__ Wgo,
                                                const float* __restrict__ bgo,
                                                const float* __restrict__ w_het,
                                                float* __restrict__ out)
{
  int bn = blockIdx.x;
  int b = bn / NN, n = bn % NN;
  __shared__ float buf[TT * 64];
  for (int idx = threadIdx.x; idx < TT * 64; idx += 64) {
    int t = idx >> 6, h = idx & 63;
    buf[idx] = g[(((long)(b * TT + t)) * NN + n) * 64 + h];
  }
  __syncthreads();
  int o = threadIdx.x;
  if (o < 12) {
    float acc = bgo[o];
    for (int j = 0; j < TT * 64; ++j) acc += buf[j] * Wgo[j * 12 + o];
    out[((long)b * 12 + o) * NN + n] = w_het[0] * acc;
  }
}

// zT = LN(z[:,:,S-1,:]; lnf);  out[b,o,n] += w_acl*(zT@W_end + b_end)
__global__ __launch_bounds__(64) void final_acl(const float* __restrict__ z,
                                                const float* __restrict__ lnf_g,
                                                const float* __restrict__ lnf_b,
                                                const float* __restrict__ W_end,
                                                const float* __restrict__ b_end,
                                                const float* __restrict__ w_acl,
                                                float* __restrict__ out)
{
  int bn = blockIdx.x;
  int lane = threadIdx.x;
  int b = bn / NN, n = bn % NN;
  float x = z[((long)bn * SS + (SS - 1)) * 64 + lane];
  float m = wave_sum(x) * (1.f / 64.f);
  float d = x - m;
  float v = wave_sum(d * d) * (1.f / 64.f);
  float zT = d * rsqrtf(v + 1e-5f) * lnf_g[lane] + lnf_b[lane];
  float wa = w_acl[0];
  for (int o = 0; o < 12; ++o) {
    float p = zT * W_end[lane * 12 + o];
    p = wave_sum(p);
    if (lane == 0) {
      long oi = ((long)b * 12 + o) * NN + n;
      out[oi] = out[oi] + wa * (p + b_end[o]);
    }
  }
}

// ---------------------------------------------------------------------------
extern "C" void kernel_launch(void* const* d_in, const int* in_sizes, int n_in,
                              void* d_out, int out_size, void* d_ws, size_t ws_size,
                              hipStream_t stream)
{
  (void)in_sizes; (void)n_in; (void)out_size; (void)ws_size;

  const float* ori_x    = (const float*)d_in[0];
  const float* coeff2   = (const float*)d_in[2];
  const float* W_val    = (const float*)d_in[5];
  const float* b_val    = (const float*)d_in[6];
  const float* tod_emb  = (const float*)d_in[7];
  const float* dow_emb  = (const float*)d_in[8];
  const float* node_emb = (const float*)d_in[9];
  const float* W_in     = (const float*)d_in[10];
  const float* b_in     = (const float*)d_in[11];
  const float* W_ce     = (const float*)d_in[12];
  const float* b_ce     = (const float*)d_in[13];
  const float* W_tp2    = (const float*)d_in[14];
  const float* b_tp2    = (const float*)d_in[15];
  const float* Wq = (const float*)d_in[20];
  const float* Wk = (const float*)d_in[21];
  const float* Wv = (const float*)d_in[22];
  const float* Wo = (const float*)d_in[23];
  const float* bq = (const float*)d_in[24];
  const float* bk = (const float*)d_in[25];
  const float* bv = (const float*)d_in[26];
  const float* bo = (const float*)d_in[27];
  const float* ln1_g = (const float*)d_in[28];
  const float* ln1_b = (const float*)d_in[29];
  const float* Wf1   = (const float*)d_in[30];
  const float* bf1   = (const float*)d_in[31];
  const float* Wf2   = (const float*)d_in[32];
  const float* bf2   = (const float*)d_in[33];
  const float* ln2_g = (const float*)d_in[34];
  const float* ln2_b = (const float*)d_in[35];
  const float* lnf_g = (const float*)d_in[36];
  const float* lnf_b = (const float*)d_in[37];
  const float* W_end = (const float*)d_in[38];
  const float* b_end = (const float*)d_in[39];
  const float* w_acl = (const float*)d_in[40];
  const float* w_het = (const float*)d_in[41];
  const float* adj     = (const float*)d_in[42];
  const float* adj_sem = (const float*)d_in[43];
  const float* Wg1 = (const float*)d_in[44];
  const float* Wg2 = (const float*)d_in[45];
  const float* bg  = (const float*)d_in[46];
  const float* Wgo = (const float*)d_in[47];
  const float* bgo = (const float*)d_in[48];
  float* out = (float*)d_out;
  float* ws  = (float*)d_ws;

  const int ROWS_TN = BB * TT * NN;   // 14736
  const int ROWS_BN = BB * NN;        // 1228

  // ---- workspace layout (float offsets, all 16-float aligned) ----
  float* Z     = ws;                             // 864512
  float* C2    = ws + 864512;                    // 864512
  __hip_bfloat16* Zb    = (__hip_bfloat16*)(ws + 1729024);   // 44*320*64 bf16
  __hip_bfloat16* WinT  = (__hip_bfloat16*)(ws + 2179584);   // 704*1824 bf16
  __hip_bfloat16* WqkvT = (__hip_bfloat16*)(ws + 2821632);   // 192*64
  __hip_bfloat16* WoT   = (__hip_bfloat16*)(ws + 2827776);   // 64*64
  __hip_bfloat16* Wf1T  = (__hip_bfloat16*)(ws + 2829824);   // 256*64
  __hip_bfloat16* Wf2T  = (__hip_bfloat16*)(ws + 2838016);   // 64*256
  float* BQKV  = ws + 2846208;                   // 192 (+pad)
  float* POOL  = ws + 2846416;
  // phase 1
  float* XEMB = POOL;                            // 2239872 [B,T,N,152]
  __hip_bfloat16* XEMBT = (__hip_bfloat16*)(POOL + 2239872); // 1228*1824 bf16
  float* XGP  = POOL + 3359808;                  // 1886208 [B,T,N,128]
  float* G    = POOL + 5246016;                  // 943104
  float* WGP  = POOL + 6189120;                  // 19456
  // phase 2 (overlays phase 1)
  float* Qa = POOL;                              // 901120 [bs,NP,64]
  float* KT = POOL + 901120;                     // 878592 [bs,64,KTP]
  float* VT = POOL + 1779712;                    // 878592
  __hip_bfloat16* Obf  = (__hip_bfloat16*)(POOL + 2658304);  // RPAD*64 bf16
  float* O2 = POOL + 3092480;                    // 868352
  float* H1 = POOL + 3960832;                    // 864512
  __hip_bfloat16* H1b  = (__hip_bfloat16*)(POOL + 4825344);  // RPAD*64 bf16
  __hip_bfloat16* FFHb = (__hip_bfloat16*)(POOL + 5259520);  // RPAD*256 bf16
  float* FF = POOL + 6996224;                    // 864512

  // ---- phase 1 ----
  embed_kernel<<<dim3(8750), dim3(256), 0, stream>>>(
      ori_x, W_val, b_val, tod_emb, dow_emb, node_emb, XEMB, ROWS_TN * EMB);
  transpose_emb<<<dim3(8750), dim3(256), 0, stream>>>(XEMB, XEMBT, ROWS_TN * EMB);
  zinit_kernel<<<dim3(3377), dim3(256), 0, stream>>>(Z, b_in, ROWS_BN * SS * HH);
  // weight converts
  transpose_cvt<<<dim3(57, 22), dim3(256), 0, stream>>>(W_in, WinT, 1824, 704);
  transpose_cvt<<<dim3(2, 2), dim3(256), 0, stream>>>(Wq, WqkvT, 64, 64);
  transpose_cvt<<<dim3(2, 2), dim3(256), 0, stream>>>(Wk, WqkvT + 64 * 64, 64, 64);
  transpose_cvt<<<dim3(2, 2), dim3(256), 0, stream>>>(Wv, WqkvT + 128 * 64, 64, 64);
  transpose_cvt<<<dim3(2, 2), dim3(256), 0, stream>>>(Wo, WoT, 64, 64);
  transpose_cvt<<<dim3(2, 8), dim3(256), 0, stream>>>(Wf1, Wf1T, 64, 256);
  transpose_cvt<<<dim3(8, 2), dim3(256), 0, stream>>>(Wf2, Wf2T, 256, 64);
  pack_bias<<<dim3(1), dim3(64), 0, stream>>>(bq, bk, bv, BQKV);
  // x_in (bf16 MFMA, split-K 4)
  gemm_xin<<<dim3(20, 11, 4), dim3(256), 0, stream>>>(XEMBT, WinT, Z);
  c2_kernel<<<dim3(ROWS_BN * SS), dim3(64), 0, stream>>>(coeff2, W_ce, b_ce, C2);
  pack_wg<<<dim3(76), dim3(256), 0, stream>>>(Wg1, Wg2, WGP);
  gemm_kernel<<<dim3(231, 2, 1), dim3(256), 0, stream>>>(
      XEMB, EMB, 0L, WGP, 128, 0L, XGP, 128, 0L, nullptr, ROWS_TN, 128, EMB, 0);
  gemm_kernel<<<dim3(5, 1, 48), dim3(256), 0, stream>>>(
      adj, NN, 0L, XGP, 128, (long)NN * 128, G, HH, (long)NN * HH, nullptr,
      NN, HH, NN, 0);
  gemm_kernel<<<dim3(5, 1, 48), dim3(256), 0, stream>>>(
      adj_sem, NN, 0L, XGP + 64, 128, (long)NN * 128, G, HH, (long)NN * HH, bg,
      NN, HH, NN, GF_ACCUM | GF_BIAS | GF_RELU);
  gp_kernel<<<dim3(ROWS_BN), dim3(64), 0, stream>>>(G, Wgo, bgo, w_het, out);
  ztbf_kernel<<<dim3(NBS * NP / 4), dim3(256), 0, stream>>>(Z, Zb);

  // ---- phase 2: Euler scan, 11 steps ----
  for (int i = 0; i < SS; ++i) {
    qkv_mfma<<<dim3(NBS, 5), dim3(256), 0, stream>>>(Zb, WqkvT, BQKV, Qa, KT, VT);
    attn_kernel<<<dim3(NBS * NHH, 13), dim3(256), 0, stream>>>(Qa, KT, VT, Obf);
    gemm_scan<64, 64, 0><<<dim3(212), dim3(256), 0, stream>>>(
        Obf, WoT, bo, O2, nullptr);
    ln1_kernel<<<dim3(3377), dim3(256), 0, stream>>>(Z, O2, ln1_g, ln1_b, H1, H1b);
    gemm_scan<64, 256, 1><<<dim3(212), dim3(256), 0, stream>>>(
        H1b, Wf1T, bf1, nullptr, FFHb);
    gemm_scan<256, 64, 0><<<dim3(212), dim3(256), 0, stream>>>(
        FFHb, Wf2T, bf2, FF, nullptr);
    ln2_update<<<dim3(3377), dim3(256), 0, stream>>>(
        H1, FF, ln2_g, ln2_b, C2, W_tp2, b_tp2, Z, Zb, i);
  }

  // ---- epilogue ----
  final_acl<<<dim3(ROWS_BN), dim3(64), 0, stream>>>(
      Z, lnf_g, lnf_b, W_end, b_end, w_acl, out);
}

// Round 6
// 1152.668 us; speedup vs baseline: 3.2517x; 1.5456x over previous
//
#include <hip/hip_runtime.h>
#include <hip/hip_bf16.h>
#include <math.h>

// Problem dims
#define BB   4
#define TT   12
#define NN   307
#define SS   11
#define HH   64
#define NHH  4
#define DHH  16
#define EMB  152
#define ROWS 13508          // B*S*N
#define NBS  44             // B*S
#define NP   320            // padded node count
#define RPAD 13568          // 212*64 padded flat rows
#define KLP  24             // LDS K pitch (shorts; 48B rows -> 16B-aligned b128 reads)
#define VLP  336            // LDS V^T pitch (shorts; 672B rows -> 16B-aligned)
#define PLP  40             // LDS P chunk pitch (shorts)

#define GF_BIAS  1
#define GF_RELU  2
#define GF_ACCUM 4

typedef short short8 __attribute__((ext_vector_type(8)));   // 8 bf16
typedef short short4a __attribute__((ext_vector_type(4)));  // 4 bf16
typedef float floatx4 __attribute__((ext_vector_type(4)));
#define MFMA_B16(a, b, c) __builtin_amdgcn_mfma_f32_16x16x32_bf16(a, b, c, 0, 0, 0)

__device__ __forceinline__ float wave_sum(float v) {
#pragma unroll
  for (int off = 32; off; off >>= 1) v += __shfl_xor(v, off);
  return v;
}
__device__ __forceinline__ short f2bf(float x) {
  __hip_bfloat16 h = __float2bfloat16(x);
  return *reinterpret_cast<short*>(&h);
}
// row r in (b,s,n) order -> flat offset of the 64-float row in Z ([b,n,s,h])
__device__ __forceinline__ long zoff_of_row(int r, int* s_out, long* bn_out) {
  int b = r / (SS * NN);
  int rem = r - b * (SS * NN);
  int s = rem / NN;
  int n = rem - s * NN;
  long bn = (long)b * NN + n;
  if (s_out) *s_out = s;
  if (bn_out) *bn_out = bn;
  return (bn * SS + s) * 64;
}

// ---------------------------------------------------------------------------
// fp32 tiled GEMM (phase-1 GCN matmuls only)
// ---------------------------------------------------------------------------
__global__ __launch_bounds__(256) void gemm_kernel(
    const float* __restrict__ A, int lda, long strideA,
    const float* __restrict__ B, int ldb, long strideB,
    float* __restrict__ C, int ldc, long strideC,
    const float* __restrict__ bias,
    int M, int N, int K, int flags)
{
  int bt = blockIdx.z;
  A += (long)bt * strideA;
  B += (long)bt * strideB;
  C += (long)bt * strideC;
  int m0 = blockIdx.x * 64, n0 = blockIdx.y * 64;

  __shared__ __align__(16) float As[16][68];
  __shared__ __align__(16) float Bs[16][64];

  int tid = threadIdx.x;
  int tx = tid & 15, ty = tid >> 4;
  float acc[4][4] = {};

  for (int k0 = 0; k0 < K; k0 += 16) {
#pragma unroll
    for (int l = 0; l < 4; ++l) {
      int idx = tid + l * 256;
      int m = idx >> 4, k = idx & 15;
      float v = 0.f;
      if (m0 + m < M && k0 + k < K) v = A[(long)(m0 + m) * lda + k0 + k];
      As[k][m] = v;
    }
#pragma unroll
    for (int l = 0; l < 4; ++l) {
      int idx = tid + l * 256;
      int k = idx >> 6, n = idx & 63;
      float v = 0.f;
      if (k0 + k < K && n0 + n < N) v = B[(long)(k0 + k) * ldb + n0 + n];
      Bs[k][n] = v;
    }
    __syncthreads();
#pragma unroll
    for (int k = 0; k < 16; ++k) {
      float4 a4 = *reinterpret_cast<const float4*>(&As[k][ty * 4]);
      float4 b4 = *reinterpret_cast<const float4*>(&Bs[k][tx * 4]);
      float a[4] = {a4.x, a4.y, a4.z, a4.w};
      float b[4] = {b4.x, b4.y, b4.z, b4.w};
#pragma unroll
      for (int i = 0; i < 4; ++i)
#pragma unroll
        for (int j = 0; j < 4; ++j)
          acc[i][j] += a[i] * b[j];
    }
    __syncthreads();
  }

#pragma unroll
  for (int i = 0; i < 4; ++i) {
    int m = m0 + ty * 4 + i;
    if (m >= M) continue;
#pragma unroll
    for (int j = 0; j < 4; ++j) {
      int n = n0 + tx * 4 + j;
      if (n >= N) continue;
      float v = acc[i][j];
      if (flags & GF_ACCUM) v += C[(long)m * ldc + n];
      if (flags & GF_BIAS)  v += bias[n];
      if (flags & GF_RELU)  v = fmaxf(v, 0.f);
      C[(long)m * ldc + n] = v;
    }
  }
}

// transpose + scale + fp32->bf16: out[N,K] = scale * in[K,N]^T
__global__ __launch_bounds__(256) void transpose_cvt(
    const float* __restrict__ in, __hip_bfloat16* __restrict__ out,
    int K, int N, float scale)
{
  __shared__ float t[32][33];
  int k0 = blockIdx.x * 32, n0 = blockIdx.y * 32;
  int tx = threadIdx.x & 31, ty = threadIdx.x >> 5;
#pragma unroll
  for (int i = 0; i < 32; i += 8) {
    int k = k0 + ty + i, n = n0 + tx;
    if (k < K && n < N) t[ty + i][tx] = in[(long)k * N + n];
  }
  __syncthreads();
#pragma unroll
  for (int i = 0; i < 32; i += 8) {
    int n = n0 + ty + i, k = k0 + tx;
    if (k < K && n < N)
      out[(long)n * K + k] = __float2bfloat16(t[tx][ty + i] * scale);
  }
}

__global__ void pack_bias(const float* __restrict__ bq, const float* __restrict__ bk,
                          const float* __restrict__ bv, float* __restrict__ bqkv)
{
  int t = threadIdx.x;
  if (t < 64) {
    bqkv[t] = bq[t] * 0.25f;   // score scale folded into q
    bqkv[64 + t] = bk[t];
    bqkv[128 + t] = bv[t];
  }
}

__global__ void zinit_kernel(float* __restrict__ Z, const float* __restrict__ b_in,
                             int total)
{
  int idx = blockIdx.x * 256 + threadIdx.x;
  if (idx < total) Z[idx] = b_in[idx % (SS * HH)];
}

// ---------------------------------------------------------------------------
// DataEmbedding
// ---------------------------------------------------------------------------
__global__ void embed_kernel(const float* __restrict__ ori,
                             const float* __restrict__ W_val,
                             const float* __restrict__ b_val,
                             const float* __restrict__ tod_emb,
                             const float* __restrict__ dow_emb,
                             const float* __restrict__ node_emb,
                             float* __restrict__ x_emb, int total)
{
  int idx = blockIdx.x * 256 + threadIdx.x;
  if (idx >= total) return;
  int c = idx % EMB;
  int r = idx / EMB;            // (b*T + t)*N + n
  int n = r % NN;
  float v;
  if (c < 24) {
    const float* x = ori + (long)r * 3;
    v = x[0] * W_val[c] + x[1] * W_val[24 + c] + x[2] * W_val[48 + c] + b_val[c];
  } else if (c < 48) {
    float f = ori[(long)r * 3 + 1];
    f = f - floorf(f);
    int tod = (int)(f * 288.f);
    tod = min(max(tod, 0), 287);
    v = tod_emb[tod * 24 + (c - 24)];
  } else if (c < 72) {
    float f = ori[(long)r * 3 + 2];
    f = f - floorf(f);
    int dow = (int)(f * 7.f);
    dow = min(max(dow, 0), 6);
    v = dow_emb[dow * 24 + (c - 48)];
  } else {
    v = node_emb[n * 80 + (c - 72)];
  }
  x_emb[idx] = v;
}

__global__ void transpose_emb(const float* __restrict__ x_emb,
                              __hip_bfloat16* __restrict__ x_embT, int total)
{
  int idx = blockIdx.x * 256 + threadIdx.x;
  if (idx >= total) return;
  int c = idx % EMB;
  int r = idx / EMB;            // (b*N + n)*T + t
  int t = r % TT;
  int r2 = r / TT;
  int n = r2 % NN;
  int b = r2 / NN;
  x_embT[idx] = __float2bfloat16(x_emb[(((long)(b * TT + t)) * NN + n) * EMB + c]);
}

__global__ void c2_kernel(const float* __restrict__ coeff2,
                          const float* __restrict__ W_ce,
                          const float* __restrict__ b_ce,
                          float* __restrict__ c2)
{
  int row = blockIdx.x;         // (b*N+n)*S + s
  int h = threadIdx.x;
  float a0 = coeff2[(long)row * 2];
  float a1 = coeff2[(long)row * 2 + 1];
  c2[(long)row * 64 + h] = a0 * W_ce[h] + a1 * W_ce[64 + h] + b_ce[h];
}

__global__ void pack_wg(const float* __restrict__ Wg1, const float* __restrict__ Wg2,
                        float* __restrict__ WGP)
{
  int idx = blockIdx.x * 256 + threadIdx.x;
  if (idx >= EMB * 128) return;
  int k = idx >> 7, c = idx & 127;
  WGP[idx] = (c < 64) ? Wg1[k * 64 + c] : Wg2[k * 64 + c - 64];
}

// ---------------------------------------------------------------------------
// x_in GEMM, bf16 MFMA, split-K=4, atomicAdd into bias-initialized Z.
// ---------------------------------------------------------------------------
__global__ __launch_bounds__(256) void gemm_xin(
    const __hip_bfloat16* __restrict__ A, const __hip_bfloat16* __restrict__ BT,
    float* __restrict__ C)
{
  int tid = threadIdx.x, w = tid >> 6, l = tid & 63;
  int m0 = blockIdx.x * 64 + w * 16;
  int n0 = blockIdx.y * 64;
  int k0s = blockIdx.z * 480;
  int k0e = min(1824, k0s + 480);

  int cq = l & 15, rq = l >> 4;
  int arow = min(m0 + cq, 1227);
  const short* Ap = (const short*)A + (long)arow * 1824 + rq * 8;
  const short* Bp = (const short*)BT + rq * 8;

  floatx4 acc[4] = {};
  for (int k0 = k0s; k0 < k0e; k0 += 32) {
    short8 a = *(const short8*)(Ap + k0);
#pragma unroll
    for (int nt = 0; nt < 4; ++nt) {
      short8 b = *(const short8*)(Bp + (long)(n0 + nt * 16 + cq) * 1824 + k0);
      acc[nt] = MFMA_B16(a, b, acc[nt]);
    }
  }
#pragma unroll
  for (int nt = 0; nt < 4; ++nt) {
    int c = n0 + nt * 16 + cq;
#pragma unroll
    for (int r = 0; r < 4; ++r) {
      int row = m0 + rq * 4 + r;
      if (row < 1228) atomicAdd(&C[(long)row * 704 + c], acc[nt][r]);
    }
  }
}

// Z (fp32, [b,n,s,h]) -> Zb (bf16, [bs, node(pad 320), 64]); pads zero-filled.
__global__ __launch_bounds__(256) void ztbf_kernel(const float* __restrict__ Z,
                                                   __hip_bfloat16* __restrict__ Zb)
{
  int row = blockIdx.x * 4 + (threadIdx.x >> 6);
  if (row >= NBS * NP) return;
  int lane = threadIdx.x & 63;
  int bs = row / NP, node = row - bs * NP;
  int b = bs / SS, s = bs - b * SS;
  float v = 0.f;
  if (node < NN) v = Z[(((long)(b * NN + node)) * SS + s) * 64 + lane];
  Zb[(long)row * 64 + lane] = __float2bfloat16(v);
}

// ---------------------------------------------------------------------------
// QKV projection, per-bs MFMA. Emits bf16 Qb/Kb [bs,NP,64], Vtb [bs,64,NP].
// ---------------------------------------------------------------------------
__global__ __launch_bounds__(256) void qkv_mfma(
    const __hip_bfloat16* __restrict__ Zb, const __hip_bfloat16* __restrict__ WT,
    const float* __restrict__ bqkv,
    __hip_bfloat16* __restrict__ Qb, __hip_bfloat16* __restrict__ Kb,
    __hip_bfloat16* __restrict__ Vtb)
{
  int bs = blockIdx.x, mt = blockIdx.y;
  int tid = threadIdx.x, w = tid >> 6, l = tid & 63;
  int m0 = mt * 64 + w * 16;
  int cq = l & 15, rq = l >> 4;

  const short* Ap = (const short*)Zb + ((long)bs * NP + m0 + cq) * 64 + rq * 8;
  short8 a0 = *(const short8*)Ap;
  short8 a1 = *(const short8*)(Ap + 32);

#pragma unroll
  for (int nt = 0; nt < 12; ++nt) {
    const short* Bp = (const short*)WT + (long)(nt * 16 + cq) * 64 + rq * 8;
    floatx4 acc = {0.f, 0.f, 0.f, 0.f};
    acc = MFMA_B16(a0, *(const short8*)Bp, acc);
    acc = MFMA_B16(a1, *(const short8*)(Bp + 32), acc);
    int c = nt * 16 + cq;
    float bias = bqkv[c];
#pragma unroll
    for (int r = 0; r < 4; ++r) {
      int node = m0 + rq * 4 + r;
      if (node < NN) {
        __hip_bfloat16 v = __float2bfloat16(acc[r] + bias);
        if (c < 64)       Qb[((long)bs * NP + node) * 64 + c] = v;
        else if (c < 128) Kb[((long)bs * NP + node) * 64 + (c - 64)] = v;
        else              Vtb[((long)bs * 64 + (c - 128)) * NP + node] = v;
      }
    }
  }
}

// ---------------------------------------------------------------------------
// MFMA attention using ONLY the proven 16x16x32 intrinsic.
// Block = (bs*head, 4-group chunk); each wave owns one 16-query group.
// QK^T: k-padded fragments (d=16 in quads 0-1, zeros in quads 2-3).
// P^T: exp'd scores go through a wave-private double-buffered LDS chunk
//      ([q][32keys], no barriers) and re-enter PV as native K=32 B-fragments.
// O^T = V^T@P^T accumulated unnormalized; scaled by 1/sum at the end.
// All pad lanes (keys>=307, queries>=307) are zero-guarded; exp clamped.
// ---------------------------------------------------------------------------
__global__ __launch_bounds__(256) void attn_mfma(
    const __hip_bfloat16* __restrict__ Qb, const __hip_bfloat16* __restrict__ Kb,
    const __hip_bfloat16* __restrict__ Vtb, __hip_bfloat16* __restrict__ O)
{
  int bsh = blockIdx.x;           // bs*NH + head
  int head = bsh & 3;
  int bs = bsh >> 2;

  __shared__ __align__(16) short Kl[NP * KLP];      // K [key][d]
  __shared__ __align__(16) short Vl[16 * VLP];      // V^T [d][key]
  __shared__ __align__(16) short Pd[4][2][16 * PLP];// per-wave P chunk [q][key32]

  int tid = threadIdx.x;
  const short* kg = (const short*)Kb + (long)bs * NP * 64 + head * 16;
  for (int ch = tid; ch < NP * 4; ch += 256) {
    int node = ch >> 2, part = (ch & 3) * 4;
    short4a kv = {0, 0, 0, 0};
    if (node < NN) kv = *(const short4a*)(kg + (long)node * 64 + part);
    *(short4a*)&Kl[node * KLP + part] = kv;
  }
  const short* vg = (const short*)Vtb + ((long)bs * 64 + head * 16) * NP;
  for (int ch = tid; ch < 16 * 80; ch += 256) {
    int d = ch / 80, k4 = (ch % 80) * 4;
    short4a vv = {0, 0, 0, 0};
    if (k4 + 3 < NN) {
      vv = *(const short4a*)(vg + (long)d * NP + k4);
    } else {
#pragma unroll
      for (int j = 0; j < 4; ++j)
        if (k4 + j < NN) vv[j] = vg[(long)d * NP + k4 + j];
    }
    *(short4a*)&Vl[d * VLP + k4] = vv;
  }
  __syncthreads();

  int wave = tid >> 6, lane = tid & 63;
  int m = lane & 15, quad = lane >> 4;
  int gg = blockIdx.y * 4 + wave;     // 16-query group, 0..19
  int q0 = gg * 16;
  int qv = q0 + m;                    // this lane's query column

  const short8 z8 = {0, 0, 0, 0, 0, 0, 0, 0};
  const floatx4 zf = {0.f, 0.f, 0.f, 0.f};

  // Q^T B-fragment (k-padded: quads 2,3 zero; pad queries zero)
  short8 qf = z8;
  if (quad < 2 && qv < NN)
    qf = *(const short8*)((const short*)Qb +
        ((long)bs * NP + qv) * 64 + head * 16 + quad * 8);

  short* Pw0 = &Pd[wave][0][0];
  short* Pw1 = &Pd[wave][1][0];

  float sum = 0.f;
  floatx4 oa = zf, ob = zf;

  for (int c = 0; c < 10; ++c) {
    // ---- QK^T for key tiles 2c, 2c+1 (keys c*32 .. c*32+31) ----
    short8 kf0 = z8, kf1 = z8;
    if (quad < 2) {
      kf0 = *(const short8*)&Kl[((2 * c) * 16 + m) * KLP + quad * 8];
      kf1 = *(const short8*)&Kl[((2 * c + 1) * 16 + m) * KLP + quad * 8];
    }
    floatx4 s0 = MFMA_B16(kf0, qf, zf);
    floatx4 s1 = MFMA_B16(kf1, qf, zf);

    // exp (clamped; no max-sub: scale folded into Wq keeps |s| small)
    float e0[4], e1[4];
#pragma unroll
    for (int j = 0; j < 4; ++j) {
      e0[j] = __expf(fminf(s0[j], 30.f));
      e1[j] = __expf(fminf(s1[j], 30.f));
    }
    if (c == 9) {                    // tile 19: keys 304+quad*4+reg; valid < 307
      if (quad == 0) e1[3] = 0.f;
      else { e1[0] = 0.f; e1[1] = 0.f; e1[2] = 0.f; e1[3] = 0.f; }
    }
    sum += e0[0] + e0[1] + e0[2] + e0[3] + e1[0] + e1[1] + e1[2] + e1[3];

    // pack to bf16, store P chunk [q=m][key-in-chunk]
    short4a p0, p1;
#pragma unroll
    for (int j = 0; j < 4; ++j) { p0[j] = f2bf(e0[j]); p1[j] = f2bf(e1[j]); }
    short* Pw = (c & 1) ? Pw1 : Pw0;
    *(short4a*)&Pw[m * PLP + quad * 4] = p0;
    *(short4a*)&Pw[m * PLP + 16 + quad * 4] = p1;

    // read back as native K=32 B-fragment: B[k=quad*8+j][n=q=m]
    short8 pf = *(const short8*)&Pw[m * PLP + quad * 8];
    // V^T A-fragment: A[m=d][k=key=quad*8+j]
    short8 vf = *(const short8*)&Vl[m * VLP + c * 32 + quad * 8];
    if (c & 1) ob = MFMA_B16(vf, pf, ob);
    else       oa = MFMA_B16(vf, pf, oa);
  }

  // per-query softmax denominator: reduce partial sums across quads
  sum += __shfl_xor(sum, 16);
  sum += __shfl_xor(sum, 32);
  float inv = 1.f / sum;

  if (qv < NN) {
    short4a pk;
#pragma unroll
    for (int r = 0; r < 4; ++r) pk[r] = f2bf((oa[r] + ob[r]) * inv);
    *(short4a*)((short*)O + ((long)bs * NN + qv) * 64 + head * 16 + quad * 4) = pk;
  }
}

// ---------------------------------------------------------------------------
// Fused: o2 = O@Wo + bo; h1 = LN(z + o2; ln1) -> H1b. Two-pass LN (E[d^2]).
// ---------------------------------------------------------------------------
__global__ __launch_bounds__(256) void wo_ln1_mfma(
    const __hip_bfloat16* __restrict__ A, const __hip_bfloat16* __restrict__ BT,
    const float* __restrict__ bo, const float* __restrict__ Zf,
    const float* __restrict__ g, const float* __restrict__ bb,
    __hip_bfloat16* __restrict__ H1b)
{
  int tid = threadIdx.x, w = tid >> 6, l = tid & 63;
  int m0 = blockIdx.x * 64 + w * 16;
  int cq = l & 15, rq = l >> 4;

  const short* Ap = (const short*)A + (long)(m0 + cq) * 64 + rq * 8;
  short8 a0 = *(const short8*)Ap;
  short8 a1 = *(const short8*)(Ap + 32);

  float x[4][4];                      // [nt][r]
#pragma unroll
  for (int nt = 0; nt < 4; ++nt) {
    const short* Bp = (const short*)BT + (long)(nt * 16 + cq) * 64 + rq * 8;
    floatx4 acc = {0.f, 0.f, 0.f, 0.f};
    acc = MFMA_B16(a0, *(const short8*)Bp, acc);
    acc = MFMA_B16(a1, *(const short8*)(Bp + 32), acc);
    float bv = bo[nt * 16 + cq];
#pragma unroll
    for (int r = 0; r < 4; ++r) x[nt][r] = acc[r] + bv;
  }
#pragma unroll
  for (int r = 0; r < 4; ++r) {
    int row = m0 + rq * 4 + r;
    long zo = zoff_of_row(min(row, ROWS - 1), nullptr, nullptr);
#pragma unroll
    for (int nt = 0; nt < 4; ++nt) x[nt][r] += Zf[zo + nt * 16 + cq];
  }
  float gv[4], bv2[4];
#pragma unroll
  for (int nt = 0; nt < 4; ++nt) { gv[nt] = g[nt * 16 + cq]; bv2[nt] = bb[nt * 16 + cq]; }

#pragma unroll
  for (int r = 0; r < 4; ++r) {
    float s = x[0][r] + x[1][r] + x[2][r] + x[3][r];
#pragma unroll
    for (int off = 1; off <= 8; off <<= 1) s += __shfl_xor(s, off);
    float mean = s * (1.f / 64.f);
    float vs = 0.f;
#pragma unroll
    for (int nt = 0; nt < 4; ++nt) {
      float d = x[nt][r] - mean;
      vs += d * d;
    }
#pragma unroll
    for (int off = 1; off <= 8; off <<= 1) vs += __shfl_xor(vs, off);
    float rstd = rsqrtf(vs * (1.f / 64.f) + 1e-5f);
    int row = m0 + rq * 4 + r;
    if (row < ROWS) {
#pragma unroll
      for (int nt = 0; nt < 4; ++nt)
        H1b[(long)row * 64 + nt * 16 + cq] =
            __float2bfloat16((x[nt][r] - mean) * rstd * gv[nt] + bv2[nt]);
    }
  }
}

// ---------------------------------------------------------------------------
// Flat-row MFMA GEMM for the scan
// ---------------------------------------------------------------------------
template <int K, int N, int RELU>
__global__ __launch_bounds__(256) void gemm_scan(
    const __hip_bfloat16* __restrict__ A, const __hip_bfloat16* __restrict__ BT,
    const float* __restrict__ bias, float* __restrict__ Cf,
    __hip_bfloat16* __restrict__ Cb)
{
  int tid = threadIdx.x, w = tid >> 6, l = tid & 63;
  int m0 = blockIdx.x * 64 + w * 16;
  int cq = l & 15, rq = l >> 4;
  constexpr int NK = K / 32;

  short8 af[NK];
  const short* Ap = (const short*)A + (long)(m0 + cq) * K + rq * 8;
#pragma unroll
  for (int kk = 0; kk < NK; ++kk) af[kk] = *(const short8*)(Ap + kk * 32);

#pragma unroll
  for (int nt = 0; nt < N / 16; ++nt) {
    const short* Bp = (const short*)BT + (long)(nt * 16 + cq) * K + rq * 8;
    floatx4 acc = {0.f, 0.f, 0.f, 0.f};
#pragma unroll
    for (int kk = 0; kk < NK; ++kk)
      acc = MFMA_B16(af[kk], *(const short8*)(Bp + kk * 32), acc);
    int c = nt * 16 + cq;
    float bv = bias ? bias[c] : 0.f;
#pragma unroll
    for (int r = 0; r < 4; ++r) {
      int row = m0 + rq * 4 + r;
      if (row < ROWS) {
        float v = acc[r] + bv;
        if (RELU) v = fmaxf(v, 0.f);
        if (Cf) Cf[(long)row * N + c] = v;
        if (Cb) Cb[(long)row * N + c] = __float2bfloat16(v);
      }
    }
  }
}

// t = tanh(LN(h1+ff; ln2)); Z += t*x2s[iter]; writes Zb (bf16) for next iter
__global__ __launch_bounds__(256) void ln2_update(
    const __hip_bfloat16* __restrict__ H1b, const float* __restrict__ FF,
    const float* __restrict__ g2, const float* __restrict__ b2,
    const float* __restrict__ C2, const float* __restrict__ W_tp2,
    const float* __restrict__ b_tp2,
    float* __restrict__ Z, __hip_bfloat16* __restrict__ Zb, int iter)
{
  int row = blockIdx.x * 4 + (threadIdx.x >> 6);   // (b*S+s)*N + n
  if (row >= ROWS) return;
  int lane = threadIdx.x & 63;
  long p = (long)row * 64 + lane;
  float x = __bfloat162float(H1b[p]) + FF[p];
  float m = wave_sum(x) * (1.f / 64.f);
  float d = x - m;
  float v = wave_sum(d * d) * (1.f / 64.f);
  float t = tanhf(d * rsqrtf(v + 1e-5f) * g2[lane] + b2[lane]);

  int s1; long bn;
  long zo = zoff_of_row(row, &s1, &bn);
  float acc = b_tp2[s1 * SS + iter];
#pragma unroll
  for (int s = 0; s < SS; ++s)
    acc += C2[(bn * SS + s) * 64 + lane] * W_tp2[s * (SS * SS) + s1 * SS + iter];

  float zn = Z[zo + lane] + t * acc;
  Z[zo + lane] = zn;
  int b = (int)(bn / NN), n = (int)(bn - (long)b * NN);
  Zb[(((long)(b * SS + s1)) * NP + n) * 64 + lane] = __float2bfloat16(zn);
}

// gp: out[b,o,n] = w_het * (sum_{t,h} g[b,t,n,h]*Wgo[t*H+h,o] + bgo[o])
__global__ __launch_bounds__(64) void gp_kernel(const float* __restrict__ g,
                                                const float* __restrict__ Wgo,
                                                const float* __restrict__ bgo,
                                                const float* __restrict__ w_het,
                                                float* __restrict__ out)
{
  int bn = blockIdx.x;
  int b = bn / NN, n = bn % NN;
  __shared__ float buf[TT * 64];
  for (int idx = threadIdx.x; idx < TT * 64; idx += 64) {
    int t = idx >> 6, h = idx & 63;
    buf[idx] = g[(((long)(b * TT + t)) * NN + n) * 64 + h];
  }
  __syncthreads();
  int o = threadIdx.x;
  if (o < 12) {
    float acc = bgo[o];
    for (int j = 0; j < TT * 64; ++j) acc += buf[j] * Wgo[j * 12 + o];
    out[((long)b * 12 + o) * NN + n] = w_het[0] * acc;
  }
}

// zT = LN(z[:,:,S-1,:]; lnf);  out[b,o,n] += w_acl*(zT@W_end + b_end)
__global__ __launch_bounds__(64) void final_acl(const float* __restrict__ z,
                                                const float* __restrict__ lnf_g,
                                                const float* __restrict__ lnf_b,
                                                const float* __restrict__ W_end,
                                                const float* __restrict__ b_end,
                                                const float* __restrict__ w_acl,
                                                float* __restrict__ out)
{
  int bn = blockIdx.x;
  int lane = threadIdx.x;
  int b = bn / NN, n = bn % NN;
  float x = z[((long)bn * SS + (SS - 1)) * 64 + lane];
  float m = wave_sum(x) * (1.f / 64.f);
  float d = x - m;
  float v = wave_sum(d * d) * (1.f / 64.f);
  float zT = d * rsqrtf(v + 1e-5f) * lnf_g[lane] + lnf_b[lane];
  float wa = w_acl[0];
  for (int o = 0; o < 12; ++o) {
    float p = zT * W_end[lane * 12 + o];
    p = wave_sum(p);
    if (lane == 0) {
      long oi = ((long)b * 12 + o) * NN + n;
      out[oi] = out[oi] + wa * (p + b_end[o]);
    }
  }
}

// ---------------------------------------------------------------------------
extern "C" void kernel_launch(void* const* d_in, const int* in_sizes, int n_in,
                              void* d_out, int out_size, void* d_ws, size_t ws_size,
                              hipStream_t stream)
{
  (void)in_sizes; (void)n_in; (void)out_size; (void)ws_size;

  const float* ori_x    = (const float*)d_in[0];
  const float* coeff2   = (const float*)d_in[2];
  const float* W_val    = (const float*)d_in[5];
  const float* b_val    = (const float*)d_in[6];
  const float* tod_emb  = (const float*)d_in[7];
  const float* dow_emb  = (const float*)d_in[8];
  const float* node_emb = (const float*)d_in[9];
  const float* W_in     = (const float*)d_in[10];
  const float* b_in     = (const float*)d_in[11];
  const float* W_ce     = (const float*)d_in[12];
  const float* b_ce     = (const float*)d_in[13];
  const float* W_tp2    = (const float*)d_in[14];
  const float* b_tp2    = (const float*)d_in[15];
  const float* Wq = (const float*)d_in[20];
  const float* Wk = (const float*)d_in[21];
  const float* Wv = (const float*)d_in[22];
  const float* Wo = (const float*)d_in[23];
  const float* bq = (const float*)d_in[24];
  const float* bk = (const float*)d_in[25];
  const float* bv = (const float*)d_in[26];
  const float* bo = (const float*)d_in[27];
  const float* ln1_g = (const float*)d_in[28];
  const float* ln1_b = (const float*)d_in[29];
  const float* Wf1   = (const float*)d_in[30];
  const float* bf1   = (const float*)d_in[31];
  const float* Wf2   = (const float*)d_in[32];
  const float* bf2   = (const float*)d_in[33];
  const float* ln2_g = (const float*)d_in[34];
  const float* ln2_b = (const float*)d_in[35];
  const float* lnf_g = (const float*)d_in[36];
  const float* lnf_b = (const float*)d_in[37];
  const float* W_end = (const float*)d_in[38];
  const float* b_end = (const float*)d_in[39];
  const float* w_acl = (const float*)d_in[40];
  const float* w_het = (const float*)d_in[41];
  const float* adj     = (const float*)d_in[42];
  const float* adj_sem = (const float*)d_in[43];
  const float* Wg1 = (const float*)d_in[44];
  const float* Wg2 = (const float*)d_in[45];
  const float* bg  = (const float*)d_in[46];
  const float* Wgo = (const float*)d_in[47];
  const float* bgo = (const float*)d_in[48];
  float* out = (float*)d_out;
  float* ws  = (float*)d_ws;

  const int ROWS_TN = BB * TT * NN;   // 14736
  const int ROWS_BN = BB * NN;        // 1228

  // ---- workspace layout (float offsets, 16-float aligned) ----
  float* Z     = ws;                             // 864512
  float* C2    = ws + 864512;                    // 864512
  __hip_bfloat16* Zb    = (__hip_bfloat16*)(ws + 1729024);   // 44*320*64
  __hip_bfloat16* WinT  = (__hip_bfloat16*)(ws + 2179584);   // 704*1824
  __hip_bfloat16* WqkvT = (__hip_bfloat16*)(ws + 2821632);   // 192*64
  __hip_bfloat16* WoT   = (__hip_bfloat16*)(ws + 2827776);   // 64*64
  __hip_bfloat16* Wf1T  = (__hip_bfloat16*)(ws + 2829824);   // 256*64
  __hip_bfloat16* Wf2T  = (__hip_bfloat16*)(ws + 2838016);   // 64*256
  float* BQKV  = ws + 2846208;                   // 192 (+pad)
  float* POOL  = ws + 2846416;
  // phase 1
  float* XEMB = POOL;                            // 2239872 [B,T,N,152]
  __hip_bfloat16* XEMBT = (__hip_bfloat16*)(POOL + 2239872); // 1228*1824
  float* XGP  = POOL + 3359808;                  // 1886208 [B,T,N,128]
  float* G    = POOL + 5246016;                  // 943104
  float* WGP  = POOL + 6189120;                  // 19456
  // phase 2 (overlays phase 1)
  __hip_bfloat16* Qb   = (__hip_bfloat16*)POOL;              // 44*320*64
  __hip_bfloat16* Kb   = (__hip_bfloat16*)(POOL + 450560);   // 44*320*64
  __hip_bfloat16* Vtb  = (__hip_bfloat16*)(POOL + 901120);   // 44*64*320
  __hip_bfloat16* Obf  = (__hip_bfloat16*)(POOL + 1351680);  // RPAD*64
  __hip_bfloat16* H1b  = (__hip_bfloat16*)(POOL + 1785856);  // RPAD*64
  __hip_bfloat16* FFHb = (__hip_bfloat16*)(POOL + 2220032);  // RPAD*256
  float* FF = POOL + 3956736;                    // 864512

  // ---- phase 1 ----
  embed_kernel<<<dim3(8750), dim3(256), 0, stream>>>(
      ori_x, W_val, b_val, tod_emb, dow_emb, node_emb, XEMB, ROWS_TN * EMB);
  transpose_emb<<<dim3(8750), dim3(256), 0, stream>>>(XEMB, XEMBT, ROWS_TN * EMB);
  zinit_kernel<<<dim3(3377), dim3(256), 0, stream>>>(Z, b_in, ROWS_BN * SS * HH);
  transpose_cvt<<<dim3(57, 22), dim3(256), 0, stream>>>(W_in, WinT, 1824, 704, 1.f);
  transpose_cvt<<<dim3(2, 2), dim3(256), 0, stream>>>(Wq, WqkvT, 64, 64, 0.25f);
  transpose_cvt<<<dim3(2, 2), dim3(256), 0, stream>>>(Wk, WqkvT + 64 * 64, 64, 64, 1.f);
  transpose_cvt<<<dim3(2, 2), dim3(256), 0, stream>>>(Wv, WqkvT + 128 * 64, 64, 64, 1.f);
  transpose_cvt<<<dim3(2, 2), dim3(256), 0, stream>>>(Wo, WoT, 64, 64, 1.f);
  transpose_cvt<<<dim3(2, 8), dim3(256), 0, stream>>>(Wf1, Wf1T, 64, 256, 1.f);
  transpose_cvt<<<dim3(8, 2), dim3(256), 0, stream>>>(Wf2, Wf2T, 256, 64, 1.f);
  pack_bias<<<dim3(1), dim3(64), 0, stream>>>(bq, bk, bv, BQKV);
  gemm_xin<<<dim3(20, 11, 4), dim3(256), 0, stream>>>(XEMBT, WinT, Z);
  c2_kernel<<<dim3(ROWS_BN * SS), dim3(64), 0, stream>>>(coeff2, W_ce, b_ce, C2);
  pack_wg<<<dim3(76), dim3(256), 0, stream>>>(Wg1, Wg2, WGP);
  gemm_kernel<<<dim3(231, 2, 1), dim3(256), 0, stream>>>(
      XEMB, EMB, 0L, WGP, 128, 0L, XGP, 128, 0L, nullptr, ROWS_TN, 128, EMB, 0);
  gemm_kernel<<<dim3(5, 1, 48), dim3(256), 0, stream>>>(
      adj, NN, 0L, XGP, 128, (long)NN * 128, G, HH, (long)NN * HH, nullptr,
      NN, HH, NN, 0);
  gemm_kernel<<<dim3(5, 1, 48), dim3(256), 0, stream>>>(
      adj_sem, NN, 0L, XGP + 64, 128, (long)NN * 128, G, HH, (long)NN * HH, bg,
      NN, HH, NN, GF_ACCUM | GF_BIAS | GF_RELU);
  gp_kernel<<<dim3(ROWS_BN), dim3(64), 0, stream>>>(G, Wgo, bgo, w_het, out);
  ztbf_kernel<<<dim3(NBS * NP / 4), dim3(256), 0, stream>>>(Z, Zb);

  // ---- phase 2: Euler scan, 11 steps, 6 dispatches each ----
  for (int i = 0; i < SS; ++i) {
    qkv_mfma<<<dim3(NBS, 5), dim3(256), 0, stream>>>(
        Zb, WqkvT, BQKV, Qb, Kb, Vtb);
    attn_mfma<<<dim3(NBS * NHH, 5), dim3(256), 0, stream>>>(Qb, Kb, Vtb, Obf);
    wo_ln1_mfma<<<dim3(212), dim3(256), 0, stream>>>(
        Obf, WoT, bo, Z, ln1_g, ln1_b, H1b);
    gemm_scan<64, 256, 1><<<dim3(212), dim3(256), 0, stream>>>(
        H1b, Wf1T, bf1, nullptr, FFHb);
    gemm_scan<256, 64, 0><<<dim3(212), dim3(256), 0, stream>>>(
        FFHb, Wf2T, bf2, FF, nullptr);
    ln2_update<<<dim3(3377), dim3(256), 0, stream>>>(
        H1b, FF, ln2_g, ln2_b, C2, W_tp2, b_tp2, Z, Zb, i);
  }

  // ---- epilogue ----
  final_acl<<<dim3(ROWS_BN), dim3(64), 0, stream>>>(
      Z, lnf_g, lnf_b, W_end, b_end, w_acl, out);
}

// Round 7
// 839.373 us; speedup vs baseline: 4.4654x; 1.3733x over previous
//
#include <hip/hip_runtime.h>
#include <hip/hip_bf16.h>
#include <math.h>

// Problem dims
#define BB   4
#define TT   12
#define NN   307
#define SS   11
#define HH   64
#define NHH  4
#define DHH  16
#define EMB  152
#define ROWS 13508          // B*S*N
#define NBS  44             // B*S
#define NBT  48             // B*T
#define NP   320            // padded node count
#define EP   160            // padded embedding dim (K for xg_mfma)
#define RPAD 13568          // 212*64 padded flat rows
#define KLP  24             // LDS K pitch (shorts) in attn
#define VLP  336            // LDS V^T pitch (shorts) in attn
#define PLP  40             // LDS P chunk pitch (shorts) in attn
#define HCP  264            // LDS hidden chunk pitch (shorts) in ffn

typedef short short8 __attribute__((ext_vector_type(8)));   // 8 bf16
typedef short short4a __attribute__((ext_vector_type(4)));  // 4 bf16
typedef float floatx4 __attribute__((ext_vector_type(4)));
#define MFMA_B16(a, b, c) __builtin_amdgcn_mfma_f32_16x16x32_bf16(a, b, c, 0, 0, 0)

__device__ __forceinline__ float wave_sum(float v) {
#pragma unroll
  for (int off = 32; off; off >>= 1) v += __shfl_xor(v, off);
  return v;
}
__device__ __forceinline__ short f2bf(float x) {
  __hip_bfloat16 h = __float2bfloat16(x);
  return *reinterpret_cast<short*>(&h);
}
// row r in (b,s,n) order -> flat offset of the 64-float row in Z ([b,n,s,h])
__device__ __forceinline__ long zoff_of_row(int r, int* s_out, long* bn_out) {
  int b = r / (SS * NN);
  int rem = r - b * (SS * NN);
  int s = rem / NN;
  int n = rem - s * NN;
  long bn = (long)b * NN + n;
  if (s_out) *s_out = s;
  if (bn_out) *bn_out = bn;
  return (bn * SS + s) * 64;
}

// transpose + scale + fp32->bf16: out[N,K] = scale * in[K,N]^T
__global__ __launch_bounds__(256) void transpose_cvt(
    const float* __restrict__ in, __hip_bfloat16* __restrict__ out,
    int K, int N, float scale)
{
  __shared__ float t[32][33];
  int k0 = blockIdx.x * 32, n0 = blockIdx.y * 32;
  int tx = threadIdx.x & 31, ty = threadIdx.x >> 5;
#pragma unroll
  for (int i = 0; i < 32; i += 8) {
    int k = k0 + ty + i, n = n0 + tx;
    if (k < K && n < N) t[ty + i][tx] = in[(long)k * N + n];
  }
  __syncthreads();
#pragma unroll
  for (int i = 0; i < 32; i += 8) {
    int n = n0 + ty + i, k = k0 + tx;
    if (k < K && n < N)
      out[(long)n * K + k] = __float2bfloat16(t[tx][ty + i] * scale);
  }
}

__global__ void pack_bias(const float* __restrict__ bq, const float* __restrict__ bk,
                          const float* __restrict__ bv, float* __restrict__ bqkv)
{
  int t = threadIdx.x;
  if (t < 64) {
    bqkv[t] = bq[t] * 0.25f;   // score scale folded into q
    bqkv[64 + t] = bk[t];
    bqkv[128 + t] = bv[t];
  }
}

__global__ void zinit_kernel(float* __restrict__ Z, const float* __restrict__ b_in,
                             int total)
{
  int idx = blockIdx.x * 256 + threadIdx.x;
  if (idx < total) Z[idx] = b_in[idx % (SS * HH)];
}

// ---------------------------------------------------------------------------
// DataEmbedding -> bf16 XEMBb [bt, node(320), 160], zero-padded
// ---------------------------------------------------------------------------
__global__ void embed_kernel(const float* __restrict__ ori,
                             const float* __restrict__ W_val,
                             const float* __restrict__ b_val,
                             const float* __restrict__ tod_emb,
                             const float* __restrict__ dow_emb,
                             const float* __restrict__ node_emb,
                             __hip_bfloat16* __restrict__ xe, int total)
{
  int idx = blockIdx.x * 256 + threadIdx.x;
  if (idx >= total) return;
  int c = idx % EP;
  int r = idx / EP;             // bt*NP + node
  int node = r % NP;
  int bt = r / NP;
  float v = 0.f;
  if (node < NN && c < EMB) {
    long orr = (long)bt * NN + node;
    if (c < 24) {
      const float* x = ori + orr * 3;
      v = x[0] * W_val[c] + x[1] * W_val[24 + c] + x[2] * W_val[48 + c] + b_val[c];
    } else if (c < 48) {
      float f = ori[orr * 3 + 1];
      f = f - floorf(f);
      int tod = (int)(f * 288.f);
      tod = min(max(tod, 0), 287);
      v = tod_emb[tod * 24 + (c - 24)];
    } else if (c < 72) {
      float f = ori[orr * 3 + 2];
      f = f - floorf(f);
      int dow = (int)(f * 7.f);
      dow = min(max(dow, 0), 6);
      v = dow_emb[dow * 24 + (c - 48)];
    } else {
      v = node_emb[node * 80 + (c - 72)];
    }
  }
  xe[idx] = __float2bfloat16(v);
}

// XEMBT[(b*NN+n)*1824 + t*152 + c] = XEMBb[((b*12+t)*NP + n)*160 + c]
__global__ void transpose_emb(const __hip_bfloat16* __restrict__ xe,
                              __hip_bfloat16* __restrict__ x_embT, int total)
{
  int idx = blockIdx.x * 256 + threadIdx.x;
  if (idx >= total) return;
  int c = idx % EMB;
  int r = idx / EMB;            // (b*NN + n)*TT + t
  int t = r % TT;
  int r2 = r / TT;
  int n = r2 % NN;
  int b = r2 / NN;
  x_embT[idx] = xe[(((long)(b * TT + t)) * NP + n) * EP + c];
}

__global__ void c2_kernel(const float* __restrict__ coeff2,
                          const float* __restrict__ W_ce,
                          const float* __restrict__ b_ce,
                          float* __restrict__ c2)
{
  int row = blockIdx.x;         // (b*N+n)*S + s
  int h = threadIdx.x;
  float a0 = coeff2[(long)row * 2];
  float a1 = coeff2[(long)row * 2 + 1];
  c2[(long)row * 64 + h] = a0 * W_ce[h] + a1 * W_ce[64 + h] + b_ce[h];
}

// WGPT[c][k] (bf16, [128,160]): c<64 -> Wg1[k][c], else Wg2[k][c-64]; k>=152 -> 0
__global__ void pack_wgT(const float* __restrict__ Wg1, const float* __restrict__ Wg2,
                         __hip_bfloat16* __restrict__ WGPT)
{
  int idx = blockIdx.x * 256 + threadIdx.x;
  if (idx >= 128 * EP) return;
  int c = idx / EP, k = idx % EP;
  float v = 0.f;
  if (k < EMB) v = (c < 64) ? Wg1[k * 64 + c] : Wg2[k * 64 + (c - 64)];
  WGPT[idx] = __float2bfloat16(v);
}

// adjb (bf16, [320,320]) zero-padded from adj [307,307]
__global__ void pack_adj(const float* __restrict__ adj, const float* __restrict__ adj_sem,
                         __hip_bfloat16* __restrict__ adjb,
                         __hip_bfloat16* __restrict__ adjsb)
{
  int idx = blockIdx.x * 256 + threadIdx.x;
  if (idx >= NP * NP) return;
  int m = idx / NP, k = idx % NP;
  float v1 = 0.f, v2 = 0.f;
  if (m < NN && k < NN) { v1 = adj[m * NN + k]; v2 = adj_sem[m * NN + k]; }
  adjb[idx] = __float2bfloat16(v1);
  adjsb[idx] = __float2bfloat16(v2);
}

// ---------------------------------------------------------------------------
// xg_mfma: XGT[bt, c(128), node(320)] = (XEMBb[bt] @ WGP)^T  (bf16 out)
// ---------------------------------------------------------------------------
__global__ __launch_bounds__(256) void xg_mfma(
    const __hip_bfloat16* __restrict__ XE, const __hip_bfloat16* __restrict__ WGPT,
    __hip_bfloat16* __restrict__ XGT)
{
  int bt = blockIdx.x;
  int tid = threadIdx.x, w = tid >> 6, l = tid & 63;
  int m0 = blockIdx.y * 64 + w * 16;      // node tile
  int cq = l & 15, rq = l >> 4;

  short8 af[5];
  const short* Ap = (const short*)XE + ((long)bt * NP + m0 + cq) * EP + rq * 8;
#pragma unroll
  for (int kk = 0; kk < 5; ++kk) af[kk] = *(const short8*)(Ap + kk * 32);

#pragma unroll
  for (int ct = 0; ct < 8; ++ct) {
    const short* Bp = (const short*)WGPT + (long)(ct * 16 + cq) * EP + rq * 8;
    floatx4 acc = {0.f, 0.f, 0.f, 0.f};
#pragma unroll
    for (int kk = 0; kk < 5; ++kk)
      acc = MFMA_B16(af[kk], *(const short8*)(Bp + kk * 32), acc);
    // transposed store: XGT[c][node], 4 consecutive nodes per lane
    short4a pk;
#pragma unroll
    for (int r = 0; r < 4; ++r) pk[r] = f2bf(acc[r]);
    *(short4a*)((short*)XGT + ((long)bt * 128 + ct * 16 + cq) * NP + m0 + rq * 4) = pk;
  }
}

// ---------------------------------------------------------------------------
// gcn_mfma: GT[bt, node, 64] = relu( (adj@XG1 + adjsem@XG2 + bg) )  fp32 out
// computed as C^T = XG1^T·adj^T + XG2^T·adjsem^T (B = row-major adjb!)
// ---------------------------------------------------------------------------
__global__ __launch_bounds__(256) void gcn_mfma(
    const __hip_bfloat16* __restrict__ XGT, const __hip_bfloat16* __restrict__ adjb,
    const __hip_bfloat16* __restrict__ adjsb, const float* __restrict__ bg,
    float* __restrict__ GT)
{
  int bt = blockIdx.x;
  int tid = threadIdx.x, w = tid >> 6, l = tid & 63;
  int n0 = blockIdx.y * 64;               // output node tile
  int cq = l & 15, rq = l >> 4;

  // A fragments: XGT rows h = w*16+cq (Wg1 part) and 64+w*16+cq (Wg2 part)
  short8 a1[10], a2[10];
  const short* A1p = (const short*)XGT + ((long)bt * 128 + w * 16 + cq) * NP + rq * 8;
  const short* A2p = A1p + 64 * NP;
#pragma unroll
  for (int kk = 0; kk < 10; ++kk) {
    a1[kk] = *(const short8*)(A1p + kk * 32);
    a2[kk] = *(const short8*)(A2p + kk * 32);
  }

  float bgv[4];
#pragma unroll
  for (int r = 0; r < 4; ++r) bgv[r] = bg[w * 16 + rq * 4 + r];

#pragma unroll
  for (int nt = 0; nt < 4; ++nt) {
    const short* B1p = (const short*)adjb + (long)(n0 + nt * 16 + cq) * NP + rq * 8;
    const short* B2p = (const short*)adjsb + (long)(n0 + nt * 16 + cq) * NP + rq * 8;
    floatx4 acc = {0.f, 0.f, 0.f, 0.f};
#pragma unroll
    for (int kk = 0; kk < 10; ++kk) {
      acc = MFMA_B16(a1[kk], *(const short8*)(B1p + kk * 32), acc);
      acc = MFMA_B16(a2[kk], *(const short8*)(B2p + kk * 32), acc);
    }
    // C row = h = w*16 + rq*4 + r, col = node = n0 + nt*16 + cq
    int node = n0 + nt * 16 + cq;
    if (node < NN) {
      float4 pk;
      pk.x = fmaxf(acc[0] + bgv[0], 0.f);
      pk.y = fmaxf(acc[1] + bgv[1], 0.f);
      pk.z = fmaxf(acc[2] + bgv[2], 0.f);
      pk.w = fmaxf(acc[3] + bgv[3], 0.f);
      *(float4*)(GT + (((long)bt * NP + node) * 64 + w * 16 + rq * 4)) = pk;
    }
  }
}

// gp: out[b,o,n] = w_het * (sum_{t,h} GT[b*TT+t, n, h]*Wgo[t*64+h, o] + bgo[o])
__global__ __launch_bounds__(64) void gp_kernel(const float* __restrict__ GT,
                                                const float* __restrict__ Wgo,
                                                const float* __restrict__ bgo,
                                                const float* __restrict__ w_het,
                                                float* __restrict__ out)
{
  int bn = blockIdx.x;
  int b = bn / NN, n = bn % NN;
  __shared__ float buf[TT * 64];
  for (int idx = threadIdx.x; idx < TT * 64; idx += 64) {
    int t = idx >> 6, h = idx & 63;
    buf[idx] = GT[(((long)(b * TT + t)) * NP + n) * 64 + h];
  }
  __syncthreads();
  int o = threadIdx.x;
  if (o < 12) {
    float acc = bgo[o];
    for (int j = 0; j < TT * 64; ++j) acc += buf[j] * Wgo[j * 12 + o];
    out[((long)b * 12 + o) * NN + n] = w_het[0] * acc;
  }
}

// ---------------------------------------------------------------------------
// x_in GEMM, bf16 MFMA, split-K=4, atomicAdd into bias-initialized Z.
// ---------------------------------------------------------------------------
__global__ __launch_bounds__(256) void gemm_xin(
    const __hip_bfloat16* __restrict__ A, const __hip_bfloat16* __restrict__ BT,
    float* __restrict__ C)
{
  int tid = threadIdx.x, w = tid >> 6, l = tid & 63;
  int m0 = blockIdx.x * 64 + w * 16;
  int n0 = blockIdx.y * 64;
  int k0s = blockIdx.z * 480;
  int k0e = min(1824, k0s + 480);

  int cq = l & 15, rq = l >> 4;
  int arow = min(m0 + cq, 1227);
  const short* Ap = (const short*)A + (long)arow * 1824 + rq * 8;
  const short* Bp = (const short*)BT + rq * 8;

  floatx4 acc[4] = {};
  for (int k0 = k0s; k0 < k0e; k0 += 32) {
    short8 a = *(const short8*)(Ap + k0);
#pragma unroll
    for (int nt = 0; nt < 4; ++nt) {
      short8 b = *(const short8*)(Bp + (long)(n0 + nt * 16 + cq) * 1824 + k0);
      acc[nt] = MFMA_B16(a, b, acc[nt]);
    }
  }
#pragma unroll
  for (int nt = 0; nt < 4; ++nt) {
    int c = n0 + nt * 16 + cq;
#pragma unroll
    for (int r = 0; r < 4; ++r) {
      int row = m0 + rq * 4 + r;
      if (row < 1228) atomicAdd(&C[(long)row * 704 + c], acc[nt][r]);
    }
  }
}

// Z (fp32, [b,n,s,h]) -> Zb (bf16, [bs, node(pad 320), 64]); pads zero-filled.
__global__ __launch_bounds__(256) void ztbf_kernel(const float* __restrict__ Z,
                                                   __hip_bfloat16* __restrict__ Zb)
{
  int row = blockIdx.x * 4 + (threadIdx.x >> 6);
  if (row >= NBS * NP) return;
  int lane = threadIdx.x & 63;
  int bs = row / NP, node = row - bs * NP;
  int b = bs / SS, s = bs - b * SS;
  float v = 0.f;
  if (node < NN) v = Z[(((long)(b * NN + node)) * SS + s) * 64 + lane];
  Zb[(long)row * 64 + lane] = __float2bfloat16(v);
}

// ---------------------------------------------------------------------------
// QKV projection, per-bs MFMA. Emits bf16 Qb/Kb [bs,NP,64], Vtb [bs,64,NP].
// ---------------------------------------------------------------------------
__global__ __launch_bounds__(256) void qkv_mfma(
    const __hip_bfloat16* __restrict__ Zb, const __hip_bfloat16* __restrict__ WT,
    const float* __restrict__ bqkv,
    __hip_bfloat16* __restrict__ Qb, __hip_bfloat16* __restrict__ Kb,
    __hip_bfloat16* __restrict__ Vtb)
{
  int bs = blockIdx.x, mt = blockIdx.y;
  int tid = threadIdx.x, w = tid >> 6, l = tid & 63;
  int m0 = mt * 64 + w * 16;
  int cq = l & 15, rq = l >> 4;

  const short* Ap = (const short*)Zb + ((long)bs * NP + m0 + cq) * 64 + rq * 8;
  short8 a0 = *(const short8*)Ap;
  short8 a1 = *(const short8*)(Ap + 32);

#pragma unroll
  for (int nt = 0; nt < 12; ++nt) {
    const short* Bp = (const short*)WT + (long)(nt * 16 + cq) * 64 + rq * 8;
    floatx4 acc = {0.f, 0.f, 0.f, 0.f};
    acc = MFMA_B16(a0, *(const short8*)Bp, acc);
    acc = MFMA_B16(a1, *(const short8*)(Bp + 32), acc);
    int c = nt * 16 + cq;
    float bias = bqkv[c];
#pragma unroll
    for (int r = 0; r < 4; ++r) {
      int node = m0 + rq * 4 + r;
      if (node < NN) {
        __hip_bfloat16 v = __float2bfloat16(acc[r] + bias);
        if (c < 64)       Qb[((long)bs * NP + node) * 64 + c] = v;
        else if (c < 128) Kb[((long)bs * NP + node) * 64 + (c - 64)] = v;
        else              Vtb[((long)bs * 64 + (c - 128)) * NP + node] = v;
      }
    }
  }
}

// ---------------------------------------------------------------------------
// MFMA attention (proven 16x16x32-only structure from R6).
// ---------------------------------------------------------------------------
__global__ __launch_bounds__(256) void attn_mfma(
    const __hip_bfloat16* __restrict__ Qb, const __hip_bfloat16* __restrict__ Kb,
    const __hip_bfloat16* __restrict__ Vtb, __hip_bfloat16* __restrict__ O)
{
  int bsh = blockIdx.x;           // bs*NH + head
  int head = bsh & 3;
  int bs = bsh >> 2;

  __shared__ __align__(16) short Kl[NP * KLP];      // K [key][d]
  __shared__ __align__(16) short Vl[16 * VLP];      // V^T [d][key]
  __shared__ __align__(16) short Pd[4][2][16 * PLP];// per-wave P chunk

  int tid = threadIdx.x;
  const short* kg = (const short*)Kb + (long)bs * NP * 64 + head * 16;
  for (int ch = tid; ch < NP * 4; ch += 256) {
    int node = ch >> 2, part = (ch & 3) * 4;
    short4a kv = {0, 0, 0, 0};
    if (node < NN) kv = *(const short4a*)(kg + (long)node * 64 + part);
    *(short4a*)&Kl[node * KLP + part] = kv;
  }
  const short* vg = (const short*)Vtb + ((long)bs * 64 + head * 16) * NP;
  for (int ch = tid; ch < 16 * 80; ch += 256) {
    int d = ch / 80, k4 = (ch % 80) * 4;
    short4a vv = {0, 0, 0, 0};
    if (k4 + 3 < NN) {
      vv = *(const short4a*)(vg + (long)d * NP + k4);
    } else {
#pragma unroll
      for (int j = 0; j < 4; ++j)
        if (k4 + j < NN) vv[j] = vg[(long)d * NP + k4 + j];
    }
    *(short4a*)&Vl[d * VLP + k4] = vv;
  }
  __syncthreads();

  int wave = tid >> 6, lane = tid & 63;
  int m = lane & 15, quad = lane >> 4;
  int gg = blockIdx.y * 4 + wave;     // 16-query group, 0..19
  int q0 = gg * 16;
  int qv = q0 + m;

  const short8 z8 = {0, 0, 0, 0, 0, 0, 0, 0};
  const floatx4 zf = {0.f, 0.f, 0.f, 0.f};

  short8 qf = z8;
  if (quad < 2 && qv < NN)
    qf = *(const short8*)((const short*)Qb +
        ((long)bs * NP + qv) * 64 + head * 16 + quad * 8);

  short* Pw0 = &Pd[wave][0][0];
  short* Pw1 = &Pd[wave][1][0];

  float sum = 0.f;
  floatx4 oa = zf, ob = zf;

  for (int c = 0; c < 10; ++c) {
    short8 kf0 = z8, kf1 = z8;
    if (quad < 2) {
      kf0 = *(const short8*)&Kl[((2 * c) * 16 + m) * KLP + quad * 8];
      kf1 = *(const short8*)&Kl[((2 * c + 1) * 16 + m) * KLP + quad * 8];
    }
    floatx4 s0 = MFMA_B16(kf0, qf, zf);
    floatx4 s1 = MFMA_B16(kf1, qf, zf);

    float e0[4], e1[4];
#pragma unroll
    for (int j = 0; j < 4; ++j) {
      e0[j] = __expf(fminf(s0[j], 30.f));
      e1[j] = __expf(fminf(s1[j], 30.f));
    }
    if (c == 9) {
      if (quad == 0) e1[3] = 0.f;
      else { e1[0] = 0.f; e1[1] = 0.f; e1[2] = 0.f; e1[3] = 0.f; }
    }
    sum += e0[0] + e0[1] + e0[2] + e0[3] + e1[0] + e1[1] + e1[2] + e1[3];

    short4a p0, p1;
#pragma unroll
    for (int j = 0; j < 4; ++j) { p0[j] = f2bf(e0[j]); p1[j] = f2bf(e1[j]); }
    short* Pw = (c & 1) ? Pw1 : Pw0;
    *(short4a*)&Pw[m * PLP + quad * 4] = p0;
    *(short4a*)&Pw[m * PLP + 16 + quad * 4] = p1;

    short8 pf = *(const short8*)&Pw[m * PLP + quad * 8];
    short8 vf = *(const short8*)&Vl[m * VLP + c * 32 + quad * 8];
    if (c & 1) ob = MFMA_B16(vf, pf, ob);
    else       oa = MFMA_B16(vf, pf, oa);
  }

  sum += __shfl_xor(sum, 16);
  sum += __shfl_xor(sum, 32);
  float inv = 1.f / sum;

  if (qv < NN) {
    short4a pk;
#pragma unroll
    for (int r = 0; r < 4; ++r) pk[r] = f2bf((oa[r] + ob[r]) * inv);
    *(short4a*)((short*)O + ((long)bs * NN + qv) * 64 + head * 16 + quad * 4) = pk;
  }
}

// ---------------------------------------------------------------------------
// Fused: o2 = O@Wo + bo; h1 = LN(z + o2; ln1) -> H1b. Two-pass LN.
// ---------------------------------------------------------------------------
__global__ __launch_bounds__(256) void wo_ln1_mfma(
    const __hip_bfloat16* __restrict__ A, const __hip_bfloat16* __restrict__ BT,
    const float* __restrict__ bo, const float* __restrict__ Zf,
    const float* __restrict__ g, const float* __restrict__ bb,
    __hip_bfloat16* __restrict__ H1b)
{
  int tid = threadIdx.x, w = tid >> 6, l = tid & 63;
  int m0 = blockIdx.x * 64 + w * 16;
  int cq = l & 15, rq = l >> 4;

  const short* Ap = (const short*)A + (long)(m0 + cq) * 64 + rq * 8;
  short8 a0 = *(const short8*)Ap;
  short8 a1 = *(const short8*)(Ap + 32);

  float x[4][4];
#pragma unroll
  for (int nt = 0; nt < 4; ++nt) {
    const short* Bp = (const short*)BT + (long)(nt * 16 + cq) * 64 + rq * 8;
    floatx4 acc = {0.f, 0.f, 0.f, 0.f};
    acc = MFMA_B16(a0, *(const short8*)Bp, acc);
    acc = MFMA_B16(a1, *(const short8*)(Bp + 32), acc);
    float bv = bo[nt * 16 + cq];
#pragma unroll
    for (int r = 0; r < 4; ++r) x[nt][r] = acc[r] + bv;
  }
#pragma unroll
  for (int r = 0; r < 4; ++r) {
    int row = m0 + rq * 4 + r;
    long zo = zoff_of_row(min(row, ROWS - 1), nullptr, nullptr);
#pragma unroll
    for (int nt = 0; nt < 4; ++nt) x[nt][r] += Zf[zo + nt * 16 + cq];
  }
  float gv[4], bv2[4];
#pragma unroll
  for (int nt = 0; nt < 4; ++nt) { gv[nt] = g[nt * 16 + cq]; bv2[nt] = bb[nt * 16 + cq]; }

#pragma unroll
  for (int r = 0; r < 4; ++r) {
    float s = x[0][r] + x[1][r] + x[2][r] + x[3][r];
#pragma unroll
    for (int off = 1; off <= 8; off <<= 1) s += __shfl_xor(s, off);
    float mean = s * (1.f / 64.f);
    float vs = 0.f;
#pragma unroll
    for (int nt = 0; nt < 4; ++nt) {
      float d = x[nt][r] - mean;
      vs += d * d;
    }
#pragma unroll
    for (int off = 1; off <= 8; off <<= 1) vs += __shfl_xor(vs, off);
    float rstd = rsqrtf(vs * (1.f / 64.f) + 1e-5f);
    int row = m0 + rq * 4 + r;
    if (row < ROWS) {
#pragma unroll
      for (int nt = 0; nt < 4; ++nt)
        H1b[(long)row * 64 + nt * 16 + cq] =
            __float2bfloat16((x[nt][r] - mean) * rstd * gv[nt] + bv2[nt]);
    }
  }
}

// ---------------------------------------------------------------------------
// Fused FFN: ff = relu(h1@Wf1+bf1)@Wf2 + bf2 -> FF (fp32).
// Hidden acts round-trip through a wave-private LDS chunk (attn-proven).
// ---------------------------------------------------------------------------
__global__ __launch_bounds__(256) void ffn_mfma(
    const __hip_bfloat16* __restrict__ H1b,
    const __hip_bfloat16* __restrict__ Wf1T, const float* __restrict__ bf1,
    const __hip_bfloat16* __restrict__ Wf2T, const float* __restrict__ bf2,
    float* __restrict__ FF)
{
  __shared__ __align__(16) short Hc[4][16 * HCP];
  int tid = threadIdx.x, w = tid >> 6, l = tid & 63;
  int m0 = blockIdx.x * 64 + w * 16;
  int cq = l & 15, rq = l >> 4;

  const short* Ap = (const short*)H1b + (long)(m0 + cq) * 64 + rq * 8;
  short8 a0 = *(const short8*)Ap;
  short8 a1 = *(const short8*)(Ap + 32);
  short* Hw = &Hc[w][0];

  // Phase A: hidden = relu(h1@Wf1+bf1), C-layout -> LDS [row 16][hidden 256]
#pragma unroll
  for (int ht = 0; ht < 16; ++ht) {
    const short* Bp = (const short*)Wf1T + (long)(ht * 16 + cq) * 64 + rq * 8;
    floatx4 acc = {0.f, 0.f, 0.f, 0.f};
    acc = MFMA_B16(a0, *(const short8*)Bp, acc);
    acc = MFMA_B16(a1, *(const short8*)(Bp + 32), acc);
    float bv = bf1[ht * 16 + cq];
#pragma unroll
    for (int r = 0; r < 4; ++r)
      Hw[(rq * 4 + r) * HCP + ht * 16 + cq] = f2bf(fmaxf(acc[r] + bv, 0.f));
  }

  // Phase B: ff = hidden@Wf2 + bf2 (A-fragments straight from LDS)
#pragma unroll
  for (int nt = 0; nt < 4; ++nt) {
    const short* Bp = (const short*)Wf2T + (long)(nt * 16 + cq) * 256 + rq * 8;
    floatx4 acc = {0.f, 0.f, 0.f, 0.f};
#pragma unroll
    for (int kk = 0; kk < 8; ++kk) {
      short8 pf = *(const short8*)&Hw[cq * HCP + kk * 32 + rq * 8];
      acc = MFMA_B16(pf, *(const short8*)(Bp + kk * 32), acc);
    }
    int c = nt * 16 + cq;
    float bv = bf2[c];
#pragma unroll
    for (int r = 0; r < 4; ++r) {
      int row = m0 + rq * 4 + r;
      if (row < ROWS) FF[(long)row * 64 + c] = acc[r] + bv;
    }
  }
}

// t = tanh(LN(h1+ff; ln2)); Z += t*x2s[iter]; writes Zb (bf16) for next iter
__global__ __launch_bounds__(256) void ln2_update(
    const __hip_bfloat16* __restrict__ H1b, const float* __restrict__ FF,
    const float* __restrict__ g2, const float* __restrict__ b2,
    const float* __restrict__ C2, const float* __restrict__ W_tp2,
    const float* __restrict__ b_tp2,
    float* __restrict__ Z, __hip_bfloat16* __restrict__ Zb, int iter)
{
  int row = blockIdx.x * 4 + (threadIdx.x >> 6);   // (b*S+s)*N + n
  if (row >= ROWS) return;
  int lane = threadIdx.x & 63;
  long p = (long)row * 64 + lane;
  float x = __bfloat162float(H1b[p]) + FF[p];
  float m = wave_sum(x) * (1.f / 64.f);
  float d = x - m;
  float v = wave_sum(d * d) * (1.f / 64.f);
  float t = tanhf(d * rsqrtf(v + 1e-5f) * g2[lane] + b2[lane]);

  int s1; long bn;
  long zo = zoff_of_row(row, &s1, &bn);
  float acc = b_tp2[s1 * SS + iter];
#pragma unroll
  for (int s = 0; s < SS; ++s)
    acc += C2[(bn * SS + s) * 64 + lane] * W_tp2[s * (SS * SS) + s1 * SS + iter];

  float zn = Z[zo + lane] + t * acc;
  Z[zo + lane] = zn;
  int b = (int)(bn / NN), n = (int)(bn - (long)b * NN);
  Zb[(((long)(b * SS + s1)) * NP + n) * 64 + lane] = __float2bfloat16(zn);
}

// zT = LN(z[:,:,S-1,:]; lnf);  out[b,o,n] += w_acl*(zT@W_end + b_end)
__global__ __launch_bounds__(64) void final_acl(const float* __restrict__ z,
                                                const float* __restrict__ lnf_g,
                                                const float* __restrict__ lnf_b,
                                                const float* __restrict__ W_end,
                                                const float* __restrict__ b_end,
                                                const float* __restrict__ w_acl,
                                                float* __restrict__ out)
{
  int bn = blockIdx.x;
  int lane = threadIdx.x;
  int b = bn / NN, n = bn % NN;
  float x = z[((long)bn * SS + (SS - 1)) * 64 + lane];
  float m = wave_sum(x) * (1.f / 64.f);
  float d = x - m;
  float v = wave_sum(d * d) * (1.f / 64.f);
  float zT = d * rsqrtf(v + 1e-5f) * lnf_g[lane] + lnf_b[lane];
  float wa = w_acl[0];
  for (int o = 0; o < 12; ++o) {
    float p = zT * W_end[lane * 12 + o];
    p = wave_sum(p);
    if (lane == 0) {
      long oi = ((long)b * 12 + o) * NN + n;
      out[oi] = out[oi] + wa * (p + b_end[o]);
    }
  }
}

// ---------------------------------------------------------------------------
extern "C" void kernel_launch(void* const* d_in, const int* in_sizes, int n_in,
                              void* d_out, int out_size, void* d_ws, size_t ws_size,
                              hipStream_t stream)
{
  (void)in_sizes; (void)n_in; (void)out_size; (void)ws_size;

  const float* ori_x    = (const float*)d_in[0];
  const float* coeff2   = (const float*)d_in[2];
  const float* W_val    = (const float*)d_in[5];
  const float* b_val    = (const float*)d_in[6];
  const float* tod_emb  = (const float*)d_in[7];
  const float* dow_emb  = (const float*)d_in[8];
  const float* node_emb = (const float*)d_in[9];
  const float* W_in     = (const float*)d_in[10];
  const float* b_in     = (const float*)d_in[11];
  const float* W_ce     = (const float*)d_in[12];
  const float* b_ce     = (const float*)d_in[13];
  const float* W_tp2    = (const float*)d_in[14];
  const float* b_tp2    = (const float*)d_in[15];
  const float* Wq = (const float*)d_in[20];
  const float* Wk = (const float*)d_in[21];
  const float* Wv = (const float*)d_in[22];
  const float* Wo = (const float*)d_in[23];
  const float* bq = (const float*)d_in[24];
  const float* bk = (const float*)d_in[25];
  const float* bv = (const float*)d_in[26];
  const float* bo = (const float*)d_in[27];
  const float* ln1_g = (const float*)d_in[28];
  const float* ln1_b = (const float*)d_in[29];
  const float* Wf1   = (const float*)d_in[30];
  const float* bf1   = (const float*)d_in[31];
  const float* Wf2   = (const float*)d_in[32];
  const float* bf2   = (const float*)d_in[33];
  const float* ln2_g = (const float*)d_in[34];
  const float* ln2_b = (const float*)d_in[35];
  const float* lnf_g = (const float*)d_in[36];
  const float* lnf_b = (const float*)d_in[37];
  const float* W_end = (const float*)d_in[38];
  const float* b_end = (const float*)d_in[39];
  const float* w_acl = (const float*)d_in[40];
  const float* w_het = (const float*)d_in[41];
  const float* adj     = (const float*)d_in[42];
  const float* adj_sem = (const float*)d_in[43];
  const float* Wg1 = (const float*)d_in[44];
  const float* Wg2 = (const float*)d_in[45];
  const float* bg  = (const float*)d_in[46];
  const float* Wgo = (const float*)d_in[47];
  const float* bgo = (const float*)d_in[48];
  float* out = (float*)d_out;
  float* ws  = (float*)d_ws;

  const int ROWS_BN = BB * NN;        // 1228

  // ---- workspace layout (float offsets, 16-float aligned) ----
  float* Z     = ws;                             // 864512
  float* C2    = ws + 864512;                    // 864512
  __hip_bfloat16* Zb    = (__hip_bfloat16*)(ws + 1729024);   // 44*320*64
  __hip_bfloat16* WinT  = (__hip_bfloat16*)(ws + 2179584);   // 704*1824
  __hip_bfloat16* WqkvT = (__hip_bfloat16*)(ws + 2821632);   // 192*64
  __hip_bfloat16* WoT   = (__hip_bfloat16*)(ws + 2827776);   // 64*64
  __hip_bfloat16* Wf1T  = (__hip_bfloat16*)(ws + 2829824);   // 256*64
  __hip_bfloat16* Wf2T  = (__hip_bfloat16*)(ws + 2838016);   // 64*256
  float* BQKV  = ws + 2846208;                   // 192 (+pad)
  float* POOL  = ws + 2846416;
  // phase 1
  __hip_bfloat16* XEMBb = (__hip_bfloat16*)POOL;             // 48*320*160
  __hip_bfloat16* XEMBT = (__hip_bfloat16*)(POOL + 1228800); // 1228*1824
  __hip_bfloat16* XGT   = (__hip_bfloat16*)(POOL + 2348736); // 48*128*320
  float* GT             = POOL + 3331776;                    // 48*320*64 fp32
  __hip_bfloat16* ADJB  = (__hip_bfloat16*)(POOL + 4314816); // 320*320
  __hip_bfloat16* ADJSB = (__hip_bfloat16*)(POOL + 4366016); // 320*320
  __hip_bfloat16* WGPT  = (__hip_bfloat16*)(POOL + 4417216); // 128*160
  // phase 2 (overlays phase 1)
  __hip_bfloat16* Qb   = (__hip_bfloat16*)POOL;              // 44*320*64
  __hip_bfloat16* Kb   = (__hip_bfloat16*)(POOL + 450560);   // 44*320*64
  __hip_bfloat16* Vtb  = (__hip_bfloat16*)(POOL + 901120);   // 44*64*320
  __hip_bfloat16* Obf  = (__hip_bfloat16*)(POOL + 1351680);  // RPAD*64
  __hip_bfloat16* H1b  = (__hip_bfloat16*)(POOL + 1785856);  // RPAD*64
  float* FF = POOL + 2220032;                    // ROWS*64 fp32

  // ---- phase 1 ----
  embed_kernel<<<dim3(9600), dim3(256), 0, stream>>>(
      ori_x, W_val, b_val, tod_emb, dow_emb, node_emb, XEMBb, NBT * NP * EP);
  transpose_emb<<<dim3(8750), dim3(256), 0, stream>>>(
      XEMBb, XEMBT, ROWS_BN * TT * EMB);
  zinit_kernel<<<dim3(3377), dim3(256), 0, stream>>>(Z, b_in, ROWS_BN * SS * HH);
  transpose_cvt<<<dim3(57, 22), dim3(256), 0, stream>>>(W_in, WinT, 1824, 704, 1.f);
  transpose_cvt<<<dim3(2, 2), dim3(256), 0, stream>>>(Wq, WqkvT, 64, 64, 0.25f);
  transpose_cvt<<<dim3(2, 2), dim3(256), 0, stream>>>(Wk, WqkvT + 64 * 64, 64, 64, 1.f);
  transpose_cvt<<<dim3(2, 2), dim3(256), 0, stream>>>(Wv, WqkvT + 128 * 64, 64, 64, 1.f);
  transpose_cvt<<<dim3(2, 2), dim3(256), 0, stream>>>(Wo, WoT, 64, 64, 1.f);
  transpose_cvt<<<dim3(2, 8), dim3(256), 0, stream>>>(Wf1, Wf1T, 64, 256, 1.f);
  transpose_cvt<<<dim3(8, 2), dim3(256), 0, stream>>>(Wf2, Wf2T, 256, 64, 1.f);
  pack_bias<<<dim3(1), dim3(64), 0, stream>>>(bq, bk, bv, BQKV);
  pack_wgT<<<dim3(80), dim3(256), 0, stream>>>(Wg1, Wg2, WGPT);
  pack_adj<<<dim3(400), dim3(256), 0, stream>>>(adj, adj_sem, ADJB, ADJSB);
  gemm_xin<<<dim3(20, 11, 4), dim3(256), 0, stream>>>(XEMBT, WinT, Z);
  c2_kernel<<<dim3(ROWS_BN * SS), dim3(64), 0, stream>>>(coeff2, W_ce, b_ce, C2);
  // GCN branch (all MFMA)
  xg_mfma<<<dim3(NBT, 5), dim3(256), 0, stream>>>(XEMBb, WGPT, XGT);
  gcn_mfma<<<dim3(NBT, 5), dim3(256), 0, stream>>>(XGT, ADJB, ADJSB, bg, GT);
  gp_kernel<<<dim3(ROWS_BN), dim3(64), 0, stream>>>(GT, Wgo, bgo, w_het, out);
  ztbf_kernel<<<dim3(NBS * NP / 4), dim3(256), 0, stream>>>(Z, Zb);

  // ---- phase 2: Euler scan, 11 steps, 5 dispatches each ----
  for (int i = 0; i < SS; ++i) {
    qkv_mfma<<<dim3(NBS, 5), dim3(256), 0, stream>>>(
        Zb, WqkvT, BQKV, Qb, Kb, Vtb);
    attn_mfma<<<dim3(NBS * NHH, 5), dim3(256), 0, stream>>>(Qb, Kb, Vtb, Obf);
    wo_ln1_mfma<<<dim3(212), dim3(256), 0, stream>>>(
        Obf, WoT, bo, Z, ln1_g, ln1_b, H1b);
    ffn_mfma<<<dim3(212), dim3(256), 0, stream>>>(
        H1b, Wf1T, bf1, Wf2T, bf2, FF);
    ln2_update<<<dim3(3377), dim3(256), 0, stream>>>(
        H1b, FF, ln2_g, ln2_b, C2, W_tp2, b_tp2, Z, Zb, i);
  }

  // ---- epilogue ----
  final_acl<<<dim3(ROWS_BN), dim3(64), 0, stream>>>(
      Z, lnf_g, lnf_b, W_end, b_end, w_acl, out);
}

// Round 8
// 768.474 us; speedup vs baseline: 4.8774x; 1.0923x over previous
//
#include <hip/hip_runtime.h>
#include <hip/hip_bf16.h>
#include <math.h>

// Problem dims
#define BB   4
#define TT   12
#define NN   307
#define SS   11
#define HH   64
#define NHH  4
#define DHH  16
#define EMB  152
#define ROWS 13508          // B*S*N
#define NBS  44             // B*S
#define NBT  48             // B*T
#define NP   320            // padded node count
#define EP   160            // padded embedding dim
#define RPAD 13568          // 212*64 padded flat rows
#define KLP  24             // LDS K pitch (shorts) in attn
#define VLP  336            // LDS V^T pitch (shorts) in attn
#define PLP  40             // LDS P chunk pitch (shorts) in attn
#define HCP  264            // LDS hidden chunk pitch (shorts)
#define HLP  72             // LDS h1 chunk pitch (shorts)

typedef short short8 __attribute__((ext_vector_type(8)));   // 8 bf16
typedef short short4a __attribute__((ext_vector_type(4)));  // 4 bf16
typedef float floatx4 __attribute__((ext_vector_type(4)));
#define MFMA_B16(a, b, c) __builtin_amdgcn_mfma_f32_16x16x32_bf16(a, b, c, 0, 0, 0)

__device__ __forceinline__ float wave_sum(float v) {
#pragma unroll
  for (int off = 32; off; off >>= 1) v += __shfl_xor(v, off);
  return v;
}
__device__ __forceinline__ short f2bf(float x) {
  __hip_bfloat16 h = __float2bfloat16(x);
  return *reinterpret_cast<short*>(&h);
}
// row r in (b,s,n) order -> flat offset of the 64-float row in Z ([b,n,s,h])
__device__ __forceinline__ long zoff_of_row(int r, int* s_out, long* bn_out) {
  int b = r / (SS * NN);
  int rem = r - b * (SS * NN);
  int s = rem / NN;
  int n = rem - s * NN;
  long bn = (long)b * NN + n;
  if (s_out) *s_out = s;
  if (bn_out) *bn_out = bn;
  return (bn * SS + s) * 64;
}

// transpose + scale + fp32->bf16: out[N,K] = scale * in[K,N]^T
__global__ __launch_bounds__(256) void transpose_cvt(
    const float* __restrict__ in, __hip_bfloat16* __restrict__ out,
    int K, int N, float scale)
{
  __shared__ float t[32][33];
  int k0 = blockIdx.x * 32, n0 = blockIdx.y * 32;
  int tx = threadIdx.x & 31, ty = threadIdx.x >> 5;
#pragma unroll
  for (int i = 0; i < 32; i += 8) {
    int k = k0 + ty + i, n = n0 + tx;
    if (k < K && n < N) t[ty + i][tx] = in[(long)k * N + n];
  }
  __syncthreads();
#pragma unroll
  for (int i = 0; i < 32; i += 8) {
    int n = n0 + ty + i, k = k0 + tx;
    if (k < K && n < N)
      out[(long)n * K + k] = __float2bfloat16(t[tx][ty + i] * scale);
  }
}

__global__ void pack_bias(const float* __restrict__ bq, const float* __restrict__ bk,
                          const float* __restrict__ bv, float* __restrict__ bqkv)
{
  int t = threadIdx.x;
  if (t < 64) {
    bqkv[t] = bq[t] * 0.25f;   // score scale folded into q
    bqkv[64 + t] = bk[t];
    bqkv[128 + t] = bv[t];
  }
}

__global__ void zinit_kernel(float* __restrict__ Z, const float* __restrict__ b_in,
                             int total)
{
  int idx = blockIdx.x * 256 + threadIdx.x;
  if (idx < total) Z[idx] = b_in[idx % (SS * HH)];
}

// ---------------------------------------------------------------------------
// DataEmbedding -> bf16 XEMBb [bt, node(320), 160], zero-padded
// ---------------------------------------------------------------------------
__global__ void embed_kernel(const float* __restrict__ ori,
                             const float* __restrict__ W_val,
                             const float* __restrict__ b_val,
                             const float* __restrict__ tod_emb,
                             const float* __restrict__ dow_emb,
                             const float* __restrict__ node_emb,
                             __hip_bfloat16* __restrict__ xe, int total)
{
  int idx = blockIdx.x * 256 + threadIdx.x;
  if (idx >= total) return;
  int c = idx % EP;
  int r = idx / EP;             // bt*NP + node
  int node = r % NP;
  int bt = r / NP;
  float v = 0.f;
  if (node < NN && c < EMB) {
    long orr = (long)bt * NN + node;
    if (c < 24) {
      const float* x = ori + orr * 3;
      v = x[0] * W_val[c] + x[1] * W_val[24 + c] + x[2] * W_val[48 + c] + b_val[c];
    } else if (c < 48) {
      float f = ori[orr * 3 + 1];
      f = f - floorf(f);
      int tod = (int)(f * 288.f);
      tod = min(max(tod, 0), 287);
      v = tod_emb[tod * 24 + (c - 24)];
    } else if (c < 72) {
      float f = ori[orr * 3 + 2];
      f = f - floorf(f);
      int dow = (int)(f * 7.f);
      dow = min(max(dow, 0), 6);
      v = dow_emb[dow * 24 + (c - 48)];
    } else {
      v = node_emb[node * 80 + (c - 72)];
    }
  }
  xe[idx] = __float2bfloat16(v);
}

// XEMBT[(b*NN+n)*1824 + t*152 + c] = XEMBb[((b*12+t)*NP + n)*160 + c]
__global__ void transpose_emb(const __hip_bfloat16* __restrict__ xe,
                              __hip_bfloat16* __restrict__ x_embT, int total)
{
  int idx = blockIdx.x * 256 + threadIdx.x;
  if (idx >= total) return;
  int c = idx % EMB;
  int r = idx / EMB;            // (b*NN + n)*TT + t
  int t = r % TT;
  int r2 = r / TT;
  int n = r2 % NN;
  int b = r2 / NN;
  x_embT[idx] = xe[(((long)(b * TT + t)) * NP + n) * EP + c];
}

__global__ void c2_kernel(const float* __restrict__ coeff2,
                          const float* __restrict__ W_ce,
                          const float* __restrict__ b_ce,
                          float* __restrict__ c2)
{
  int row = blockIdx.x;         // (b*N+n)*S + s
  int h = threadIdx.x;
  float a0 = coeff2[(long)row * 2];
  float a1 = coeff2[(long)row * 2 + 1];
  c2[(long)row * 64 + h] = a0 * W_ce[h] + a1 * W_ce[64 + h] + b_ce[h];
}

// WGPT[c][k] (bf16, [128,160]): c<64 -> Wg1[k][c], else Wg2[k][c-64]; k>=152 -> 0
__global__ void pack_wgT(const float* __restrict__ Wg1, const float* __restrict__ Wg2,
                         __hip_bfloat16* __restrict__ WGPT)
{
  int idx = blockIdx.x * 256 + threadIdx.x;
  if (idx >= 128 * EP) return;
  int c = idx / EP, k = idx % EP;
  float v = 0.f;
  if (k < EMB) v = (c < 64) ? Wg1[k * 64 + c] : Wg2[k * 64 + (c - 64)];
  WGPT[idx] = __float2bfloat16(v);
}

// adjb (bf16, [320,320]) zero-padded from adj [307,307]
__global__ void pack_adj(const float* __restrict__ adj, const float* __restrict__ adj_sem,
                         __hip_bfloat16* __restrict__ adjb,
                         __hip_bfloat16* __restrict__ adjsb)
{
  int idx = blockIdx.x * 256 + threadIdx.x;
  if (idx >= NP * NP) return;
  int m = idx / NP, k = idx % NP;
  float v1 = 0.f, v2 = 0.f;
  if (m < NN && k < NN) { v1 = adj[m * NN + k]; v2 = adj_sem[m * NN + k]; }
  adjb[idx] = __float2bfloat16(v1);
  adjsb[idx] = __float2bfloat16(v2);
}

// ---------------------------------------------------------------------------
// xg_mfma: XGT[bt, c(128), node(320)] = (XEMBb[bt] @ WGP)^T  (bf16 out)
// ---------------------------------------------------------------------------
__global__ __launch_bounds__(256) void xg_mfma(
    const __hip_bfloat16* __restrict__ XE, const __hip_bfloat16* __restrict__ WGPT,
    __hip_bfloat16* __restrict__ XGT)
{
  int bt = blockIdx.x;
  int tid = threadIdx.x, w = tid >> 6, l = tid & 63;
  int m0 = blockIdx.y * 64 + w * 16;      // node tile
  int cq = l & 15, rq = l >> 4;

  short8 af[5];
  const short* Ap = (const short*)XE + ((long)bt * NP + m0 + cq) * EP + rq * 8;
#pragma unroll
  for (int kk = 0; kk < 5; ++kk) af[kk] = *(const short8*)(Ap + kk * 32);

#pragma unroll
  for (int ct = 0; ct < 8; ++ct) {
    const short* Bp = (const short*)WGPT + (long)(ct * 16 + cq) * EP + rq * 8;
    floatx4 acc = {0.f, 0.f, 0.f, 0.f};
#pragma unroll
    for (int kk = 0; kk < 5; ++kk)
      acc = MFMA_B16(af[kk], *(const short8*)(Bp + kk * 32), acc);
    short4a pk;
#pragma unroll
    for (int r = 0; r < 4; ++r) pk[r] = f2bf(acc[r]);
    *(short4a*)((short*)XGT + ((long)bt * 128 + ct * 16 + cq) * NP + m0 + rq * 4) = pk;
  }
}

// ---------------------------------------------------------------------------
// gcn_mfma: GT[bt, node, 64] = relu( adj@XG1 + adjsem@XG2 + bg )  fp32 out
// ---------------------------------------------------------------------------
__global__ __launch_bounds__(256) void gcn_mfma(
    const __hip_bfloat16* __restrict__ XGT, const __hip_bfloat16* __restrict__ adjb,
    const __hip_bfloat16* __restrict__ adjsb, const float* __restrict__ bg,
    float* __restrict__ GT)
{
  int bt = blockIdx.x;
  int tid = threadIdx.x, w = tid >> 6, l = tid & 63;
  int n0 = blockIdx.y * 64;
  int cq = l & 15, rq = l >> 4;

  short8 a1[10], a2[10];
  const short* A1p = (const short*)XGT + ((long)bt * 128 + w * 16 + cq) * NP + rq * 8;
  const short* A2p = A1p + 64 * NP;
#pragma unroll
  for (int kk = 0; kk < 10; ++kk) {
    a1[kk] = *(const short8*)(A1p + kk * 32);
    a2[kk] = *(const short8*)(A2p + kk * 32);
  }

  float bgv[4];
#pragma unroll
  for (int r = 0; r < 4; ++r) bgv[r] = bg[w * 16 + rq * 4 + r];

#pragma unroll
  for (int nt = 0; nt < 4; ++nt) {
    const short* B1p = (const short*)adjb + (long)(n0 + nt * 16 + cq) * NP + rq * 8;
    const short* B2p = (const short*)adjsb + (long)(n0 + nt * 16 + cq) * NP + rq * 8;
    floatx4 acc = {0.f, 0.f, 0.f, 0.f};
#pragma unroll
    for (int kk = 0; kk < 10; ++kk) {
      acc = MFMA_B16(a1[kk], *(const short8*)(B1p + kk * 32), acc);
      acc = MFMA_B16(a2[kk], *(const short8*)(B2p + kk * 32), acc);
    }
    int node = n0 + nt * 16 + cq;
    if (node < NN) {
      float4 pk;
      pk.x = fmaxf(acc[0] + bgv[0], 0.f);
      pk.y = fmaxf(acc[1] + bgv[1], 0.f);
      pk.z = fmaxf(acc[2] + bgv[2], 0.f);
      pk.w = fmaxf(acc[3] + bgv[3], 0.f);
      *(float4*)(GT + (((long)bt * NP + node) * 64 + w * 16 + rq * 4)) = pk;
    }
  }
}

// gp: out[b,o,n] = w_het * (sum_{t,h} GT[b*TT+t, n, h]*Wgo[t*64+h, o] + bgo[o])
__global__ __launch_bounds__(64) void gp_kernel(const float* __restrict__ GT,
                                                const float* __restrict__ Wgo,
                                                const float* __restrict__ bgo,
                                                const float* __restrict__ w_het,
                                                float* __restrict__ out)
{
  int bn = blockIdx.x;
  int b = bn / NN, n = bn % NN;
  __shared__ float buf[TT * 64];
  for (int idx = threadIdx.x; idx < TT * 64; idx += 64) {
    int t = idx >> 6, h = idx & 63;
    buf[idx] = GT[(((long)(b * TT + t)) * NP + n) * 64 + h];
  }
  __syncthreads();
  int o = threadIdx.x;
  if (o < 12) {
    float acc = bgo[o];
    for (int j = 0; j < TT * 64; ++j) acc += buf[j] * Wgo[j * 12 + o];
    out[((long)b * 12 + o) * NN + n] = w_het[0] * acc;
  }
}

// ---------------------------------------------------------------------------
// x_in GEMM, bf16 MFMA, split-K=4, atomicAdd into bias-initialized Z.
// ---------------------------------------------------------------------------
__global__ __launch_bounds__(256) void gemm_xin(
    const __hip_bfloat16* __restrict__ A, const __hip_bfloat16* __restrict__ BT,
    float* __restrict__ C)
{
  int tid = threadIdx.x, w = tid >> 6, l = tid & 63;
  int m0 = blockIdx.x * 64 + w * 16;
  int n0 = blockIdx.y * 64;
  int k0s = blockIdx.z * 480;
  int k0e = min(1824, k0s + 480);

  int cq = l & 15, rq = l >> 4;
  int arow = min(m0 + cq, 1227);
  const short* Ap = (const short*)A + (long)arow * 1824 + rq * 8;
  const short* Bp = (const short*)BT + rq * 8;

  floatx4 acc[4] = {};
  for (int k0 = k0s; k0 < k0e; k0 += 32) {
    short8 a = *(const short8*)(Ap + k0);
#pragma unroll
    for (int nt = 0; nt < 4; ++nt) {
      short8 b = *(const short8*)(Bp + (long)(n0 + nt * 16 + cq) * 1824 + k0);
      acc[nt] = MFMA_B16(a, b, acc[nt]);
    }
  }
#pragma unroll
  for (int nt = 0; nt < 4; ++nt) {
    int c = n0 + nt * 16 + cq;
#pragma unroll
    for (int r = 0; r < 4; ++r) {
      int row = m0 + rq * 4 + r;
      if (row < 1228) atomicAdd(&C[(long)row * 704 + c], acc[nt][r]);
    }
  }
}

// Z (fp32, [b,n,s,h]) -> Zb (bf16, [bs, node(pad 320), 64]); pads zero-filled.
__global__ __launch_bounds__(256) void ztbf_kernel(const float* __restrict__ Z,
                                                   __hip_bfloat16* __restrict__ Zb)
{
  int row = blockIdx.x * 4 + (threadIdx.x >> 6);
  if (row >= NBS * NP) return;
  int lane = threadIdx.x & 63;
  int bs = row / NP, node = row - bs * NP;
  int b = bs / SS, s = bs - b * SS;
  float v = 0.f;
  if (node < NN) v = Z[(((long)(b * NN + node)) * SS + s) * 64 + lane];
  Zb[(long)row * 64 + lane] = __float2bfloat16(v);
}

// ---------------------------------------------------------------------------
// QKV projection, per-bs MFMA. Emits bf16 Qb/Kb [bs,NP,64], Vtb [bs,64,NP].
// ---------------------------------------------------------------------------
__global__ __launch_bounds__(256) void qkv_mfma(
    const __hip_bfloat16* __restrict__ Zb, const __hip_bfloat16* __restrict__ WT,
    const float* __restrict__ bqkv,
    __hip_bfloat16* __restrict__ Qb, __hip_bfloat16* __restrict__ Kb,
    __hip_bfloat16* __restrict__ Vtb)
{
  int bs = blockIdx.x, mt = blockIdx.y;
  int tid = threadIdx.x, w = tid >> 6, l = tid & 63;
  int m0 = mt * 64 + w * 16;
  int cq = l & 15, rq = l >> 4;

  const short* Ap = (const short*)Zb + ((long)bs * NP + m0 + cq) * 64 + rq * 8;
  short8 a0 = *(const short8*)Ap;
  short8 a1 = *(const short8*)(Ap + 32);

#pragma unroll
  for (int nt = 0; nt < 12; ++nt) {
    const short* Bp = (const short*)WT + (long)(nt * 16 + cq) * 64 + rq * 8;
    floatx4 acc = {0.f, 0.f, 0.f, 0.f};
    acc = MFMA_B16(a0, *(const short8*)Bp, acc);
    acc = MFMA_B16(a1, *(const short8*)(Bp + 32), acc);
    int c = nt * 16 + cq;
    float bias = bqkv[c];
#pragma unroll
    for (int r = 0; r < 4; ++r) {
      int node = m0 + rq * 4 + r;
      if (node < NN) {
        __hip_bfloat16 v = __float2bfloat16(acc[r] + bias);
        if (c < 64)       Qb[((long)bs * NP + node) * 64 + c] = v;
        else if (c < 128) Kb[((long)bs * NP + node) * 64 + (c - 64)] = v;
        else              Vtb[((long)bs * 64 + (c - 128)) * NP + node] = v;
      }
    }
  }
}

// ---------------------------------------------------------------------------
// MFMA attention (proven R6 structure).
// ---------------------------------------------------------------------------
__global__ __launch_bounds__(256) void attn_mfma(
    const __hip_bfloat16* __restrict__ Qb, const __hip_bfloat16* __restrict__ Kb,
    const __hip_bfloat16* __restrict__ Vtb, __hip_bfloat16* __restrict__ O)
{
  int bsh = blockIdx.x;           // bs*NH + head
  int head = bsh & 3;
  int bs = bsh >> 2;

  __shared__ __align__(16) short Kl[NP * KLP];
  __shared__ __align__(16) short Vl[16 * VLP];
  __shared__ __align__(16) short Pd[4][2][16 * PLP];

  int tid = threadIdx.x;
  const short* kg = (const short*)Kb + (long)bs * NP * 64 + head * 16;
  for (int ch = tid; ch < NP * 4; ch += 256) {
    int node = ch >> 2, part = (ch & 3) * 4;
    short4a kv = {0, 0, 0, 0};
    if (node < NN) kv = *(const short4a*)(kg + (long)node * 64 + part);
    *(short4a*)&Kl[node * KLP + part] = kv;
  }
  const short* vg = (const short*)Vtb + ((long)bs * 64 + head * 16) * NP;
  for (int ch = tid; ch < 16 * 80; ch += 256) {
    int d = ch / 80, k4 = (ch % 80) * 4;
    short4a vv = {0, 0, 0, 0};
    if (k4 + 3 < NN) {
      vv = *(const short4a*)(vg + (long)d * NP + k4);
    } else {
#pragma unroll
      for (int j = 0; j < 4; ++j)
        if (k4 + j < NN) vv[j] = vg[(long)d * NP + k4 + j];
    }
    *(short4a*)&Vl[d * VLP + k4] = vv;
  }
  __syncthreads();

  int wave = tid >> 6, lane = tid & 63;
  int m = lane & 15, quad = lane >> 4;
  int gg = blockIdx.y * 4 + wave;     // 16-query group, 0..19
  int q0 = gg * 16;
  int qv = q0 + m;

  const short8 z8 = {0, 0, 0, 0, 0, 0, 0, 0};
  const floatx4 zf = {0.f, 0.f, 0.f, 0.f};

  short8 qf = z8;
  if (quad < 2 && qv < NN)
    qf = *(const short8*)((const short*)Qb +
        ((long)bs * NP + qv) * 64 + head * 16 + quad * 8);

  short* Pw0 = &Pd[wave][0][0];
  short* Pw1 = &Pd[wave][1][0];

  float sum = 0.f;
  floatx4 oa = zf, ob = zf;

  for (int c = 0; c < 10; ++c) {
    short8 kf0 = z8, kf1 = z8;
    if (quad < 2) {
      kf0 = *(const short8*)&Kl[((2 * c) * 16 + m) * KLP + quad * 8];
      kf1 = *(const short8*)&Kl[((2 * c + 1) * 16 + m) * KLP + quad * 8];
    }
    floatx4 s0 = MFMA_B16(kf0, qf, zf);
    floatx4 s1 = MFMA_B16(kf1, qf, zf);

    float e0[4], e1[4];
#pragma unroll
    for (int j = 0; j < 4; ++j) {
      e0[j] = __expf(fminf(s0[j], 30.f));
      e1[j] = __expf(fminf(s1[j], 30.f));
    }
    if (c == 9) {
      if (quad == 0) e1[3] = 0.f;
      else { e1[0] = 0.f; e1[1] = 0.f; e1[2] = 0.f; e1[3] = 0.f; }
    }
    sum += e0[0] + e0[1] + e0[2] + e0[3] + e1[0] + e1[1] + e1[2] + e1[3];

    short4a p0, p1;
#pragma unroll
    for (int j = 0; j < 4; ++j) { p0[j] = f2bf(e0[j]); p1[j] = f2bf(e1[j]); }
    short* Pw = (c & 1) ? Pw1 : Pw0;
    *(short4a*)&Pw[m * PLP + quad * 4] = p0;
    *(short4a*)&Pw[m * PLP + 16 + quad * 4] = p1;

    short8 pf = *(const short8*)&Pw[m * PLP + quad * 8];
    short8 vf = *(const short8*)&Vl[m * VLP + c * 32 + quad * 8];
    if (c & 1) ob = MFMA_B16(vf, pf, ob);
    else       oa = MFMA_B16(vf, pf, oa);
  }

  sum += __shfl_xor(sum, 16);
  sum += __shfl_xor(sum, 32);
  float inv = 1.f / sum;

  if (qv < NN) {
    short4a pk;
#pragma unroll
    for (int r = 0; r < 4; ++r) pk[r] = f2bf((oa[r] + ob[r]) * inv);
    *(short4a*)((short*)O + ((long)bs * NN + qv) * 64 + head * 16 + quad * 4) = pk;
  }
}

// ---------------------------------------------------------------------------
// Fused scan epilogue: o2 = O@Wo+bo; h1 = LN1(z+o2); ff = FFN(h1);
// t = tanh(LN2(h1+ff)); Z += t*x2s[iter]; Zb = bf16(Z).
// All row-local: one kernel, no H1b/FF global round-trips.
// ---------------------------------------------------------------------------
__global__ __launch_bounds__(256) void block_step(
    const __hip_bfloat16* __restrict__ A, const __hip_bfloat16* __restrict__ WoT,
    const float* __restrict__ bo, const float* __restrict__ ln1g,
    const float* __restrict__ ln1b,
    const __hip_bfloat16* __restrict__ Wf1T, const float* __restrict__ bf1,
    const __hip_bfloat16* __restrict__ Wf2T, const float* __restrict__ bf2,
    const float* __restrict__ ln2g, const float* __restrict__ ln2b,
    const float* __restrict__ C2, const float* __restrict__ W_tp2,
    const float* __restrict__ b_tp2,
    float* __restrict__ Z, __hip_bfloat16* __restrict__ Zb, int iter)
{
  __shared__ __align__(16) short Hl[4][16 * HLP];   // h1 chunk per wave
  __shared__ __align__(16) short Hc[4][16 * HCP];   // hidden chunk per wave

  int tid = threadIdx.x, w = tid >> 6, l = tid & 63;
  int m0 = blockIdx.x * 64 + w * 16;
  int cq = l & 15, rq = l >> 4;

  // ---- Wo GEMM ----
  const short* Ap = (const short*)A + (long)(m0 + cq) * 64 + rq * 8;
  short8 a0 = *(const short8*)Ap;
  short8 a1 = *(const short8*)(Ap + 32);

  float x[4][4];                      // [nt][r]: row m0+rq*4+r, col nt*16+cq
#pragma unroll
  for (int nt = 0; nt < 4; ++nt) {
    const short* Bp = (const short*)WoT + (long)(nt * 16 + cq) * 64 + rq * 8;
    floatx4 acc = {0.f, 0.f, 0.f, 0.f};
    acc = MFMA_B16(a0, *(const short8*)Bp, acc);
    acc = MFMA_B16(a1, *(const short8*)(Bp + 32), acc);
    float bv = bo[nt * 16 + cq];
#pragma unroll
    for (int r = 0; r < 4; ++r) x[nt][r] = acc[r] + bv;
  }
  // residual from Z
  int rows[4], s1v[4];
  long bnv[4], zov[4];
#pragma unroll
  for (int r = 0; r < 4; ++r) {
    rows[r] = m0 + rq * 4 + r;
    zov[r] = zoff_of_row(min(rows[r], ROWS - 1), &s1v[r], &bnv[r]);
#pragma unroll
    for (int nt = 0; nt < 4; ++nt) x[nt][r] += Z[zov[r] + nt * 16 + cq];
  }
  float g1v[4], b1v[4], g2v[4], b2v[4], f2v[4];
#pragma unroll
  for (int nt = 0; nt < 4; ++nt) {
    g1v[nt] = ln1g[nt * 16 + cq];
    b1v[nt] = ln1b[nt * 16 + cq];
    g2v[nt] = ln2g[nt * 16 + cq];
    b2v[nt] = ln2b[nt * 16 + cq];
    f2v[nt] = bf2[nt * 16 + cq];
  }

  // ---- LN1 (row reduction across cq lanes) -> h1 ----
  float h1[4][4];
  short* Hw1 = &Hl[w][0];
#pragma unroll
  for (int r = 0; r < 4; ++r) {
    float s = x[0][r] + x[1][r] + x[2][r] + x[3][r];
#pragma unroll
    for (int off = 1; off <= 8; off <<= 1) s += __shfl_xor(s, off);
    float mean = s * (1.f / 64.f);
    float vs = 0.f;
#pragma unroll
    for (int nt = 0; nt < 4; ++nt) {
      float d = x[nt][r] - mean;
      vs += d * d;
    }
#pragma unroll
    for (int off = 1; off <= 8; off <<= 1) vs += __shfl_xor(vs, off);
    float rstd = rsqrtf(vs * (1.f / 64.f) + 1e-5f);
#pragma unroll
    for (int nt = 0; nt < 4; ++nt) {
      float h = (x[nt][r] - mean) * rstd * g1v[nt] + b1v[nt];
      h1[nt][r] = h;
      Hw1[(rq * 4 + r) * HLP + nt * 16 + cq] = f2bf(h);
    }
  }

  // ---- FFN phase A: hidden = relu(h1@Wf1+bf1) -> LDS hidden chunk ----
  short8 ha0 = *(const short8*)&Hw1[cq * HLP + rq * 8];
  short8 ha1 = *(const short8*)&Hw1[cq * HLP + 32 + rq * 8];
  short* Hw = &Hc[w][0];
#pragma unroll
  for (int ht = 0; ht < 16; ++ht) {
    const short* Bp = (const short*)Wf1T + (long)(ht * 16 + cq) * 64 + rq * 8;
    floatx4 acc = {0.f, 0.f, 0.f, 0.f};
    acc = MFMA_B16(ha0, *(const short8*)Bp, acc);
    acc = MFMA_B16(ha1, *(const short8*)(Bp + 32), acc);
    float bv = bf1[ht * 16 + cq];
#pragma unroll
    for (int r = 0; r < 4; ++r)
      Hw[(rq * 4 + r) * HCP + ht * 16 + cq] = f2bf(fmaxf(acc[r] + bv, 0.f));
  }

  // ---- FFN phase B: x = h1 + hidden@Wf2 + bf2 ----
#pragma unroll
  for (int nt = 0; nt < 4; ++nt) {
    const short* Bp = (const short*)Wf2T + (long)(nt * 16 + cq) * 256 + rq * 8;
    floatx4 acc = {0.f, 0.f, 0.f, 0.f};
#pragma unroll
    for (int kk = 0; kk < 8; ++kk) {
      short8 pf = *(const short8*)&Hw[cq * HCP + kk * 32 + rq * 8];
      acc = MFMA_B16(pf, *(const short8*)(Bp + kk * 32), acc);
    }
#pragma unroll
    for (int r = 0; r < 4; ++r) x[nt][r] = h1[nt][r] + acc[r] + f2v[nt];
  }

  // ---- LN2 + tanh + Euler update ----
#pragma unroll
  for (int r = 0; r < 4; ++r) {
    if (rows[r] >= ROWS) continue;
    float s = x[0][r] + x[1][r] + x[2][r] + x[3][r];
#pragma unroll
    for (int off = 1; off <= 8; off <<= 1) s += __shfl_xor(s, off);
    float mean = s * (1.f / 64.f);
    float vs = 0.f;
#pragma unroll
    for (int nt = 0; nt < 4; ++nt) {
      float d = x[nt][r] - mean;
      vs += d * d;
    }
#pragma unroll
    for (int off = 1; off <= 8; off <<= 1) vs += __shfl_xor(vs, off);
    float rstd = rsqrtf(vs * (1.f / 64.f) + 1e-5f);

    int s1 = s1v[r];
    long bn = bnv[r];
    // x2s weights for this row (shared across cols)
    float wtp[SS];
#pragma unroll
    for (int s2 = 0; s2 < SS; ++s2)
      wtp[s2] = W_tp2[s2 * (SS * SS) + s1 * SS + iter];
    float btp = b_tp2[s1 * SS + iter];

    int b = (int)(bn / NN), n = (int)(bn - (long)b * NN);
    long zbase = ((long)(b * SS + s1) * NP + n) * 64;
#pragma unroll
    for (int nt = 0; nt < 4; ++nt) {
      int col = nt * 16 + cq;
      float t = tanhf((x[nt][r] - mean) * rstd * g2v[nt] + b2v[nt]);
      float acc = btp;
#pragma unroll
      for (int s2 = 0; s2 < SS; ++s2)
        acc += C2[(bn * SS + s2) * 64 + col] * wtp[s2];
      float zn = Z[zov[r] + col] + t * acc;
      Z[zov[r] + col] = zn;
      Zb[zbase + col] = __float2bfloat16(zn);
    }
  }
}

// zT = LN(z[:,:,S-1,:]; lnf);  out[b,o,n] += w_acl*(zT@W_end + b_end)
__global__ __launch_bounds__(64) void final_acl(const float* __restrict__ z,
                                                const float* __restrict__ lnf_g,
                                                const float* __restrict__ lnf_b,
                                                const float* __restrict__ W_end,
                                                const float* __restrict__ b_end,
                                                const float* __restrict__ w_acl,
                                                float* __restrict__ out)
{
  int bn = blockIdx.x;
  int lane = threadIdx.x;
  int b = bn / NN, n = bn % NN;
  float x = z[((long)bn * SS + (SS - 1)) * 64 + lane];
  float m = wave_sum(x) * (1.f / 64.f);
  float d = x - m;
  float v = wave_sum(d * d) * (1.f / 64.f);
  float zT = d * rsqrtf(v + 1e-5f) * lnf_g[lane] + lnf_b[lane];
  float wa = w_acl[0];
  for (int o = 0; o < 12; ++o) {
    float p = zT * W_end[lane * 12 + o];
    p = wave_sum(p);
    if (lane == 0) {
      long oi = ((long)b * 12 + o) * NN + n;
      out[oi] = out[oi] + wa * (p + b_end[o]);
    }
  }
}

// ---------------------------------------------------------------------------
extern "C" void kernel_launch(void* const* d_in, const int* in_sizes, int n_in,
                              void* d_out, int out_size, void* d_ws, size_t ws_size,
                              hipStream_t stream)
{
  (void)in_sizes; (void)n_in; (void)out_size; (void)ws_size;

  const float* ori_x    = (const float*)d_in[0];
  const float* coeff2   = (const float*)d_in[2];
  const float* W_val    = (const float*)d_in[5];
  const float* b_val    = (const float*)d_in[6];
  const float* tod_emb  = (const float*)d_in[7];
  const float* dow_emb  = (const float*)d_in[8];
  const float* node_emb = (const float*)d_in[9];
  const float* W_in     = (const float*)d_in[10];
  const float* b_in     = (const float*)d_in[11];
  const float* W_ce     = (const float*)d_in[12];
  const float* b_ce     = (const float*)d_in[13];
  const float* W_tp2    = (const float*)d_in[14];
  const float* b_tp2    = (const float*)d_in[15];
  const float* Wq = (const float*)d_in[20];
  const float* Wk = (const float*)d_in[21];
  const float* Wv = (const float*)d_in[22];
  const float* Wo = (const float*)d_in[23];
  const float* bq = (const float*)d_in[24];
  const float* bk = (const float*)d_in[25];
  const float* bv = (const float*)d_in[26];
  const float* bo = (const float*)d_in[27];
  const float* ln1_g = (const float*)d_in[28];
  const float* ln1_b = (const float*)d_in[29];
  const float* Wf1   = (const float*)d_in[30];
  const float* bf1   = (const float*)d_in[31];
  const float* Wf2   = (const float*)d_in[32];
  const float* bf2   = (const float*)d_in[33];
  const float* ln2_g = (const float*)d_in[34];
  const float* ln2_b = (const float*)d_in[35];
  const float* lnf_g = (const float*)d_in[36];
  const float* lnf_b = (const float*)d_in[37];
  const float* W_end = (const float*)d_in[38];
  const float* b_end = (const float*)d_in[39];
  const float* w_acl = (const float*)d_in[40];
  const float* w_het = (const float*)d_in[41];
  const float* adj     = (const float*)d_in[42];
  const float* adj_sem = (const float*)d_in[43];
  const float* Wg1 = (const float*)d_in[44];
  const float* Wg2 = (const float*)d_in[45];
  const float* bg  = (const float*)d_in[46];
  const float* Wgo = (const float*)d_in[47];
  const float* bgo = (const float*)d_in[48];
  float* out = (float*)d_out;
  float* ws  = (float*)d_ws;

  const int ROWS_BN = BB * NN;        // 1228

  // ---- workspace layout (float offsets, 16-float aligned) ----
  float* Z     = ws;                             // 864512
  float* C2    = ws + 864512;                    // 864512
  __hip_bfloat16* Zb    = (__hip_bfloat16*)(ws + 1729024);   // 44*320*64
  __hip_bfloat16* WinT  = (__hip_bfloat16*)(ws + 2179584);   // 704*1824
  __hip_bfloat16* WqkvT = (__hip_bfloat16*)(ws + 2821632);   // 192*64
  __hip_bfloat16* WoT   = (__hip_bfloat16*)(ws + 2827776);   // 64*64
  __hip_bfloat16* Wf1T  = (__hip_bfloat16*)(ws + 2829824);   // 256*64
  __hip_bfloat16* Wf2T  = (__hip_bfloat16*)(ws + 2838016);   // 64*256
  float* BQKV  = ws + 2846208;                   // 192 (+pad)
  float* POOL  = ws + 2846416;
  // phase 1
  __hip_bfloat16* XEMBb = (__hip_bfloat16*)POOL;             // 48*320*160
  __hip_bfloat16* XEMBT = (__hip_bfloat16*)(POOL + 1228800); // 1228*1824
  __hip_bfloat16* XGT   = (__hip_bfloat16*)(POOL + 2348736); // 48*128*320
  float* GT             = POOL + 3331776;                    // 48*320*64 fp32
  __hip_bfloat16* ADJB  = (__hip_bfloat16*)(POOL + 4314816); // 320*320
  __hip_bfloat16* ADJSB = (__hip_bfloat16*)(POOL + 4366016); // 320*320
  __hip_bfloat16* WGPT  = (__hip_bfloat16*)(POOL + 4417216); // 128*160
  // phase 2 (overlays phase 1)
  __hip_bfloat16* Qb   = (__hip_bfloat16*)POOL;              // 44*320*64
  __hip_bfloat16* Kb   = (__hip_bfloat16*)(POOL + 450560);   // 44*320*64
  __hip_bfloat16* Vtb  = (__hip_bfloat16*)(POOL + 901120);   // 44*64*320
  __hip_bfloat16* Obf  = (__hip_bfloat16*)(POOL + 1351680);  // RPAD*64

  // ---- phase 1 ----
  embed_kernel<<<dim3(9600), dim3(256), 0, stream>>>(
      ori_x, W_val, b_val, tod_emb, dow_emb, node_emb, XEMBb, NBT * NP * EP);
  transpose_emb<<<dim3(8750), dim3(256), 0, stream>>>(
      XEMBb, XEMBT, ROWS_BN * TT * EMB);
  zinit_kernel<<<dim3(3377), dim3(256), 0, stream>>>(Z, b_in, ROWS_BN * SS * HH);
  transpose_cvt<<<dim3(57, 22), dim3(256), 0, stream>>>(W_in, WinT, 1824, 704, 1.f);
  transpose_cvt<<<dim3(2, 2), dim3(256), 0, stream>>>(Wq, WqkvT, 64, 64, 0.25f);
  transpose_cvt<<<dim3(2, 2), dim3(256), 0, stream>>>(Wk, WqkvT + 64 * 64, 64, 64, 1.f);
  transpose_cvt<<<dim3(2, 2), dim3(256), 0, stream>>>(Wv, WqkvT + 128 * 64, 64, 64, 1.f);
  transpose_cvt<<<dim3(2, 2), dim3(256), 0, stream>>>(Wo, WoT, 64, 64, 1.f);
  transpose_cvt<<<dim3(2, 8), dim3(256), 0, stream>>>(Wf1, Wf1T, 64, 256, 1.f);
  transpose_cvt<<<dim3(8, 2), dim3(256), 0, stream>>>(Wf2, Wf2T, 256, 64, 1.f);
  pack_bias<<<dim3(1), dim3(64), 0, stream>>>(bq, bk, bv, BQKV);
  pack_wgT<<<dim3(80), dim3(256), 0, stream>>>(Wg1, Wg2, WGPT);
  pack_adj<<<dim3(400), dim3(256), 0, stream>>>(adj, adj_sem, ADJB, ADJSB);
  gemm_xin<<<dim3(20, 11, 4), dim3(256), 0, stream>>>(XEMBT, WinT, Z);
  c2_kernel<<<dim3(ROWS_BN * SS), dim3(64), 0, stream>>>(coeff2, W_ce, b_ce, C2);
  xg_mfma<<<dim3(NBT, 5), dim3(256), 0, stream>>>(XEMBb, WGPT, XGT);
  gcn_mfma<<<dim3(NBT, 5), dim3(256), 0, stream>>>(XGT, ADJB, ADJSB, bg, GT);
  gp_kernel<<<dim3(ROWS_BN), dim3(64), 0, stream>>>(GT, Wgo, bgo, w_het, out);
  ztbf_kernel<<<dim3(NBS * NP / 4), dim3(256), 0, stream>>>(Z, Zb);

  // ---- phase 2: Euler scan, 11 steps, 3 dispatches each ----
  for (int i = 0; i < SS; ++i) {
    qkv_mfma<<<dim3(NBS, 5), dim3(256), 0, stream>>>(
        Zb, WqkvT, BQKV, Qb, Kb, Vtb);
    attn_mfma<<<dim3(NBS * NHH, 5), dim3(256), 0, stream>>>(Qb, Kb, Vtb, Obf);
    block_step<<<dim3(212), dim3(256), 0, stream>>>(
        Obf, WoT, bo, ln1_g, ln1_b, Wf1T, bf1, Wf2T, bf2,
        ln2_g, ln2_b, C2, W_tp2, b_tp2, Z, Zb, i);
  }

  // ---- epilogue ----
  final_acl<<<dim3(ROWS_BN), dim3(64), 0, stream>>>(
      Z, lnf_g, lnf_b, W_end, b_end, w_acl, out);
}